// Round 6
// baseline (223.517 us; speedup 1.0000x reference)
//
#include <hip/hip_runtime.h>
#include <hip/hip_bf16.h>

#define B_ 4
#define C_ 512
#define T_ 1024
#define SCALE_ 0.125f
#define EPS_ 1e-5f

typedef unsigned short u16;
typedef __attribute__((ext_vector_type(8))) unsigned short u16x8;
typedef __attribute__((ext_vector_type(4))) unsigned short u16x4;
typedef __attribute__((ext_vector_type(8))) short s16x8;
typedef __attribute__((ext_vector_type(4))) float f32x4;

// ws byte offsets (ws is 256 MiB)
#define QT_OFF    (0x0ull)         // bf16 Qt[B][T][C]   4 MB (Q pre-scaled by 1/8)
#define KT_OFF    (0x400000ull)    // bf16 Kt[B][T][C]   4 MB
#define V_OFF     (0x800000ull)    // bf16 V [B][C][T]   4 MB
#define XT_OFF    (0xC00000ull)    // bf16 Xt[B][T][C]   4 MB
#define O_OFF     (0x1000000ull)   // bf16 O[B][8][T][64] 4 MB (normalized, pre-affine)
#define AB_OFF    (0x1410000ull)   // fp32 ab[B][8][2]
#define VSUM_OFF  (0x1420000ull)   // fp32 vsum[B][8][64]
#define BIAS2_OFF (0x1430000ull)   // fp32 bias2[B][8][512]
#define LSUM_OFF  (0x1440000ull)   // fp32 lsum [B*8][1024]  128 KB
#define L2SUM_OFF (0x1460000ull)   // fp32 l2sum[B*8][1024]  128 KB
#define WB_OFF    (0x1480000ull)   // bf16 W[4][512][512]: wq,wk,wv,wp  2 MB
#define LP_OFF    (0x1680000ull)   // fp32 lpart [4][32][1024] 512 KB
#define L2P_OFF   (0x1700000ull)   // fp32 l2part[4][32][1024] 512 KB
#define OP_OFF    (0x2000000ull)   // fp32 Opart[4][32][1024][64] 32 MB

static __device__ __forceinline__ u16 f2bf(float f) {
  unsigned u = __float_as_uint(f);
  unsigned r = (u + 0x7fff + ((u >> 16) & 1)) >> 16;  // RNE
  return (u16)r;
}
static __device__ __forceinline__ float b2f(u16 x) {
  return __uint_as_float(((unsigned)x) << 16);
}
static __device__ __forceinline__ f32x4 mfma16(s16x8 a, s16x8 b, f32x4 c) {
  return __builtin_amdgcn_mfma_f32_16x16x32_bf16(a, b, c, 0, 0, 0);
}

// -------- convert all 4 weight matrices fp32 -> bf16 once --------
__global__ __launch_bounds__(256) void wcvt(const float* __restrict__ wq,
                                            const float* __restrict__ wk,
                                            const float* __restrict__ wv,
                                            const float* __restrict__ wp,
                                            u16* __restrict__ out) {
  const int i = (blockIdx.x << 8) + threadIdx.x;  // grid 512 -> 131072 threads
  const int idx = i << 3;                         // 8 elems each, 1048576 total
  const int which = idx >> 18;                    // uniform per block (128 blk/W)
  const int off = idx & 262143;
  const float* s = which == 0 ? wq : which == 1 ? wk : which == 2 ? wv : wp;
  const float4 f0 = *(const float4*)(s + off);
  const float4 f1 = *(const float4*)(s + off + 4);
  u16x8 o;
  o[0] = f2bf(f0.x); o[1] = f2bf(f0.y); o[2] = f2bf(f0.z); o[3] = f2bf(f0.w);
  o[4] = f2bf(f1.x); o[5] = f2bf(f1.y); o[6] = f2bf(f1.z); o[7] = f2bf(f1.w);
  *(u16x8*)(out + idx) = o;
}

// ---------------- transpose x -> Xt[b][t][c] bf16 ----------------
__global__ __launch_bounds__(256) void transpose_x(const float* __restrict__ x,
                                                   u16* __restrict__ xt) {
  const int b = blockIdx.z;
  const int t0 = blockIdx.x << 6;
  const int c0 = blockIdx.y << 6;
  const float* __restrict__ X = x + (size_t)b * (C_ * (size_t)T_);
  u16* __restrict__ Xt = xt + (size_t)b * (T_ * (size_t)C_);
  __shared__ float Ts[64][65];
  const int tid = threadIdx.x;
#pragma unroll
  for (int i = 0; i < 4; ++i) {
    const int e = tid + (i << 8);
    const int r = e >> 4, c4 = e & 15;
    const float4 v = *(const float4*)(X + (size_t)(c0 + r) * T_ + t0 + (c4 << 2));
    Ts[r][(c4 << 2) + 0] = v.x; Ts[r][(c4 << 2) + 1] = v.y;
    Ts[r][(c4 << 2) + 2] = v.z; Ts[r][(c4 << 2) + 3] = v.w;
  }
  __syncthreads();
#pragma unroll
  for (int i = 0; i < 2; ++i) {
    const int e = tid + (i << 8);
    const int tt = e >> 3, c8 = e & 7;
    u16x8 o;
#pragma unroll
    for (int j = 0; j < 8; ++j) o[j] = f2bf(Ts[(c8 << 3) + j][tt]);
    *(u16x8*)(Xt + (size_t)(t0 + tt) * C_ + c0 + (c8 << 3)) = o;
  }
}

// ------- Qt/Kt = Xt @ W^T -> [t][o] bf16 (Q scaled by 1/8), 64x64 tiles -----
__global__ __launch_bounds__(256) void gemm_qkt(const u16* __restrict__ xt,
                                                const u16* __restrict__ wqb,
                                                const u16* __restrict__ wkb,
                                                u16* __restrict__ qto,
                                                u16* __restrict__ kto) {
  const int which = blockIdx.z >> 2;
  const int b = blockIdx.z & 3;
  const u16* __restrict__ W = which ? wkb : wqb;
  u16* __restrict__ Y = (which ? kto : qto) + (size_t)b * (T_ * (size_t)C_);
  const u16* __restrict__ A = xt + (size_t)b * (T_ * (size_t)C_);
  const float sc = which ? 1.0f : SCALE_;
  const int m0 = blockIdx.x << 6;  // t
  const int n0 = blockIdx.y << 6;  // o
  __shared__ u16 As[64][72];
  __shared__ u16 Bs[64][72];
  const int tid = threadIdx.x;
  const int w = tid >> 6, lane = tid & 63, lr = lane & 15, lq = lane >> 4;
  const int mw = (w >> 1) << 5, nw = (w & 1) << 5;
  f32x4 acc[2][2] = {};
  for (int k0 = 0; k0 < C_; k0 += 64) {
#pragma unroll
    for (int it = 0; it < 2; ++it) {
      const int e = tid + (it << 8);
      const int r = e >> 3, c8 = e & 7;
      *(u16x8*)&As[r][c8 << 3] =
          *(const u16x8*)(A + (size_t)(m0 + r) * C_ + k0 + (c8 << 3));
      *(u16x8*)&Bs[r][c8 << 3] =
          *(const u16x8*)(W + (size_t)(n0 + r) * C_ + k0 + (c8 << 3));
    }
    __syncthreads();
#pragma unroll
    for (int kf = 0; kf < 2; ++kf) {
      const int ko = (kf << 5) + (lq << 3);
      s16x8 a[2], bb[2];
#pragma unroll
      for (int i = 0; i < 2; ++i) a[i] = *(const s16x8*)&As[mw + (i << 4) + lr][ko];
#pragma unroll
      for (int j = 0; j < 2; ++j) bb[j] = *(const s16x8*)&Bs[nw + (j << 4) + lr][ko];
#pragma unroll
      for (int i = 0; i < 2; ++i)
#pragma unroll
        for (int j = 0; j < 2; ++j) acc[i][j] = mfma16(a[i], bb[j], acc[i][j]);
    }
    __syncthreads();
  }
#pragma unroll
  for (int i = 0; i < 2; ++i) {
    const int row = mw + (i << 4) + (lq << 2);
#pragma unroll
    for (int j = 0; j < 2; ++j) {
      const int col = nw + (j << 4) + lr;
#pragma unroll
      for (int r = 0; r < 4; ++r)
        Y[(size_t)(m0 + row + r) * C_ + n0 + col] = f2bf(acc[i][j][r] * sc);
    }
  }
}

// ---------------- V = Wv @ X  -> [o][t] bf16, 64x64 tiles ----------------
__global__ __launch_bounds__(256) void gemm_v(const u16* __restrict__ xt,
                                              const u16* __restrict__ wvb,
                                              u16* __restrict__ vout) {
  const int b = blockIdx.z;
  const int n0 = blockIdx.x << 6;  // t
  const int m0 = blockIdx.y << 6;  // o
  const u16* __restrict__ Bg = xt + (size_t)b * (T_ * (size_t)C_);
  u16* __restrict__ Y = vout + (size_t)b * (C_ * (size_t)T_);
  __shared__ u16 As[64][72];
  __shared__ u16 Bs[64][72];
  const int tid = threadIdx.x;
  const int w = tid >> 6, lane = tid & 63, lr = lane & 15, lq = lane >> 4;
  const int mw = (w >> 1) << 5, nw = (w & 1) << 5;
  f32x4 acc[2][2] = {};
  for (int k0 = 0; k0 < C_; k0 += 64) {
#pragma unroll
    for (int it = 0; it < 2; ++it) {
      const int e = tid + (it << 8);
      const int r = e >> 3, c8 = e & 7;
      *(u16x8*)&As[r][c8 << 3] =
          *(const u16x8*)(wvb + (size_t)(m0 + r) * C_ + k0 + (c8 << 3));
      *(u16x8*)&Bs[r][c8 << 3] =
          *(const u16x8*)(Bg + (size_t)(n0 + r) * C_ + k0 + (c8 << 3));
    }
    __syncthreads();
#pragma unroll
    for (int kf = 0; kf < 2; ++kf) {
      const int ko = (kf << 5) + (lq << 3);
      s16x8 a[2], bb[2];
#pragma unroll
      for (int i = 0; i < 2; ++i) a[i] = *(const s16x8*)&As[mw + (i << 4) + lr][ko];
#pragma unroll
      for (int j = 0; j < 2; ++j) bb[j] = *(const s16x8*)&Bs[nw + (j << 4) + lr][ko];
#pragma unroll
      for (int i = 0; i < 2; ++i)
#pragma unroll
        for (int j = 0; j < 2; ++j) acc[i][j] = mfma16(a[i], bb[j], acc[i][j]);
    }
    __syncthreads();
  }
#pragma unroll
  for (int i = 0; i < 2; ++i) {
    const int row = mw + (i << 4) + (lq << 2);
#pragma unroll
    for (int j = 0; j < 2; ++j) {
      const int col = nw + (j << 4) + lr;
#pragma unroll
      for (int r = 0; r < 4; ++r)
        Y[(size_t)(m0 + row + r) * T_ + n0 + col] = f2bf(acc[i][j][r]);
    }
  }
}

// ---------------- vsum[b][g][d] = sum_t V ----------------
__global__ __launch_bounds__(256) void vsum_k(const u16* __restrict__ v,
                                              float* __restrict__ vsum) {
  const int bg = blockIdx.x;  // b*8+g
  const int tid = threadIdx.x;
  const int d = tid >> 2, part = tid & 3;
  const u16* __restrict__ Vr =
      v + ((size_t)(bg >> 3) * C_ + ((bg & 7) << 6) + d) * T_ + (part << 8);
  float s = 0.f;
  for (int t = 0; t < 256; t += 8) {
    const u16x8 x = *(const u16x8*)(Vr + t);
#pragma unroll
    for (int j = 0; j < 8; ++j) s += b2f(x[j]);
  }
  s += __shfl_down(s, 2, 64);
  s += __shfl_down(s, 1, 64);
  if (part == 0) vsum[(bg << 6) + d] = s;
}

// ---- FUSED attention v6: T-SPLIT grid 1024 = (b, qb, tq). Each block:
// one q16-tile x one 256-t quarter (2 chunks of 128), R5's wave-pair QK
// structure (even wave = K0 half, odd = +4 half; m[8] = 32 VGPRs, all 8
// heads, single pass). ~51.5 KB LDS -> 3 blocks/CU resident = 24 waves/CU
// (R5 was GRID-limited to 1 block/CU = 21% occupancy). No duplicated QK
// work; cost = raw f32 partial-O (32 MB) + partial l/l2, combined by
// combine_o. XCD map: b = (id&7)>>1 -> per-XCD L2 keeps one b's K/V/Q.
__global__ __launch_bounds__(512, 4) void attn_fused(
    const u16* __restrict__ Qt, const u16* __restrict__ Kt,
    const u16* __restrict__ v, const float* __restrict__ wh,
    float* __restrict__ Opart, float* __restrict__ lpart,
    float* __restrict__ l2part) {
  const int id = blockIdx.x;
  const int xcd = id & 7;
  const int b = xcd >> 1;
  const int hi = id >> 3;                      // [0,128)
  const int qb = ((xcd & 1) << 5) | (hi & 31); // [0,64)
  const int tq = hi >> 5;                      // [0,4) t-quarter
  const int q0 = qb << 4;
  const int tid = threadIdx.x;
  const int w = tid >> 6, lane = tid & 63;
  const int lr = lane & 15, quad = lane >> 4;

  __shared__ __align__(16) u16 Qs[16][522];       // 16704 B
  __shared__ __align__(16) u16 Plds[8][16][136];  // 34816 B
  float* Sbuf = (float*)&Plds[0][0][0];  // epilogue alias (Plds dead by then)

  {  // stage Q tile (16 x 512)
    const u16* Qb = Qt + ((size_t)b * T_ + q0) * C_;
    for (int i = tid; i < 1024; i += 512) {
      const int r = i >> 6, c8 = i & 63;
      *(u16x8*)&Qs[r][c8 << 3] = *(const u16x8*)(Qb + (size_t)r * C_ + (c8 << 3));
    }
  }

  const int tp = ((lr >> 2) << 3) + (lr & 3);  // permuted K row (validated)
  const u16* __restrict__ Qrow = &Qs[lr][quad << 3];
  const int g = w;  // PV head owned by this wave
  const int win = w >> 1, half = w & 1;  // QK: window pair, K-half
  const u16* __restrict__ Vg = v + ((size_t)b * C_ + (g << 6)) * (size_t)T_;

  float lacc[8] = {}, l2acc[8] = {};
  f32x4 acc[4] = {};

  __syncthreads();

  for (int c = 0; c < 2; ++c) {
    // ---- QK + mix + exp: this wave's 16 (permuted) t-rows of window ----
    const int tbase = (tq << 8) + (c << 7) + (win << 5);
    const u16* __restrict__ K0 =
        Kt + ((size_t)b * T_ + tbase + tp + (half << 2)) * C_ + (quad << 3);
    f32x4 m[8] = {};
#pragma unroll 2
    for (int h = 0; h < 8; ++h) {
      f32x4 a0 = {0.f, 0.f, 0.f, 0.f};
#pragma unroll
      for (int kf = 0; kf < 2; ++kf) {
        const int co = (h << 6) + (kf << 5);
        const s16x8 qf = *(const s16x8*)(Qrow + co);
        const s16x8 k0 = *(const s16x8*)(K0 + co);
        a0 = mfma16(k0, qf, a0);
      }
#pragma unroll
      for (int gg = 0; gg < 8; ++gg) {
        const float wgh = wh[(gg << 3) + h];  // uniform -> SGPR
        m[gg] += a0 * wgh;
      }
    }
    // lane's t slots: win*32 + quad*8 + half*4 + {0..3}; q = lr
#pragma unroll
    for (int gg = 0; gg < 8; ++gg) {
      f32x4 e0;
#pragma unroll
      for (int k = 0; k < 4; ++k) e0[k] = __expf(m[gg][k]);
      u16x4 o;
#pragma unroll
      for (int k = 0; k < 4; ++k) o[k] = f2bf(e0[k]);
      *(u16x4*)&Plds[gg][lr][(win << 5) + (quad << 3) + (half << 2)] = o;
      lacc[gg] += e0[0] + e0[1] + e0[2] + e0[3];
      l2acc[gg] += e0[0] * e0[0] + e0[1] * e0[1] + e0[2] * e0[2] + e0[3] * e0[3];
    }
    __syncthreads();  // P ready
    // ---- PV: this wave's g over the whole 128-t chunk ----
#pragma unroll
    for (int tw = 0; tw < 4; ++tw) {
      const s16x8 pa = *(const s16x8*)&Plds[g][lr][(tw << 5) + (quad << 3)];
#pragma unroll
      for (int dj = 0; dj < 4; ++dj) {
        const s16x8 vb =
            *(const s16x8*)(Vg + (size_t)((dj << 4) + lr) * T_ + (tq << 8) +
                            (c << 7) + (tw << 5) + (quad << 3));
        acc[dj] = mfma16(pa, vb, acc[dj]);
      }
    }
    __syncthreads();  // P consumed, safe to overwrite next chunk
  }

  // ---- write raw f32 partial O (normalization happens in combine_o) ----
  const int bg = (b << 3) + g;
  const size_t obase = ((((size_t)(tq << 5) + bg) << 10) + q0) * 64;
#pragma unroll
  for (int dj = 0; dj < 4; ++dj) {
    const int d = (dj << 4) + lr;
#pragma unroll
    for (int r = 0; r < 4; ++r) {
      const int q = (quad << 2) + r;
      Opart[obase + (size_t)q * 64 + d] = acc[dj][r];
    }
  }

  // ---- epilogue: l/l2 reduce (buffers alias Plds), write partials ----
  float* lbuf = Sbuf;          // [8w][8g][16q]  4 KB
  float* l2buf = Sbuf + 1024;  // [8w][8g][16q]  4 KB
#pragma unroll
  for (int gg = 0; gg < 8; ++gg) {
    float l = lacc[gg];
    l += __shfl_xor(l, 16, 64);
    l += __shfl_xor(l, 32, 64);
    float l2 = l2acc[gg];
    l2 += __shfl_xor(l2, 16, 64);
    l2 += __shfl_xor(l2, 32, 64);
    if (quad == 0) {
      lbuf[(w << 7) + (gg << 4) + lr] = l;
      l2buf[(w << 7) + (gg << 4) + lr] = l2;
    }
  }
  __syncthreads();
  if (lane < 16) {  // wave w reduces its own g
    float l = 0.f, l2 = 0.f;
#pragma unroll
    for (int w2 = 0; w2 < 8; ++w2) {
      l += lbuf[(w2 << 7) + (g << 4) + lr];
      l2 += l2buf[(w2 << 7) + (g << 4) + lr];
    }
    const size_t li = (((size_t)(tq << 5) + bg) << 10) + q0 + lr;
    lpart[li] = l;
    l2part[li] = l2;
  }
}

// ---- combine: O = (sum_tq Opart) / l, l/l2 full sums -> lsum/l2sum ----
__global__ __launch_bounds__(256) void combine_o(
    const float* __restrict__ Opart, const float* __restrict__ lpart,
    const float* __restrict__ l2part, u16* __restrict__ O,
    float* __restrict__ lsum, float* __restrict__ l2sum) {
  const int bg = blockIdx.x;       // [0,32)
  const int qo = blockIdx.y;       // [0,8) q-octant
  const int tid = threadIdx.x;
  const int q = (qo << 7) + (tid >> 1);
  const int d0 = (tid & 1) << 5;
  float l = 0.f, l2 = 0.f;
#pragma unroll
  for (int tq = 0; tq < 4; ++tq) {
    const size_t li = (((size_t)(tq << 5) + bg) << 10) + q;
    l += lpart[li];
    l2 += l2part[li];
  }
  const float linv = 1.f / l;
  if ((tid & 1) == 0) {
    lsum[((size_t)bg << 10) + q] = l;
    l2sum[((size_t)bg << 10) + q] = l2;
  }
  f32x4 a[8] = {};
#pragma unroll
  for (int tq = 0; tq < 4; ++tq) {
    const float* src =
        Opart + ((((size_t)(tq << 5) + bg) << 10) + q) * 64 + d0;
#pragma unroll
    for (int j = 0; j < 8; ++j) a[j] += *(const f32x4*)(src + (j << 2));
  }
  u16* dst = O + (((size_t)bg << 10) + q) * 64 + d0;
#pragma unroll
  for (int j = 0; j < 4; ++j) {
    u16x8 o;
#pragma unroll
    for (int k = 0; k < 4; ++k) {
      o[k] = f2bf(a[2 * j][k] * linv);
      o[k + 4] = f2bf(a[2 * j + 1][k] * linv);
    }
    *(u16x8*)(dst + (j << 3)) = o;
  }
}

// ---- merged: reduce per-q l/l2 -> ab, then bias2 for this (b,g) ----
__global__ __launch_bounds__(256) void stats_k(const float* __restrict__ lsum,
                                               const float* __restrict__ l2sum,
                                               const float* __restrict__ gamma,
                                               const float* __restrict__ beta,
                                               const float* __restrict__ wp,
                                               const float* __restrict__ bp,
                                               const float* __restrict__ vsum,
                                               float* __restrict__ ab,
                                               float* __restrict__ bias2) {
  const int bg = blockIdx.x;
  const int g = bg & 7;
  const int tid = threadIdx.x;
  const f32x4 l = *(const f32x4*)(lsum + ((size_t)bg << 10) + (tid << 2));
  const f32x4 l2 = *(const f32x4*)(l2sum + ((size_t)bg << 10) + (tid << 2));
  float ssq = 0.f;
#pragma unroll
  for (int k = 0; k < 4; ++k) ssq += l2[k] / (l[k] * l[k]);
#pragma unroll
  for (int off = 32; off; off >>= 1) ssq += __shfl_xor(ssq, off, 64);
  __shared__ float red[4];
  __shared__ float bt2s;
  if ((tid & 63) == 0) red[tid >> 6] = ssq;
  __syncthreads();
  if (tid == 0) {
    const float s = red[0] + red[1] + red[2] + red[3];
    const float mean = 0.0009765625f;
    const float var = s * (1.f / 1048576.f) - mean * mean;
    const float al = gamma[g] * rsqrtf(var + EPS_);
    const float bt2 = beta[g] - al * mean;
    ab[bg * 2] = al;
    ab[bg * 2 + 1] = bt2;
    bt2s = bt2;
  }
  __syncthreads();
  const float bt2 = bt2s;
  const float* vs = vsum + (bg << 6);
#pragma unroll
  for (int oo = 0; oo < 2; ++oo) {
    const int o = tid + (oo << 8);
    const float* wr = wp + (size_t)o * C_;
    float acc = 0.f;
#pragma unroll
    for (int d = 0; d < 64; d += 4) {
      const float4 vv4 = *(const float4*)(vs + d);
      float4 ws4 = {0.f, 0.f, 0.f, 0.f};
#pragma unroll
      for (int j = 0; j < 8; ++j) {
        const float4 wv4 = *(const float4*)(wr + (j << 6) + d);
        ws4.x += wv4.x; ws4.y += wv4.y; ws4.z += wv4.z; ws4.w += wv4.w;
      }
      acc += ws4.x * vv4.x + ws4.y * vv4.y + ws4.z * vv4.z + ws4.w * vv4.w;
    }
    bias2[(bg << 9) + o] = bp[o] + bt2 * acc;
  }
}

// ------- y = al[b,g(t)]*(Mnorm @ Wp^T) + bias2[b][g(t)][o], 64x64 tiles ----
__global__ __launch_bounds__(256) void gemm_proj(const u16* __restrict__ O,
                                                 const u16* __restrict__ wpb,
                                                 const float* __restrict__ ab,
                                                 const float* __restrict__ bias2,
                                                 float* __restrict__ y) {
  const int b = blockIdx.z;
  const int m0 = blockIdx.y << 6;  // o
  const int n0 = blockIdx.x << 6;  // t
  const int gidx = blockIdx.x >> 1;
  const u16* __restrict__ Ob = O + (size_t)b * (8 * T_ * 64);
  __shared__ u16 As[64][72];
  __shared__ u16 Bs[64][72];
  const int tid = threadIdx.x;
  const int w = tid >> 6, lane = tid & 63, lr = lane & 15, lq = lane >> 4;
  const int mw = (w >> 1) << 5, nw = (w & 1) << 5;
  f32x4 acc[2][2] = {};
  for (int k0 = 0; k0 < C_; k0 += 64) {
#pragma unroll
    for (int it = 0; it < 2; ++it) {
      const int e = tid + (it << 8);
      const int r = e >> 3, c8 = e & 7;
      *(u16x8*)&As[r][c8 << 3] =
          *(const u16x8*)(wpb + (size_t)(m0 + r) * C_ + k0 + (c8 << 3));
      const int t = n0 + r;
      const int c = k0 + (c8 << 3);
      *(u16x8*)&Bs[r][c8 << 3] =
          *(const u16x8*)(Ob + (size_t)(t >> 7) * (T_ * 64) +
                          (size_t)(((t & 127) << 3) + (c >> 6)) * 64 + (c & 63));
    }
    __syncthreads();
#pragma unroll
    for (int kf = 0; kf < 2; ++kf) {
      const int ko = (kf << 5) + (lq << 3);
      s16x8 a[2], bb[2];
#pragma unroll
      for (int i = 0; i < 2; ++i) a[i] = *(const s16x8*)&As[mw + (i << 4) + lr][ko];
#pragma unroll
      for (int j = 0; j < 2; ++j) bb[j] = *(const s16x8*)&Bs[nw + (j << 4) + lr][ko];
#pragma unroll
      for (int i = 0; i < 2; ++i)
#pragma unroll
        for (int j = 0; j < 2; ++j) acc[i][j] = mfma16(a[i], bb[j], acc[i][j]);
    }
    __syncthreads();
  }
  const float al = ab[(((b << 3) + gidx) << 1)];
  const float* __restrict__ b2 = bias2 + (((b << 3) + gidx) << 9);
#pragma unroll
  for (int i = 0; i < 2; ++i) {
    const int row = mw + (i << 4) + (lq << 2);
#pragma unroll
    for (int j = 0; j < 2; ++j) {
      const int col = nw + (j << 4) + lr;
#pragma unroll
      for (int r = 0; r < 4; ++r)
        y[(size_t)b * (C_ * (size_t)T_) + (size_t)(m0 + row + r) * T_ + n0 + col] =
            acc[i][j][r] * al + b2[m0 + row + r];
    }
  }
}

extern "C" void kernel_launch(void* const* d_in, const int* in_sizes, int n_in,
                              void* d_out, int out_size, void* d_ws,
                              size_t ws_size, hipStream_t stream) {
  const float* x = (const float*)d_in[0];
  const float* wq = (const float*)d_in[1];
  const float* wk = (const float*)d_in[2];
  const float* wv = (const float*)d_in[3];
  const float* wh = (const float*)d_in[4];
  const float* gm = (const float*)d_in[5];
  const float* bt = (const float*)d_in[6];
  const float* wp = (const float*)d_in[7];
  const float* bp = (const float*)d_in[8];
  float* y = (float*)d_out;
  char* wsb = (char*)d_ws;

  u16* Qt = (u16*)(wsb + QT_OFF);
  u16* Kt = (u16*)(wsb + KT_OFF);
  u16* V = (u16*)(wsb + V_OFF);
  u16* Xt = (u16*)(wsb + XT_OFF);
  u16* Og = (u16*)(wsb + O_OFF);
  float* ab = (float*)(wsb + AB_OFF);
  float* vsum = (float*)(wsb + VSUM_OFF);
  float* bias2 = (float*)(wsb + BIAS2_OFF);
  float* lsum = (float*)(wsb + LSUM_OFF);
  float* l2sum = (float*)(wsb + L2SUM_OFF);
  u16* Wb = (u16*)(wsb + WB_OFF);
  u16* WQb = Wb;
  u16* WKb = Wb + 262144;
  u16* WVb = Wb + 524288;
  u16* WPb = Wb + 786432;
  float* lpart = (float*)(wsb + LP_OFF);
  float* l2part = (float*)(wsb + L2P_OFF);
  float* Opart = (float*)(wsb + OP_OFF);

  wcvt<<<dim3(512), 256, 0, stream>>>(wq, wk, wv, wp, Wb);
  transpose_x<<<dim3(16, 8, 4), 256, 0, stream>>>(x, Xt);
  gemm_qkt<<<dim3(16, 8, 8), 256, 0, stream>>>(Xt, WQb, WKb, Qt, Kt);
  gemm_v<<<dim3(16, 8, 4), 256, 0, stream>>>(Xt, WVb, V);
  vsum_k<<<dim3(32), 256, 0, stream>>>(V, vsum);
  attn_fused<<<dim3(1024), 512, 0, stream>>>(Qt, Kt, V, wh, Opart, lpart,
                                             l2part);
  combine_o<<<dim3(32, 8), 256, 0, stream>>>(Opart, lpart, l2part, Og, lsum,
                                             l2sum);
  stats_k<<<dim3(32), 256, 0, stream>>>(lsum, l2sum, gm, bt, wp, bp, vsum, ab,
                                        bias2);
  gemm_proj<<<dim3(16, 8, 4), 256, 0, stream>>>(Og, WPb, ab, bias2, y);
}

// Round 7
// 198.696 us; speedup vs baseline: 1.1249x; 1.1249x over previous
//
#include <hip/hip_runtime.h>
#include <hip/hip_bf16.h>

#define B_ 4
#define C_ 512
#define T_ 1024
#define SCALE_ 0.125f
#define EPS_ 1e-5f

typedef unsigned short u16;
typedef __attribute__((ext_vector_type(8))) unsigned short u16x8;
typedef __attribute__((ext_vector_type(4))) unsigned short u16x4;
typedef __attribute__((ext_vector_type(8))) short s16x8;
typedef __attribute__((ext_vector_type(4))) float f32x4;

// ws byte offsets (ws is 256 MiB)
#define QT_OFF    (0x0ull)         // bf16 Qt[B][T][C]   4 MB (Q pre-scaled by 1/8)
#define KT_OFF    (0x400000ull)    // bf16 Kt[B][T][C]   4 MB
#define V_OFF     (0x800000ull)    // bf16 V [B][C][T]   4 MB
#define XT_OFF    (0xC00000ull)    // bf16 Xt[B][T][C]   4 MB
#define O_OFF     (0x1000000ull)   // bf16 O[B][8][T][64] 4 MB (normalized, pre-affine)
#define AB_OFF    (0x1410000ull)   // fp32 ab[B][8][2]
#define VSUM_OFF  (0x1420000ull)   // fp32 vsum[B][8][64]
#define BIAS2_OFF (0x1430000ull)   // fp32 bias2[B][8][512]
#define LSUM_OFF  (0x1440000ull)   // fp32 lsum [B*8][1024]  128 KB
#define L2SUM_OFF (0x1460000ull)   // fp32 l2sum[B*8][1024]  128 KB
#define WB_OFF    (0x1480000ull)   // bf16 W[4][512][512]: wq,wk,wv,wp  2 MB
#define LP_OFF    (0x1680000ull)   // fp32 lpart [2][32][1024] 256 KB
#define L2P_OFF   (0x1700000ull)   // fp32 l2part[2][32][1024] 256 KB
#define WS_OFF    (0x1780000ull)   // fp32 ws[512][64] 128 KB
#define OP_OFF    (0x2000000ull)   // fp32 Opart[2][32][1024][64] 16 MB

static __device__ __forceinline__ u16 f2bf(float f) {
  unsigned u = __float_as_uint(f);
  unsigned r = (u + 0x7fff + ((u >> 16) & 1)) >> 16;  // RNE
  return (u16)r;
}
static __device__ __forceinline__ float b2f(u16 x) {
  return __uint_as_float(((unsigned)x) << 16);
}
static __device__ __forceinline__ f32x4 mfma16(s16x8 a, s16x8 b, f32x4 c) {
  return __builtin_amdgcn_mfma_f32_16x16x32_bf16(a, b, c, 0, 0, 0);
}

// -------- convert all 4 weight matrices fp32 -> bf16 once --------
__global__ __launch_bounds__(256) void wcvt(const float* __restrict__ wq,
                                            const float* __restrict__ wk,
                                            const float* __restrict__ wv,
                                            const float* __restrict__ wp,
                                            u16* __restrict__ out) {
  const int i = (blockIdx.x << 8) + threadIdx.x;  // grid 512 -> 131072 threads
  const int idx = i << 3;                         // 8 elems each, 1048576 total
  const int which = idx >> 18;                    // uniform per block (128 blk/W)
  const int off = idx & 262143;
  const float* s = which == 0 ? wq : which == 1 ? wk : which == 2 ? wv : wp;
  const float4 f0 = *(const float4*)(s + off);
  const float4 f1 = *(const float4*)(s + off + 4);
  u16x8 o;
  o[0] = f2bf(f0.x); o[1] = f2bf(f0.y); o[2] = f2bf(f0.z); o[3] = f2bf(f0.w);
  o[4] = f2bf(f1.x); o[5] = f2bf(f1.y); o[6] = f2bf(f1.z); o[7] = f2bf(f1.w);
  *(u16x8*)(out + idx) = o;
}

// ---- ws[o][d] = sum_j wp[o][j*64+d]; also zero vsum (blocks 0..7) ----
__global__ __launch_bounds__(256) void wsum_k(const float* __restrict__ wp,
                                              float* __restrict__ ws,
                                              float* __restrict__ vsum) {
  const int idx = (blockIdx.x << 8) + threadIdx.x;  // grid 128 -> 32768
  if (blockIdx.x < 8) vsum[idx] = 0.f;              // 2048 floats
  const int o = idx >> 6, d = idx & 63;
  float s = 0.f;
#pragma unroll
  for (int j = 0; j < 8; ++j) s += wp[(o << 9) + (j << 6) + d];
  ws[idx] = s;
}

// ---------------- transpose x -> Xt[b][t][c] bf16 ----------------
__global__ __launch_bounds__(256) void transpose_x(const float* __restrict__ x,
                                                   u16* __restrict__ xt) {
  const int b = blockIdx.z;
  const int t0 = blockIdx.x << 6;
  const int c0 = blockIdx.y << 6;
  const float* __restrict__ X = x + (size_t)b * (C_ * (size_t)T_);
  u16* __restrict__ Xt = xt + (size_t)b * (T_ * (size_t)C_);
  __shared__ float Ts[64][65];
  const int tid = threadIdx.x;
#pragma unroll
  for (int i = 0; i < 4; ++i) {
    const int e = tid + (i << 8);
    const int r = e >> 4, c4 = e & 15;
    const float4 v = *(const float4*)(X + (size_t)(c0 + r) * T_ + t0 + (c4 << 2));
    Ts[r][(c4 << 2) + 0] = v.x; Ts[r][(c4 << 2) + 1] = v.y;
    Ts[r][(c4 << 2) + 2] = v.z; Ts[r][(c4 << 2) + 3] = v.w;
  }
  __syncthreads();
#pragma unroll
  for (int i = 0; i < 2; ++i) {
    const int e = tid + (i << 8);
    const int tt = e >> 3, c8 = e & 7;
    u16x8 o;
#pragma unroll
    for (int j = 0; j < 8; ++j) o[j] = f2bf(Ts[(c8 << 3) + j][tt]);
    *(u16x8*)(Xt + (size_t)(t0 + tt) * C_ + c0 + (c8 << 3)) = o;
  }
}

// ------- Qt/Kt = Xt @ W^T -> [t][o] bf16 (Q scaled by 1/8), 64x64 tiles -----
__global__ __launch_bounds__(256) void gemm_qkt(const u16* __restrict__ xt,
                                                const u16* __restrict__ wqb,
                                                const u16* __restrict__ wkb,
                                                u16* __restrict__ qto,
                                                u16* __restrict__ kto) {
  const int which = blockIdx.z >> 2;
  const int b = blockIdx.z & 3;
  const u16* __restrict__ W = which ? wkb : wqb;
  u16* __restrict__ Y = (which ? kto : qto) + (size_t)b * (T_ * (size_t)C_);
  const u16* __restrict__ A = xt + (size_t)b * (T_ * (size_t)C_);
  const float sc = which ? 1.0f : SCALE_;
  const int m0 = blockIdx.x << 6;  // t
  const int n0 = blockIdx.y << 6;  // o
  __shared__ u16 As[64][72];
  __shared__ u16 Bs[64][72];
  const int tid = threadIdx.x;
  const int w = tid >> 6, lane = tid & 63, lr = lane & 15, lq = lane >> 4;
  const int mw = (w >> 1) << 5, nw = (w & 1) << 5;
  f32x4 acc[2][2] = {};
  for (int k0 = 0; k0 < C_; k0 += 64) {
#pragma unroll
    for (int it = 0; it < 2; ++it) {
      const int e = tid + (it << 8);
      const int r = e >> 3, c8 = e & 7;
      *(u16x8*)&As[r][c8 << 3] =
          *(const u16x8*)(A + (size_t)(m0 + r) * C_ + k0 + (c8 << 3));
      *(u16x8*)&Bs[r][c8 << 3] =
          *(const u16x8*)(W + (size_t)(n0 + r) * C_ + k0 + (c8 << 3));
    }
    __syncthreads();
#pragma unroll
    for (int kf = 0; kf < 2; ++kf) {
      const int ko = (kf << 5) + (lq << 3);
      s16x8 a[2], bb[2];
#pragma unroll
      for (int i = 0; i < 2; ++i) a[i] = *(const s16x8*)&As[mw + (i << 4) + lr][ko];
#pragma unroll
      for (int j = 0; j < 2; ++j) bb[j] = *(const s16x8*)&Bs[nw + (j << 4) + lr][ko];
#pragma unroll
      for (int i = 0; i < 2; ++i)
#pragma unroll
        for (int j = 0; j < 2; ++j) acc[i][j] = mfma16(a[i], bb[j], acc[i][j]);
    }
    __syncthreads();
  }
#pragma unroll
  for (int i = 0; i < 2; ++i) {
    const int row = mw + (i << 4) + (lq << 2);
#pragma unroll
    for (int j = 0; j < 2; ++j) {
      const int col = nw + (j << 4) + lr;
#pragma unroll
      for (int r = 0; r < 4; ++r)
        Y[(size_t)(m0 + row + r) * C_ + n0 + col] = f2bf(acc[i][j][r] * sc);
    }
  }
}

// ---------------- V = Wv @ X  -> [o][t] bf16, 64x64 tiles ----------------
__global__ __launch_bounds__(256) void gemm_v(const u16* __restrict__ xt,
                                              const u16* __restrict__ wvb,
                                              u16* __restrict__ vout) {
  const int b = blockIdx.z;
  const int n0 = blockIdx.x << 6;  // t
  const int m0 = blockIdx.y << 6;  // o
  const u16* __restrict__ Bg = xt + (size_t)b * (T_ * (size_t)C_);
  u16* __restrict__ Y = vout + (size_t)b * (C_ * (size_t)T_);
  __shared__ u16 As[64][72];
  __shared__ u16 Bs[64][72];
  const int tid = threadIdx.x;
  const int w = tid >> 6, lane = tid & 63, lr = lane & 15, lq = lane >> 4;
  const int mw = (w >> 1) << 5, nw = (w & 1) << 5;
  f32x4 acc[2][2] = {};
  for (int k0 = 0; k0 < C_; k0 += 64) {
#pragma unroll
    for (int it = 0; it < 2; ++it) {
      const int e = tid + (it << 8);
      const int r = e >> 3, c8 = e & 7;
      *(u16x8*)&As[r][c8 << 3] =
          *(const u16x8*)(wvb + (size_t)(m0 + r) * C_ + k0 + (c8 << 3));
      *(u16x8*)&Bs[r][c8 << 3] =
          *(const u16x8*)(Bg + (size_t)(n0 + r) * C_ + k0 + (c8 << 3));
    }
    __syncthreads();
#pragma unroll
    for (int kf = 0; kf < 2; ++kf) {
      const int ko = (kf << 5) + (lq << 3);
      s16x8 a[2], bb[2];
#pragma unroll
      for (int i = 0; i < 2; ++i) a[i] = *(const s16x8*)&As[mw + (i << 4) + lr][ko];
#pragma unroll
      for (int j = 0; j < 2; ++j) bb[j] = *(const s16x8*)&Bs[nw + (j << 4) + lr][ko];
#pragma unroll
      for (int i = 0; i < 2; ++i)
#pragma unroll
        for (int j = 0; j < 2; ++j) acc[i][j] = mfma16(a[i], bb[j], acc[i][j]);
    }
    __syncthreads();
  }
#pragma unroll
  for (int i = 0; i < 2; ++i) {
    const int row = mw + (i << 4) + (lq << 2);
#pragma unroll
    for (int j = 0; j < 2; ++j) {
      const int col = nw + (j << 4) + lr;
#pragma unroll
      for (int r = 0; r < 4; ++r)
        Y[(size_t)(m0 + row + r) * T_ + n0 + col] = f2bf(acc[i][j][r]);
    }
  }
}

// ------ vsum[b][g][d] = sum_t V : grid (32 bg, 8 t-chunks), atomics ------
__global__ __launch_bounds__(256) void vsum_k(const u16* __restrict__ v,
                                              float* __restrict__ vsum) {
  const int bg = blockIdx.x;
  const int tc = blockIdx.y;  // 128-t chunk
  const int tid = threadIdx.x;
  const int d = tid >> 2, part = tid & 3;
  const u16* __restrict__ Vr = v + ((size_t)(bg >> 3) * C_ + ((bg & 7) << 6) + d) * T_ +
                               (tc << 7) + (part << 5);
  float s = 0.f;
#pragma unroll
  for (int t = 0; t < 32; t += 8) {
    const u16x8 x = *(const u16x8*)(Vr + t);
#pragma unroll
    for (int j = 0; j < 8; ++j) s += b2f(x[j]);
  }
  s += __shfl_down(s, 2, 64);
  s += __shfl_down(s, 1, 64);
  if (part == 0) atomicAdd(&vsum[(bg << 6) + d], s);
}

// ---- FUSED attention v7: grid 512 = (b, qb, th). Block = q16-tile x 512-t
// half (4 chunks of 128t). R6 structure + T14 PIPELINING: a wave's whole
// per-chunk K set is 16 s16x8 frags (64 VGPR) -> double-buffer kA/kB,
// prefetch next chunk's K before this chunk's QK compute (QK = pure
// compute, zero VMEM waits); V frags (16) issued BEFORE the P-publish
// barrier so their latency hides under barrier+publish. launch_bounds
// (512,2) -> 256-VGPR budget (demand ~210; the R2/R3 spill came from the
// 4-waves/EU clamp). Occupancy ~1 block/CU is EXPECTED; the stall that
// pinned R1/R5/R6 at ~75us was correlated in-wave load latency, not
// occupancy. All kreg/vreg indexing static (macros + full unroll).
__global__ __launch_bounds__(512, 2) void attn_fused(
    const u16* __restrict__ Qt, const u16* __restrict__ Kt,
    const u16* __restrict__ v, const float* __restrict__ wh,
    float* __restrict__ Opart, float* __restrict__ lpart,
    float* __restrict__ l2part) {
  const int id = blockIdx.x;
  const int xcd = id & 7;
  const int b = xcd >> 1;
  const int hi = id >> 3;                       // [0,64)
  const int qb = ((xcd & 1) << 5) | (hi & 31);  // [0,64)
  const int tq = hi >> 5;                       // [0,2) t-half
  const int q0 = qb << 4;
  const int tid = threadIdx.x;
  const int w = tid >> 6, lane = tid & 63;
  const int lr = lane & 15, quad = lane >> 4;

  __shared__ __align__(16) u16 Qs[16][522];       // 16704 B
  __shared__ __align__(16) u16 Plds[8][16][136];  // 34816 B
  float* Sbuf = (float*)&Plds[0][0][0];  // epilogue alias (Plds dead by then)

  const int tp = ((lr >> 2) << 3) + (lr & 3);  // permuted K row (validated)
  const int g = w;                       // PV head owned by this wave
  const int win = w >> 1, half = w & 1;  // QK: window pair, K-half
  const u16* __restrict__ Kbase =
      Kt + ((size_t)b * T_ + tp + (half << 2)) * C_ + (quad << 3);
  const u16* __restrict__ Vg = v + ((size_t)b * C_ + (g << 6)) * (size_t)T_;

  s16x8 kA[16], kB[16];

// fragment f = h*2+kf -> col = f*32 (+quad*8 already in Kbase)
#define PREFETCH(KR, c)                                                        \
  {                                                                            \
    const u16* p = Kbase + (size_t)((tq << 9) + ((c) << 7) + (win << 5)) * C_; \
    _Pragma("unroll") for (int f = 0; f < 16; ++f) KR[f] =                     \
        *(const s16x8*)(p + (f << 5));                                         \
  }

#define QK_CHUNK(KR, c)                                                       \
  {                                                                           \
    f32x4 m[8] = {};                                                          \
    _Pragma("unroll") for (int h = 0; h < 8; ++h) {                           \
      const s16x8 qf0 = *(const s16x8*)(Qrow + (h << 6));                     \
      const s16x8 qf1 = *(const s16x8*)(Qrow + (h << 6) + 32);                \
      f32x4 a0 = {0.f, 0.f, 0.f, 0.f};                                        \
      a0 = mfma16(KR[2 * h], qf0, a0);                                        \
      a0 = mfma16(KR[2 * h + 1], qf1, a0);                                    \
      _Pragma("unroll") for (int gg = 0; gg < 8; ++gg) {                      \
        const float wgh = wh[(gg << 3) + h];                                  \
        m[gg] += a0 * wgh;                                                    \
      }                                                                       \
    }                                                                         \
    _Pragma("unroll") for (int gg = 0; gg < 8; ++gg) {                        \
      f32x4 e0;                                                               \
      _Pragma("unroll") for (int k = 0; k < 4; ++k) e0[k] = __expf(m[gg][k]); \
      u16x4 o;                                                                \
      _Pragma("unroll") for (int k = 0; k < 4; ++k) o[k] = f2bf(e0[k]);       \
      *(u16x4*)&Plds[gg][lr][(win << 5) + (quad << 3) + (half << 2)] = o;     \
      lacc[gg] += e0[0] + e0[1] + e0[2] + e0[3];                              \
      l2acc[gg] += e0[0] * e0[0] + e0[1] * e0[1] + e0[2] * e0[2] +            \
                   e0[3] * e0[3];                                             \
    }                                                                         \
  }

#define PV_CHUNK(c)                                                           \
  {                                                                           \
    s16x8 vreg[16];                                                           \
    const u16* vp = Vg + (tq << 9) + ((c) << 7) + (quad << 3);                \
    _Pragma("unroll") for (int tw = 0; tw < 4; ++tw)                          \
        _Pragma("unroll") for (int dj = 0; dj < 4; ++dj)                      \
            vreg[(tw << 2) + dj] = *(const s16x8*)(vp +                       \
                (size_t)((dj << 4) + lr) * T_ + (tw << 5));                   \
    __syncthreads(); /* P ready */                                            \
    _Pragma("unroll") for (int tw = 0; tw < 4; ++tw) {                        \
      const s16x8 pa = *(const s16x8*)&Plds[g][lr][(tw << 5) + (quad << 3)];  \
      _Pragma("unroll") for (int dj = 0; dj < 4; ++dj) acc[dj] =              \
          mfma16(pa, vreg[(tw << 2) + dj], acc[dj]);                          \
    }                                                                         \
    __syncthreads(); /* P consumed */                                         \
  }

  // issue chunk-0 K prefetch, then stage Q tile (16 x 512)
  PREFETCH(kA, 0);
  {
    const u16* Qb = Qt + ((size_t)b * T_ + q0) * C_;
    for (int i = tid; i < 1024; i += 512) {
      const int r = i >> 6, c8 = i & 63;
      *(u16x8*)&Qs[r][c8 << 3] = *(const u16x8*)(Qb + (size_t)r * C_ + (c8 << 3));
    }
  }
  const u16* __restrict__ Qrow = &Qs[lr][quad << 3];

  float lacc[8] = {}, l2acc[8] = {};
  f32x4 acc[4] = {};

  __syncthreads();

#pragma unroll
  for (int cc = 0; cc < 2; ++cc) {
    // chunk 2cc: compute from kA, prefetch 2cc+1 into kB
    PREFETCH(kB, 2 * cc + 1);
    QK_CHUNK(kA, 2 * cc);
    PV_CHUNK(2 * cc);
    // chunk 2cc+1: compute from kB, prefetch 2cc+2 into kA
    if (cc == 0) PREFETCH(kA, 2);
    QK_CHUNK(kB, 2 * cc + 1);
    PV_CHUNK(2 * cc + 1);
  }

  // ---- write raw f32 partial O (normalization happens in combine_o) ----
  const int bg = (b << 3) + g;
  const size_t obase = ((((size_t)(tq << 5) + bg) << 10) + q0) * 64;
#pragma unroll
  for (int dj = 0; dj < 4; ++dj) {
    const int d = (dj << 4) + lr;
#pragma unroll
    for (int r = 0; r < 4; ++r) {
      const int q = (quad << 2) + r;
      Opart[obase + (size_t)q * 64 + d] = acc[dj][r];
    }
  }

  // ---- epilogue: l/l2 reduce (buffers alias Plds), write partials ----
  float* lbuf = Sbuf;          // [8w][8g][16q]  4 KB
  float* l2buf = Sbuf + 1024;  // [8w][8g][16q]  4 KB
#pragma unroll
  for (int gg = 0; gg < 8; ++gg) {
    float l = lacc[gg];
    l += __shfl_xor(l, 16, 64);
    l += __shfl_xor(l, 32, 64);
    float l2 = l2acc[gg];
    l2 += __shfl_xor(l2, 16, 64);
    l2 += __shfl_xor(l2, 32, 64);
    if (quad == 0) {
      lbuf[(w << 7) + (gg << 4) + lr] = l;
      l2buf[(w << 7) + (gg << 4) + lr] = l2;
    }
  }
  __syncthreads();
  if (lane < 16) {  // wave w reduces its own g
    float l = 0.f, l2 = 0.f;
#pragma unroll
    for (int w2 = 0; w2 < 8; ++w2) {
      l += lbuf[(w2 << 7) + (g << 4) + lr];
      l2 += l2buf[(w2 << 7) + (g << 4) + lr];
    }
    const size_t li = (((size_t)(tq << 5) + bg) << 10) + q0 + lr;
    lpart[li] = l;
    l2part[li] = l2;
  }
#undef PREFETCH
#undef QK_CHUNK
#undef PV_CHUNK
}

// ---- combine: O = (sum_tq Opart) / l, l/l2 full sums -> lsum/l2sum ----
__global__ __launch_bounds__(256) void combine_o(
    const float* __restrict__ Opart, const float* __restrict__ lpart,
    const float* __restrict__ l2part, u16* __restrict__ O,
    float* __restrict__ lsum, float* __restrict__ l2sum) {
  const int bg = blockIdx.x;       // [0,32)
  const int qo = blockIdx.y;       // [0,8) q-octant
  const int tid = threadIdx.x;
  const int q = (qo << 7) + (tid >> 1);
  const int d0 = (tid & 1) << 5;
  float l = 0.f, l2 = 0.f;
#pragma unroll
  for (int tq = 0; tq < 2; ++tq) {
    const size_t li = (((size_t)(tq << 5) + bg) << 10) + q;
    l += lpart[li];
    l2 += l2part[li];
  }
  const float linv = 1.f / l;
  if ((tid & 1) == 0) {
    lsum[((size_t)bg << 10) + q] = l;
    l2sum[((size_t)bg << 10) + q] = l2;
  }
  f32x4 a[8] = {};
#pragma unroll
  for (int tq = 0; tq < 2; ++tq) {
    const float* src =
        Opart + ((((size_t)(tq << 5) + bg) << 10) + q) * 64 + d0;
#pragma unroll
    for (int j = 0; j < 8; ++j) a[j] += *(const f32x4*)(src + (j << 2));
  }
  u16* dst = O + (((size_t)bg << 10) + q) * 64 + d0;
#pragma unroll
  for (int j = 0; j < 4; ++j) {
    u16x8 o;
#pragma unroll
    for (int k = 0; k < 4; ++k) {
      o[k] = f2bf(a[2 * j][k] * linv);
      o[k + 4] = f2bf(a[2 * j + 1][k] * linv);
    }
    *(u16x8*)(dst + (j << 3)) = o;
  }
}

// ---- merged: reduce per-q l/l2 -> ab, then bias2 via precomputed ws ----
__global__ __launch_bounds__(256) void stats_k(const float* __restrict__ lsum,
                                               const float* __restrict__ l2sum,
                                               const float* __restrict__ gamma,
                                               const float* __restrict__ beta,
                                               const float* __restrict__ ws,
                                               const float* __restrict__ bp,
                                               const float* __restrict__ vsum,
                                               float* __restrict__ ab,
                                               float* __restrict__ bias2) {
  const int bg = blockIdx.x;
  const int g = bg & 7;
  const int tid = threadIdx.x;
  const f32x4 l = *(const f32x4*)(lsum + ((size_t)bg << 10) + (tid << 2));
  const f32x4 l2 = *(const f32x4*)(l2sum + ((size_t)bg << 10) + (tid << 2));
  float ssq = 0.f;
#pragma unroll
  for (int k = 0; k < 4; ++k) ssq += l2[k] / (l[k] * l[k]);
#pragma unroll
  for (int off = 32; off; off >>= 1) ssq += __shfl_xor(ssq, off, 64);
  __shared__ float red[4];
  __shared__ float bt2s;
  if ((tid & 63) == 0) red[tid >> 6] = ssq;
  __syncthreads();
  if (tid == 0) {
    const float s = red[0] + red[1] + red[2] + red[3];
    const float mean = 0.0009765625f;
    const float var = s * (1.f / 1048576.f) - mean * mean;
    const float al = gamma[g] * rsqrtf(var + EPS_);
    const float bt2 = beta[g] - al * mean;
    ab[bg * 2] = al;
    ab[bg * 2 + 1] = bt2;
    bt2s = bt2;
  }
  __syncthreads();
  const float bt2 = bt2s;
  const float* vs = vsum + (bg << 6);
#pragma unroll
  for (int oo = 0; oo < 2; ++oo) {
    const int o = tid + (oo << 8);
    const float* wr = ws + (o << 6);
    float acc = 0.f;
#pragma unroll
    for (int d = 0; d < 64; d += 4) {
      const float4 vv4 = *(const float4*)(vs + d);
      const float4 ws4 = *(const float4*)(wr + d);
      acc += ws4.x * vv4.x + ws4.y * vv4.y + ws4.z * vv4.z + ws4.w * vv4.w;
    }
    bias2[(bg << 9) + o] = bp[o] + bt2 * acc;
  }
}

// ------- y = al[b,g(t)]*(Mnorm @ Wp^T) + bias2[b][g(t)][o], 64x64 tiles ----
__global__ __launch_bounds__(256) void gemm_proj(const u16* __restrict__ O,
                                                 const u16* __restrict__ wpb,
                                                 const float* __restrict__ ab,
                                                 const float* __restrict__ bias2,
                                                 float* __restrict__ y) {
  const int b = blockIdx.z;
  const int m0 = blockIdx.y << 6;  // o
  const int n0 = blockIdx.x << 6;  // t
  const int gidx = blockIdx.x >> 1;
  const u16* __restrict__ Ob = O + (size_t)b * (8 * T_ * 64);
  __shared__ u16 As[64][72];
  __shared__ u16 Bs[64][72];
  const int tid = threadIdx.x;
  const int w = tid >> 6, lane = tid & 63, lr = lane & 15, lq = lane >> 4;
  const int mw = (w >> 1) << 5, nw = (w & 1) << 5;
  f32x4 acc[2][2] = {};
  for (int k0 = 0; k0 < C_; k0 += 64) {
#pragma unroll
    for (int it = 0; it < 2; ++it) {
      const int e = tid + (it << 8);
      const int r = e >> 3, c8 = e & 7;
      *(u16x8*)&As[r][c8 << 3] =
          *(const u16x8*)(wpb + (size_t)(m0 + r) * C_ + k0 + (c8 << 3));
      const int t = n0 + r;
      const int c = k0 + (c8 << 3);
      *(u16x8*)&Bs[r][c8 << 3] =
          *(const u16x8*)(Ob + (size_t)(t >> 7) * (T_ * 64) +
                          (size_t)(((t & 127) << 3) + (c >> 6)) * 64 + (c & 63));
    }
    __syncthreads();
#pragma unroll
    for (int kf = 0; kf < 2; ++kf) {
      const int ko = (kf << 5) + (lq << 3);
      s16x8 a[2], bb[2];
#pragma unroll
      for (int i = 0; i < 2; ++i) a[i] = *(const s16x8*)&As[mw + (i << 4) + lr][ko];
#pragma unroll
      for (int j = 0; j < 2; ++j) bb[j] = *(const s16x8*)&Bs[nw + (j << 4) + lr][ko];
#pragma unroll
      for (int i = 0; i < 2; ++i)
#pragma unroll
        for (int j = 0; j < 2; ++j) acc[i][j] = mfma16(a[i], bb[j], acc[i][j]);
    }
    __syncthreads();
  }
  const float al = ab[(((b << 3) + gidx) << 1)];
  const float* __restrict__ b2 = bias2 + (((b << 3) + gidx) << 9);
#pragma unroll
  for (int i = 0; i < 2; ++i) {
    const int row = mw + (i << 4) + (lq << 2);
#pragma unroll
    for (int j = 0; j < 2; ++j) {
      const int col = nw + (j << 4) + lr;
#pragma unroll
      for (int r = 0; r < 4; ++r)
        y[(size_t)b * (C_ * (size_t)T_) + (size_t)(m0 + row + r) * T_ + n0 + col] =
            acc[i][j][r] * al + b2[m0 + row + r];
    }
  }
}

extern "C" void kernel_launch(void* const* d_in, const int* in_sizes, int n_in,
                              void* d_out, int out_size, void* d_ws,
                              size_t ws_size, hipStream_t stream) {
  const float* x = (const float*)d_in[0];
  const float* wq = (const float*)d_in[1];
  const float* wk = (const float*)d_in[2];
  const float* wv = (const float*)d_in[3];
  const float* wh = (const float*)d_in[4];
  const float* gm = (const float*)d_in[5];
  const float* bt = (const float*)d_in[6];
  const float* wp = (const float*)d_in[7];
  const float* bp = (const float*)d_in[8];
  float* y = (float*)d_out;
  char* wsb = (char*)d_ws;

  u16* Qt = (u16*)(wsb + QT_OFF);
  u16* Kt = (u16*)(wsb + KT_OFF);
  u16* V = (u16*)(wsb + V_OFF);
  u16* Xt = (u16*)(wsb + XT_OFF);
  u16* Og = (u16*)(wsb + O_OFF);
  float* ab = (float*)(wsb + AB_OFF);
  float* vsum = (float*)(wsb + VSUM_OFF);
  float* bias2 = (float*)(wsb + BIAS2_OFF);
  float* lsum = (float*)(wsb + LSUM_OFF);
  float* l2sum = (float*)(wsb + L2SUM_OFF);
  u16* Wb = (u16*)(wsb + WB_OFF);
  u16* WQb = Wb;
  u16* WKb = Wb + 262144;
  u16* WVb = Wb + 524288;
  u16* WPb = Wb + 786432;
  float* lpart = (float*)(wsb + LP_OFF);
  float* l2part = (float*)(wsb + L2P_OFF);
  float* ws = (float*)(wsb + WS_OFF);
  float* Opart = (float*)(wsb + OP_OFF);

  wcvt<<<dim3(512), 256, 0, stream>>>(wq, wk, wv, wp, Wb);
  transpose_x<<<dim3(16, 8, 4), 256, 0, stream>>>(x, Xt);
  wsum_k<<<dim3(128), 256, 0, stream>>>(wp, ws, vsum);
  gemm_qkt<<<dim3(16, 8, 8), 256, 0, stream>>>(Xt, WQb, WKb, Qt, Kt);
  gemm_v<<<dim3(16, 8, 4), 256, 0, stream>>>(Xt, WVb, V);
  vsum_k<<<dim3(32, 8), 256, 0, stream>>>(V, vsum);
  attn_fused<<<dim3(512), 512, 0, stream>>>(Qt, Kt, V, wh, Opart, lpart,
                                            l2part);
  combine_o<<<dim3(32, 8), 256, 0, stream>>>(Opart, lpart, l2part, Og, lsum,
                                             l2sum);
  stats_k<<<dim3(32), 256, 0, stream>>>(lsum, l2sum, gm, bt, ws, bp, vsum, ab,
                                        bias2);
  gemm_proj<<<dim3(16, 8, 4), 256, 0, stream>>>(Og, WPb, ab, bias2, y);
}

// Round 8
// 189.381 us; speedup vs baseline: 1.1803x; 1.0492x over previous
//
#include <hip/hip_runtime.h>
#include <hip/hip_bf16.h>

#define B_ 4
#define C_ 512
#define T_ 1024
#define SCALE_ 0.125f
#define EPS_ 1e-5f

typedef unsigned short u16;
typedef __attribute__((ext_vector_type(8))) unsigned short u16x8;
typedef __attribute__((ext_vector_type(4))) unsigned short u16x4;
typedef __attribute__((ext_vector_type(8))) short s16x8;
typedef __attribute__((ext_vector_type(4))) float f32x4;

// ws byte offsets (ws is 256 MiB)
#define QT_OFF    (0x0ull)         // bf16 Qt[B][T][C]   4 MB (Q pre-scaled by 1/8)
#define KT_OFF    (0x400000ull)    // bf16 Kt[B][T][C]   4 MB
#define V_OFF     (0x800000ull)    // bf16 V [B][C][T]   4 MB
#define XT_OFF    (0xC00000ull)    // bf16 Xt[B][T][C]   4 MB
#define O_OFF     (0x1000000ull)   // bf16 O[B][8][T][64] 4 MB (normalized, pre-affine)
#define AB_OFF    (0x1410000ull)   // fp32 ab[B][8][2]
#define VSUM_OFF  (0x1420000ull)   // fp32 vsum[B][8][64]
#define BIAS2_OFF (0x1430000ull)   // fp32 bias2[B][8][512]
#define LSUM_OFF  (0x1440000ull)   // fp32 lsum [B*8][1024]  128 KB
#define L2SUM_OFF (0x1460000ull)   // fp32 l2sum[B*8][1024]  128 KB
#define WB_OFF    (0x1480000ull)   // bf16 W[4][512][512]: wq,wk,wv,wp  2 MB
#define LP_OFF    (0x1680000ull)   // fp32 lpart [4][32][1024] 512 KB
#define L2P_OFF   (0x1700000ull)   // fp32 l2part[4][32][1024] 512 KB
#define WS_OFF    (0x1780000ull)   // fp32 ws[512][64] 128 KB
#define OP_OFF    (0x2000000ull)   // fp32 Opart[4][32][1024][64] 32 MB

static __device__ __forceinline__ u16 f2bf(float f) {
  unsigned u = __float_as_uint(f);
  unsigned r = (u + 0x7fff + ((u >> 16) & 1)) >> 16;  // RNE
  return (u16)r;
}
static __device__ __forceinline__ float b2f(u16 x) {
  return __uint_as_float(((unsigned)x) << 16);
}
static __device__ __forceinline__ f32x4 mfma16(s16x8 a, s16x8 b, f32x4 c) {
  return __builtin_amdgcn_mfma_f32_16x16x32_bf16(a, b, c, 0, 0, 0);
}

// ---- prep: blocks [0,512) wcvt; [512,640) wsum+vsum-zero; [640,1152)
// transpose x -> Xt[b][t][c] bf16. Branch is block-uniform. ----
__global__ __launch_bounds__(256) void prep_k(
    const float* __restrict__ x, const float* __restrict__ wq,
    const float* __restrict__ wk, const float* __restrict__ wv,
    const float* __restrict__ wp, u16* __restrict__ wb,
    float* __restrict__ ws, float* __restrict__ vsum, u16* __restrict__ xt) {
  const int id = blockIdx.x;
  const int tid = threadIdx.x;
  __shared__ float Ts[64][65];
  if (id < 512) {  // ---- wcvt: fp32 -> bf16, 4 weight matrices ----
    const int i = (id << 8) + tid;
    const int idx = i << 3;
    const int which = idx >> 18;  // uniform per block
    const int off = idx & 262143;
    const float* s = which == 0 ? wq : which == 1 ? wk : which == 2 ? wv : wp;
    const float4 f0 = *(const float4*)(s + off);
    const float4 f1 = *(const float4*)(s + off + 4);
    u16x8 o;
    o[0] = f2bf(f0.x); o[1] = f2bf(f0.y); o[2] = f2bf(f0.z); o[3] = f2bf(f0.w);
    o[4] = f2bf(f1.x); o[5] = f2bf(f1.y); o[6] = f2bf(f1.z); o[7] = f2bf(f1.w);
    *(u16x8*)(wb + idx) = o;
  } else if (id < 640) {  // ---- ws[o][d] = sum_j wp[o][j*64+d]; zero vsum ----
    const int idx = ((id - 512) << 8) + tid;
    if (id - 512 < 8) vsum[idx] = 0.f;
    const int o = idx >> 6, d = idx & 63;
    float s = 0.f;
#pragma unroll
    for (int j = 0; j < 8; ++j) s += wp[(o << 9) + (j << 6) + d];
    ws[idx] = s;
  } else {  // ---- transpose x[b][c][t] -> Xt[b][t][c] bf16 ----
    const int id3 = id - 640;
    const int b = id3 >> 7, rem = id3 & 127;
    const int t0 = (rem & 15) << 6;
    const int c0 = (rem >> 4) << 6;
    const float* __restrict__ X = x + (size_t)b * (C_ * (size_t)T_);
    u16* __restrict__ Xt = xt + (size_t)b * (T_ * (size_t)C_);
#pragma unroll
    for (int i = 0; i < 4; ++i) {
      const int e = tid + (i << 8);
      const int r = e >> 4, c4 = e & 15;
      const float4 v =
          *(const float4*)(X + (size_t)(c0 + r) * T_ + t0 + (c4 << 2));
      Ts[r][(c4 << 2) + 0] = v.x; Ts[r][(c4 << 2) + 1] = v.y;
      Ts[r][(c4 << 2) + 2] = v.z; Ts[r][(c4 << 2) + 3] = v.w;
    }
    __syncthreads();
#pragma unroll
    for (int i = 0; i < 2; ++i) {
      const int e = tid + (i << 8);
      const int tt = e >> 3, c8 = e & 7;
      u16x8 o;
#pragma unroll
      for (int j = 0; j < 8; ++j) o[j] = f2bf(Ts[(c8 << 3) + j][tt]);
      *(u16x8*)(Xt + (size_t)(t0 + tt) * C_ + c0 + (c8 << 3)) = o;
    }
  }
}

// ---- unified QKV GEMM, 128x128 tiles (m93 geometry: 4 waves, acc[4][4]).
// z<8: Qt/Kt = Xt @ W^T -> [t][o] (Q scaled); z>=8: V = Wv @ Xt^T -> [o][t].
// All operands row-major with ld = C_ = 512. ----
__global__ __launch_bounds__(256) void gemm_qkv(
    const u16* __restrict__ xt, const u16* __restrict__ wqb,
    const u16* __restrict__ wkb, const u16* __restrict__ wvb,
    u16* __restrict__ qto, u16* __restrict__ kto, u16* __restrict__ vout) {
  const int z = blockIdx.z;
  const int tid = threadIdx.x;
  const int w = tid >> 6, lane = tid & 63, lr = lane & 15, lq = lane >> 4;
  const int wm = (w >> 1) << 6, wn = (w & 1) << 6;
  __shared__ u16 As[128][72];
  __shared__ u16 Bs[128][72];
  const u16 *Ag, *Bg;
  u16* Y;
  int m0, n0, ldy;
  float sc = 1.0f;
  if (z < 8) {
    const int which = z >> 2;
    const int b = z & 3;
    Ag = xt + (size_t)b * (T_ * (size_t)C_);
    m0 = blockIdx.x << 7;  // t
    Bg = which ? wkb : wqb;
    n0 = blockIdx.y << 7;  // o
    Y = (which ? kto : qto) + (size_t)b * (T_ * (size_t)C_);
    ldy = C_;
    if (!which) sc = SCALE_;
  } else {
    const int b = z - 8;
    Ag = wvb;
    m0 = blockIdx.y << 7;  // o
    Bg = xt + (size_t)b * (T_ * (size_t)C_);
    n0 = blockIdx.x << 7;  // t
    Y = vout + (size_t)b * (C_ * (size_t)T_);
    ldy = T_;
  }
  f32x4 acc[4][4] = {};
  for (int k0 = 0; k0 < C_; k0 += 64) {
#pragma unroll
    for (int it = 0; it < 4; ++it) {
      const int e = tid + (it << 8);
      const int r = e >> 3, c8 = (e & 7) << 3;
      *(u16x8*)&As[r][c8] =
          *(const u16x8*)(Ag + (size_t)(m0 + r) * C_ + k0 + c8);
      *(u16x8*)&Bs[r][c8] =
          *(const u16x8*)(Bg + (size_t)(n0 + r) * C_ + k0 + c8);
    }
    __syncthreads();
#pragma unroll
    for (int kf = 0; kf < 2; ++kf) {
      const int ko = (kf << 5) + (lq << 3);
      s16x8 a[4], bb[4];
#pragma unroll
      for (int i = 0; i < 4; ++i) a[i] = *(const s16x8*)&As[wm + (i << 4) + lr][ko];
#pragma unroll
      for (int j = 0; j < 4; ++j) bb[j] = *(const s16x8*)&Bs[wn + (j << 4) + lr][ko];
#pragma unroll
      for (int i = 0; i < 4; ++i)
#pragma unroll
        for (int j = 0; j < 4; ++j) acc[i][j] = mfma16(a[i], bb[j], acc[i][j]);
    }
    __syncthreads();
  }
#pragma unroll
  for (int i = 0; i < 4; ++i) {
    const int row = wm + (i << 4) + (lq << 2);
#pragma unroll
    for (int j = 0; j < 4; ++j) {
      const int col = wn + (j << 4) + lr;
#pragma unroll
      for (int r = 0; r < 4; ++r)
        Y[(size_t)(m0 + row + r) * ldy + n0 + col] = f2bf(acc[i][j][r] * sc);
    }
  }
}

// ------ vsum[b][g][d] = sum_t V : grid (32 bg, 8 t-chunks), atomics ------
__global__ __launch_bounds__(256) void vsum_k(const u16* __restrict__ v,
                                              float* __restrict__ vsum) {
  const int bg = blockIdx.x;
  const int tc = blockIdx.y;  // 128-t chunk
  const int tid = threadIdx.x;
  const int d = tid >> 2, part = tid & 3;
  const u16* __restrict__ Vr = v + ((size_t)(bg >> 3) * C_ + ((bg & 7) << 6) + d) * T_ +
                               (tc << 7) + (part << 5);
  float s = 0.f;
#pragma unroll
  for (int t = 0; t < 32; t += 8) {
    const u16x8 x = *(const u16x8*)(Vr + t);
#pragma unroll
    for (int j = 0; j < 8; ++j) s += b2f(x[j]);
  }
  s += __shfl_down(s, 2, 64);
  s += __shfl_down(s, 1, 64);
  if (part == 0) atomicAdd(&vsum[(bg << 6) + d], s);
}

// ---- FUSED attention (R6 best-measured version, 74.4us): T-SPLIT grid
// 1024 = (b, qb, tq). Each block: one q16-tile x one 256-t quarter (2
// chunks of 128), wave-pair QK (even wave = K0 half, odd = +4 half; m[8] =
// 32 VGPRs, all 8 heads, single pass). ~51.5 KB LDS -> 3 blocks/CU.
// Raw f32 partial-O + partial l/l2, combined by combine_o. ----
__global__ __launch_bounds__(512, 4) void attn_fused(
    const u16* __restrict__ Qt, const u16* __restrict__ Kt,
    const u16* __restrict__ v, const float* __restrict__ wh,
    float* __restrict__ Opart, float* __restrict__ lpart,
    float* __restrict__ l2part) {
  const int id = blockIdx.x;
  const int xcd = id & 7;
  const int b = xcd >> 1;
  const int hi = id >> 3;                       // [0,128)
  const int qb = ((xcd & 1) << 5) | (hi & 31);  // [0,64)
  const int tq = hi >> 5;                       // [0,4) t-quarter
  const int q0 = qb << 4;
  const int tid = threadIdx.x;
  const int w = tid >> 6, lane = tid & 63;
  const int lr = lane & 15, quad = lane >> 4;

  __shared__ __align__(16) u16 Qs[16][522];       // 16704 B
  __shared__ __align__(16) u16 Plds[8][16][136];  // 34816 B
  float* Sbuf = (float*)&Plds[0][0][0];  // epilogue alias (Plds dead by then)

  {  // stage Q tile (16 x 512)
    const u16* Qb = Qt + ((size_t)b * T_ + q0) * C_;
    for (int i = tid; i < 1024; i += 512) {
      const int r = i >> 6, c8 = i & 63;
      *(u16x8*)&Qs[r][c8 << 3] = *(const u16x8*)(Qb + (size_t)r * C_ + (c8 << 3));
    }
  }

  const int tp = ((lr >> 2) << 3) + (lr & 3);  // permuted K row (validated)
  const u16* __restrict__ Qrow = &Qs[lr][quad << 3];
  const int g = w;  // PV head owned by this wave
  const int win = w >> 1, half = w & 1;  // QK: window pair, K-half
  const u16* __restrict__ Vg = v + ((size_t)b * C_ + (g << 6)) * (size_t)T_;

  float lacc[8] = {}, l2acc[8] = {};
  f32x4 acc[4] = {};

  __syncthreads();

  for (int c = 0; c < 2; ++c) {
    // ---- QK + mix + exp: this wave's 16 (permuted) t-rows of window ----
    const int tbase = (tq << 8) + (c << 7) + (win << 5);
    const u16* __restrict__ K0 =
        Kt + ((size_t)b * T_ + tbase + tp + (half << 2)) * C_ + (quad << 3);
    f32x4 m[8] = {};
#pragma unroll 2
    for (int h = 0; h < 8; ++h) {
      f32x4 a0 = {0.f, 0.f, 0.f, 0.f};
#pragma unroll
      for (int kf = 0; kf < 2; ++kf) {
        const int co = (h << 6) + (kf << 5);
        const s16x8 qf = *(const s16x8*)(Qrow + co);
        const s16x8 k0 = *(const s16x8*)(K0 + co);
        a0 = mfma16(k0, qf, a0);
      }
#pragma unroll
      for (int gg = 0; gg < 8; ++gg) {
        const float wgh = wh[(gg << 3) + h];  // uniform -> SGPR
        m[gg] += a0 * wgh;
      }
    }
    // lane's t slots: win*32 + quad*8 + half*4 + {0..3}; q = lr
#pragma unroll
    for (int gg = 0; gg < 8; ++gg) {
      f32x4 e0;
#pragma unroll
      for (int k = 0; k < 4; ++k) e0[k] = __expf(m[gg][k]);
      u16x4 o;
#pragma unroll
      for (int k = 0; k < 4; ++k) o[k] = f2bf(e0[k]);
      *(u16x4*)&Plds[gg][lr][(win << 5) + (quad << 3) + (half << 2)] = o;
      lacc[gg] += e0[0] + e0[1] + e0[2] + e0[3];
      l2acc[gg] += e0[0] * e0[0] + e0[1] * e0[1] + e0[2] * e0[2] + e0[3] * e0[3];
    }
    __syncthreads();  // P ready
    // ---- PV: this wave's g over the whole 128-t chunk ----
#pragma unroll
    for (int tw = 0; tw < 4; ++tw) {
      const s16x8 pa = *(const s16x8*)&Plds[g][lr][(tw << 5) + (quad << 3)];
#pragma unroll
      for (int dj = 0; dj < 4; ++dj) {
        const s16x8 vb =
            *(const s16x8*)(Vg + (size_t)((dj << 4) + lr) * T_ + (tq << 8) +
                            (c << 7) + (tw << 5) + (quad << 3));
        acc[dj] = mfma16(pa, vb, acc[dj]);
      }
    }
    __syncthreads();  // P consumed, safe to overwrite next chunk
  }

  // ---- write raw f32 partial O (normalization happens in combine_o) ----
  const int bg = (b << 3) + g;
  const size_t obase = ((((size_t)(tq << 5) + bg) << 10) + q0) * 64;
#pragma unroll
  for (int dj = 0; dj < 4; ++dj) {
    const int d = (dj << 4) + lr;
#pragma unroll
    for (int r = 0; r < 4; ++r) {
      const int q = (quad << 2) + r;
      Opart[obase + (size_t)q * 64 + d] = acc[dj][r];
    }
  }

  // ---- epilogue: l/l2 reduce (buffers alias Plds), write partials ----
  float* lbuf = Sbuf;          // [8w][8g][16q]  4 KB
  float* l2buf = Sbuf + 1024;  // [8w][8g][16q]  4 KB
#pragma unroll
  for (int gg = 0; gg < 8; ++gg) {
    float l = lacc[gg];
    l += __shfl_xor(l, 16, 64);
    l += __shfl_xor(l, 32, 64);
    float l2 = l2acc[gg];
    l2 += __shfl_xor(l2, 16, 64);
    l2 += __shfl_xor(l2, 32, 64);
    if (quad == 0) {
      lbuf[(w << 7) + (gg << 4) + lr] = l;
      l2buf[(w << 7) + (gg << 4) + lr] = l2;
    }
  }
  __syncthreads();
  if (lane < 16) {  // wave w reduces its own g
    float l = 0.f, l2 = 0.f;
#pragma unroll
    for (int w2 = 0; w2 < 8; ++w2) {
      l += lbuf[(w2 << 7) + (g << 4) + lr];
      l2 += l2buf[(w2 << 7) + (g << 4) + lr];
    }
    const size_t li = (((size_t)(tq << 5) + bg) << 10) + q0 + lr;
    lpart[li] = l;
    l2part[li] = l2;
  }
}

// ---- combine: O = (sum_tq Opart) / l, l/l2 full sums -> lsum/l2sum ----
__global__ __launch_bounds__(256) void combine_o(
    const float* __restrict__ Opart, const float* __restrict__ lpart,
    const float* __restrict__ l2part, u16* __restrict__ O,
    float* __restrict__ lsum, float* __restrict__ l2sum) {
  const int bg = blockIdx.x;       // [0,32)
  const int qo = blockIdx.y;       // [0,8) q-octant
  const int tid = threadIdx.x;
  const int q = (qo << 7) + (tid >> 1);
  const int d0 = (tid & 1) << 5;
  float l = 0.f, l2 = 0.f;
#pragma unroll
  for (int tq = 0; tq < 4; ++tq) {
    const size_t li = (((size_t)(tq << 5) + bg) << 10) + q;
    l += lpart[li];
    l2 += l2part[li];
  }
  const float linv = 1.f / l;
  if ((tid & 1) == 0) {
    lsum[((size_t)bg << 10) + q] = l;
    l2sum[((size_t)bg << 10) + q] = l2;
  }
  f32x4 a[8] = {};
#pragma unroll
  for (int tq = 0; tq < 4; ++tq) {
    const float* src =
        Opart + ((((size_t)(tq << 5) + bg) << 10) + q) * 64 + d0;
#pragma unroll
    for (int j = 0; j < 8; ++j) a[j] += *(const f32x4*)(src + (j << 2));
  }
  u16* dst = O + (((size_t)bg << 10) + q) * 64 + d0;
#pragma unroll
  for (int j = 0; j < 4; ++j) {
    u16x8 o;
#pragma unroll
    for (int k = 0; k < 4; ++k) {
      o[k] = f2bf(a[2 * j][k] * linv);
      o[k + 4] = f2bf(a[2 * j + 1][k] * linv);
    }
    *(u16x8*)(dst + (j << 3)) = o;
  }
}

// ---- merged: reduce per-q l/l2 -> ab, then bias2 via precomputed ws ----
__global__ __launch_bounds__(256) void stats_k(const float* __restrict__ lsum,
                                               const float* __restrict__ l2sum,
                                               const float* __restrict__ gamma,
                                               const float* __restrict__ beta,
                                               const float* __restrict__ ws,
                                               const float* __restrict__ bp,
                                               const float* __restrict__ vsum,
                                               float* __restrict__ ab,
                                               float* __restrict__ bias2) {
  const int bg = blockIdx.x;
  const int g = bg & 7;
  const int tid = threadIdx.x;
  const f32x4 l = *(const f32x4*)(lsum + ((size_t)bg << 10) + (tid << 2));
  const f32x4 l2 = *(const f32x4*)(l2sum + ((size_t)bg << 10) + (tid << 2));
  float ssq = 0.f;
#pragma unroll
  for (int k = 0; k < 4; ++k) ssq += l2[k] / (l[k] * l[k]);
#pragma unroll
  for (int off = 32; off; off >>= 1) ssq += __shfl_xor(ssq, off, 64);
  __shared__ float red[4];
  __shared__ float bt2s;
  if ((tid & 63) == 0) red[tid >> 6] = ssq;
  __syncthreads();
  if (tid == 0) {
    const float s = red[0] + red[1] + red[2] + red[3];
    const float mean = 0.0009765625f;
    const float var = s * (1.f / 1048576.f) - mean * mean;
    const float al = gamma[g] * rsqrtf(var + EPS_);
    const float bt2 = beta[g] - al * mean;
    ab[bg * 2] = al;
    ab[bg * 2 + 1] = bt2;
    bt2s = bt2;
  }
  __syncthreads();
  const float bt2 = bt2s;
  const float* vs = vsum + (bg << 6);
#pragma unroll
  for (int oo = 0; oo < 2; ++oo) {
    const int o = tid + (oo << 8);
    const float* wr = ws + (o << 6);
    float acc = 0.f;
#pragma unroll
    for (int d = 0; d < 64; d += 4) {
      const float4 vv4 = *(const float4*)(vs + d);
      const float4 ws4 = *(const float4*)(wr + d);
      acc += ws4.x * vv4.x + ws4.y * vv4.y + ws4.z * vv4.z + ws4.w * vv4.w;
    }
    bias2[(bg << 9) + o] = bp[o] + bt2 * acc;
  }
}

// ------- y = al[b,g(t)]*(Onorm @ Wp^T) + bias2[b][g(t)][o], 128x128 ----
__global__ __launch_bounds__(256) void gemm_proj(const u16* __restrict__ O,
                                                 const u16* __restrict__ wpb,
                                                 const float* __restrict__ ab,
                                                 const float* __restrict__ bias2,
                                                 float* __restrict__ y) {
  const int b = blockIdx.z;
  const int m0 = blockIdx.y << 7;  // o: 4 tiles
  const int n0 = blockIdx.x << 7;  // t: 8 tiles (tile == head g)
  const int g = blockIdx.x;
  const u16* __restrict__ Ob = O + (size_t)b * (8 * T_ * 64);
  __shared__ u16 As[128][72];
  __shared__ u16 Bs[128][72];
  const int tid = threadIdx.x;
  const int w = tid >> 6, lane = tid & 63, lr = lane & 15, lq = lane >> 4;
  const int wm = (w >> 1) << 6, wn = (w & 1) << 6;
  f32x4 acc[4][4] = {};
  for (int k0 = 0; k0 < C_; k0 += 64) {
#pragma unroll
    for (int it = 0; it < 4; ++it) {
      const int e = tid + (it << 8);
      const int r = e >> 3, c8 = (e & 7) << 3;
      *(u16x8*)&As[r][c8] =
          *(const u16x8*)(wpb + (size_t)(m0 + r) * C_ + k0 + c8);
      const int t = n0 + r;
      const int c = k0 + c8;
      *(u16x8*)&Bs[r][c8] =
          *(const u16x8*)(Ob + (size_t)(t >> 7) * (T_ * 64) +
                          (size_t)(((t & 127) << 3) + (c >> 6)) * 64 + (c & 63));
    }
    __syncthreads();
#pragma unroll
    for (int kf = 0; kf < 2; ++kf) {
      const int ko = (kf << 5) + (lq << 3);
      s16x8 a[4], bb[4];
#pragma unroll
      for (int i = 0; i < 4; ++i) a[i] = *(const s16x8*)&As[wm + (i << 4) + lr][ko];
#pragma unroll
      for (int j = 0; j < 4; ++j) bb[j] = *(const s16x8*)&Bs[wn + (j << 4) + lr][ko];
#pragma unroll
      for (int i = 0; i < 4; ++i)
#pragma unroll
        for (int j = 0; j < 4; ++j) acc[i][j] = mfma16(a[i], bb[j], acc[i][j]);
    }
    __syncthreads();
  }
  const float al = ab[(((b << 3) + g) << 1)];
  const float* __restrict__ b2 = bias2 + (((b << 3) + g) << 9);
#pragma unroll
  for (int i = 0; i < 4; ++i) {
    const int row = wm + (i << 4) + (lq << 2);
#pragma unroll
    for (int j = 0; j < 4; ++j) {
      const int col = wn + (j << 4) + lr;
#pragma unroll
      for (int r = 0; r < 4; ++r)
        y[(size_t)b * (C_ * (size_t)T_) + (size_t)(m0 + row + r) * T_ + n0 + col] =
            acc[i][j][r] * al + b2[m0 + row + r];
    }
  }
}

extern "C" void kernel_launch(void* const* d_in, const int* in_sizes, int n_in,
                              void* d_out, int out_size, void* d_ws,
                              size_t ws_size, hipStream_t stream) {
  const float* x = (const float*)d_in[0];
  const float* wq = (const float*)d_in[1];
  const float* wk = (const float*)d_in[2];
  const float* wv = (const float*)d_in[3];
  const float* wh = (const float*)d_in[4];
  const float* gm = (const float*)d_in[5];
  const float* bt = (const float*)d_in[6];
  const float* wp = (const float*)d_in[7];
  const float* bp = (const float*)d_in[8];
  float* y = (float*)d_out;
  char* wsb = (char*)d_ws;

  u16* Qt = (u16*)(wsb + QT_OFF);
  u16* Kt = (u16*)(wsb + KT_OFF);
  u16* V = (u16*)(wsb + V_OFF);
  u16* Xt = (u16*)(wsb + XT_OFF);
  u16* Og = (u16*)(wsb + O_OFF);
  float* ab = (float*)(wsb + AB_OFF);
  float* vsum = (float*)(wsb + VSUM_OFF);
  float* bias2 = (float*)(wsb + BIAS2_OFF);
  float* lsum = (float*)(wsb + LSUM_OFF);
  float* l2sum = (float*)(wsb + L2SUM_OFF);
  u16* Wb = (u16*)(wsb + WB_OFF);
  u16* WQb = Wb;
  u16* WKb = Wb + 262144;
  u16* WVb = Wb + 524288;
  u16* WPb = Wb + 786432;
  float* lpart = (float*)(wsb + LP_OFF);
  float* l2part = (float*)(wsb + L2P_OFF);
  float* ws = (float*)(wsb + WS_OFF);
  float* Opart = (float*)(wsb + OP_OFF);

  prep_k<<<dim3(1152), 256, 0, stream>>>(x, wq, wk, wv, wp, Wb, ws, vsum, Xt);
  gemm_qkv<<<dim3(8, 4, 12), 256, 0, stream>>>(Xt, WQb, WKb, WVb, Qt, Kt, V);
  vsum_k<<<dim3(32, 8), 256, 0, stream>>>(V, vsum);
  attn_fused<<<dim3(1024), 512, 0, stream>>>(Qt, Kt, V, wh, Opart, lpart,
                                             l2part);
  combine_o<<<dim3(32, 8), 256, 0, stream>>>(Opart, lpart, l2part, Og, lsum,
                                             l2sum);
  stats_k<<<dim3(32), 256, 0, stream>>>(lsum, l2sum, gm, bt, ws, bp, vsum, ab,
                                        bias2);
  gemm_proj<<<dim3(8, 4, 4), 256, 0, stream>>>(Og, WPb, ab, bias2, y);
}

// Round 9
// 169.945 us; speedup vs baseline: 1.3152x; 1.1144x over previous
//
#include <hip/hip_runtime.h>
#include <hip/hip_bf16.h>

#define B_ 4
#define C_ 512
#define T_ 1024
#define SCALE_ 0.125f
#define EPS_ 1e-5f

typedef unsigned short u16;
typedef __attribute__((ext_vector_type(8))) unsigned short u16x8;
typedef __attribute__((ext_vector_type(4))) unsigned short u16x4;
typedef __attribute__((ext_vector_type(8))) short s16x8;
typedef __attribute__((ext_vector_type(4))) float f32x4;

// ws byte offsets (ws is 256 MiB)
#define QT_OFF    (0x0ull)         // bf16 Qt[B][T][C]   4 MB (Q pre-scaled by 1/8)
#define KS_OFF    (0x400000ull)    // bf16 KS swizzled [B][t32][half][f][lane][8] 4 MB
#define VS_OFF    (0x800000ull)    // bf16 VS swizzled [B][g][t32][dj][lane][8]   4 MB
#define XT_OFF    (0xC00000ull)    // bf16 Xt[B][T][C]   4 MB
#define O_OFF     (0x1000000ull)   // bf16 O[B][8][T][64] 4 MB (normalized, pre-affine)
#define AB_OFF    (0x1410000ull)   // fp32 ab[B][8][2]
#define VSUM_OFF  (0x1420000ull)   // fp32 vsum[B][8][64]
#define BIAS2_OFF (0x1430000ull)   // fp32 bias2[B][8][512]
#define LSUM_OFF  (0x1440000ull)   // fp32 lsum [B*8][1024]  128 KB
#define L2SUM_OFF (0x1460000ull)   // fp32 l2sum[B*8][1024]  128 KB
#define WB_OFF    (0x1480000ull)   // bf16 W[4][512][512]: wq,wk,wv,wp  2 MB
#define LP_OFF    (0x1680000ull)   // fp32 lpart [4][32][1024] 512 KB
#define L2P_OFF   (0x1700000ull)   // fp32 l2part[4][32][1024] 512 KB
#define WS_OFF    (0x1780000ull)   // fp32 ws[512][64] 128 KB
#define OP_OFF    (0x2000000ull)   // fp32 Opart[4][32][1024][64] 32 MB

static __device__ __forceinline__ u16 f2bf(float f) {
  unsigned u = __float_as_uint(f);
  unsigned r = (u + 0x7fff + ((u >> 16) & 1)) >> 16;  // RNE
  return (u16)r;
}
static __device__ __forceinline__ float b2f(u16 x) {
  return __uint_as_float(((unsigned)x) << 16);
}
static __device__ __forceinline__ f32x4 mfma16(s16x8 a, s16x8 b, f32x4 c) {
  return __builtin_amdgcn_mfma_f32_16x16x32_bf16(a, b, c, 0, 0, 0);
}

// ---- prep: blocks [0,512) wcvt; [512,640) wsum+vsum-zero; [640,1152)
// transpose x -> Xt[b][t][c] bf16. Branch is block-uniform. ----
__global__ __launch_bounds__(256) void prep_k(
    const float* __restrict__ x, const float* __restrict__ wq,
    const float* __restrict__ wk, const float* __restrict__ wv,
    const float* __restrict__ wp, u16* __restrict__ wb,
    float* __restrict__ ws, float* __restrict__ vsum, u16* __restrict__ xt) {
  const int id = blockIdx.x;
  const int tid = threadIdx.x;
  __shared__ float Ts[64][65];
  if (id < 512) {  // ---- wcvt: fp32 -> bf16, 4 weight matrices ----
    const int i = (id << 8) + tid;
    const int idx = i << 3;
    const int which = idx >> 18;  // uniform per block
    const int off = idx & 262143;
    const float* s = which == 0 ? wq : which == 1 ? wk : which == 2 ? wv : wp;
    const float4 f0 = *(const float4*)(s + off);
    const float4 f1 = *(const float4*)(s + off + 4);
    u16x8 o;
    o[0] = f2bf(f0.x); o[1] = f2bf(f0.y); o[2] = f2bf(f0.z); o[3] = f2bf(f0.w);
    o[4] = f2bf(f1.x); o[5] = f2bf(f1.y); o[6] = f2bf(f1.z); o[7] = f2bf(f1.w);
    *(u16x8*)(wb + idx) = o;
  } else if (id < 640) {  // ---- ws[o][d] = sum_j wp[o][j*64+d]; zero vsum ----
    const int idx = ((id - 512) << 8) + tid;
    if (id - 512 < 8) vsum[idx] = 0.f;
    const int o = idx >> 6, d = idx & 63;
    float s = 0.f;
#pragma unroll
    for (int j = 0; j < 8; ++j) s += wp[(o << 9) + (j << 6) + d];
    ws[idx] = s;
  } else {  // ---- transpose x[b][c][t] -> Xt[b][t][c] bf16 ----
    const int id3 = id - 640;
    const int b = id3 >> 7, rem = id3 & 127;
    const int t0 = (rem & 15) << 6;
    const int c0 = (rem >> 4) << 6;
    const float* __restrict__ X = x + (size_t)b * (C_ * (size_t)T_);
    u16* __restrict__ Xt = xt + (size_t)b * (T_ * (size_t)C_);
#pragma unroll
    for (int i = 0; i < 4; ++i) {
      const int e = tid + (i << 8);
      const int r = e >> 4, c4 = e & 15;
      const float4 v =
          *(const float4*)(X + (size_t)(c0 + r) * T_ + t0 + (c4 << 2));
      Ts[r][(c4 << 2) + 0] = v.x; Ts[r][(c4 << 2) + 1] = v.y;
      Ts[r][(c4 << 2) + 2] = v.z; Ts[r][(c4 << 2) + 3] = v.w;
    }
    __syncthreads();
#pragma unroll
    for (int i = 0; i < 2; ++i) {
      const int e = tid + (i << 8);
      const int tt = e >> 3, c8 = e & 7;
      u16x8 o;
#pragma unroll
      for (int j = 0; j < 8; ++j) o[j] = f2bf(Ts[(c8 << 3) + j][tt]);
      *(u16x8*)(Xt + (size_t)(t0 + tt) * C_ + c0 + (c8 << 3)) = o;
    }
  }
}

// ---- unified QKV GEMM, 128x128 tiles. z<4: Q -> Qt[t][o] (scaled).
// z in [4,8): K -> KS SWIZZLED fragment layout [b][t32][half][f][lane][8]
// (tp row-perm baked in) so attn K loads are lane-contiguous 1KB bursts.
// z>=8: V -> VS SWIZZLED [b][g][t32][dj][lane][8] for the same reason. ----
__global__ __launch_bounds__(256) void gemm_qkv(
    const u16* __restrict__ xt, const u16* __restrict__ wqb,
    const u16* __restrict__ wkb, const u16* __restrict__ wvb,
    u16* __restrict__ qto, u16* __restrict__ ks, u16* __restrict__ vs) {
  const int z = blockIdx.z;
  const int tid = threadIdx.x;
  const int w = tid >> 6, lane = tid & 63, lr = lane & 15, lq = lane >> 4;
  const int wm = (w >> 1) << 6, wn = (w & 1) << 6;
  __shared__ u16 As[128][72];
  __shared__ u16 Bs[128][72];
  const u16 *Ag, *Bg;
  int m0, n0, mode, b;
  if (z < 8) {
    const int which = z >> 2;
    b = z & 3;
    Ag = xt + (size_t)b * (T_ * (size_t)C_);
    m0 = blockIdx.x << 7;  // t
    Bg = which ? wkb : wqb;
    n0 = blockIdx.y << 7;  // o
    mode = which;          // 0 = Q, 1 = K
  } else {
    b = z - 8;
    Ag = wvb;
    m0 = blockIdx.y << 7;  // o
    Bg = xt + (size_t)b * (T_ * (size_t)C_);
    n0 = blockIdx.x << 7;  // t
    mode = 2;
  }
  f32x4 acc[4][4] = {};
  for (int k0 = 0; k0 < C_; k0 += 64) {
#pragma unroll
    for (int it = 0; it < 4; ++it) {
      const int e = tid + (it << 8);
      const int r = e >> 3, c8 = (e & 7) << 3;
      *(u16x8*)&As[r][c8] =
          *(const u16x8*)(Ag + (size_t)(m0 + r) * C_ + k0 + c8);
      *(u16x8*)&Bs[r][c8] =
          *(const u16x8*)(Bg + (size_t)(n0 + r) * C_ + k0 + c8);
    }
    __syncthreads();
#pragma unroll
    for (int kf = 0; kf < 2; ++kf) {
      const int ko = (kf << 5) + (lq << 3);
      s16x8 a[4], bb[4];
#pragma unroll
      for (int i = 0; i < 4; ++i) a[i] = *(const s16x8*)&As[wm + (i << 4) + lr][ko];
#pragma unroll
      for (int j = 0; j < 4; ++j) bb[j] = *(const s16x8*)&Bs[wn + (j << 4) + lr][ko];
#pragma unroll
      for (int i = 0; i < 4; ++i)
#pragma unroll
        for (int j = 0; j < 4; ++j) acc[i][j] = mfma16(a[i], bb[j], acc[i][j]);
    }
    __syncthreads();
  }
  if (mode == 0) {
    u16* Y = qto + (size_t)b * (T_ * (size_t)C_);
#pragma unroll
    for (int i = 0; i < 4; ++i) {
      const int row = wm + (i << 4) + (lq << 2);
#pragma unroll
      for (int j = 0; j < 4; ++j) {
        const int col = wn + (j << 4) + lr;
#pragma unroll
        for (int r = 0; r < 4; ++r)
          Y[(size_t)(m0 + row + r) * C_ + n0 + col] =
              f2bf(acc[i][j][r] * SCALE_);
      }
    }
  } else if (mode == 1) {
    // K swizzle: t -> (t32, half, lrk); o -> (f, quadk, e)
#pragma unroll
    for (int i = 0; i < 4; ++i) {
#pragma unroll
      for (int j = 0; j < 4; ++j) {
        const int o = n0 + wn + (j << 4) + lr;
        const int f = o >> 5, quadk = (o >> 3) & 3, e = o & 7;
#pragma unroll
        for (int r = 0; r < 4; ++r) {
          const int t = m0 + wm + (i << 4) + (lq << 2) + r;
          const int t32 = t >> 5, rr = t & 31;
          const int half = (rr >> 2) & 1;
          const int lrk = ((rr >> 3) << 2) | (rr & 3);
          const size_t idx =
              ((((size_t)((((b << 5) | t32) << 1) | half) << 4 | f) << 6 |
                (quadk << 4) | lrk)
               << 3) |
              e;
          ks[idx] = f2bf(acc[i][j][r]);
        }
      }
    }
  } else {
    // V swizzle: o -> (g, dj, lrv); t -> (t32, quadv, e)
#pragma unroll
    for (int i = 0; i < 4; ++i) {
#pragma unroll
      for (int j = 0; j < 4; ++j) {
        const int t = n0 + wn + (j << 4) + lr;
        const int t32 = t >> 5, quadv = (t >> 3) & 3, e = t & 7;
#pragma unroll
        for (int r = 0; r < 4; ++r) {
          const int o = m0 + wm + (i << 4) + (lq << 2) + r;
          const int g = o >> 6, dj = (o >> 4) & 3, lrv = o & 15;
          const size_t idx =
              ((((size_t)((((b << 3) | g) << 5) | t32) << 2 | dj) << 6 |
                (quadv << 4) | lrv)
               << 3) |
              e;
          vs[idx] = f2bf(acc[i][j][r]);
        }
      }
    }
  }
}

// ------ vsum[b][g][d] = sum_t V, reading swizzled VS; atomics ------
__global__ __launch_bounds__(256) void vsum_k(const u16* __restrict__ vs,
                                              float* __restrict__ vsum) {
  const int bg = blockIdx.x;
  const int tcb = blockIdx.y;  // 4 t32-values per block
  const int tid = threadIdx.x;
  const int d = tid >> 2, part = tid & 3;
  const int dj = d >> 4, lrv = d & 15;
  const int t32 = (tcb << 2) + part;
  const u16* __restrict__ p = vs + (((size_t)bg) << 16) + ((size_t)t32 << 11) +
                              (dj << 9) + (lrv << 3);
  float s = 0.f;
#pragma unroll
  for (int q = 0; q < 4; ++q) {
    const u16x8 x = *(const u16x8*)(p + (q << 7));
#pragma unroll
    for (int j = 0; j < 8; ++j) s += b2f(x[j]);
  }
  s += __shfl_down(s, 2, 64);
  s += __shfl_down(s, 1, 64);
  if (part == 0) atomicAdd(&vsum[(bg << 6) + d], s);
}

// ---- FUSED attention (R8 structure; K/V now read from SWIZZLED global
// layouts -> every K/V load is a lane-contiguous 1KB burst instead of 16
// scattered 64B rows). T-SPLIT grid 1024 = (b, qb, tq); 512 thr; 2 chunks
// of 128 t; wave-pair QK; m[8]=32 VGPRs; ~51.5KB LDS -> 3 blocks/CU. ----
__global__ __launch_bounds__(512, 4) void attn_fused(
    const u16* __restrict__ Qt, const u16* __restrict__ KS,
    const u16* __restrict__ VS, const float* __restrict__ wh,
    float* __restrict__ Opart, float* __restrict__ lpart,
    float* __restrict__ l2part) {
  const int id = blockIdx.x;
  const int xcd = id & 7;
  const int b = xcd >> 1;
  const int hi = id >> 3;                       // [0,128)
  const int qb = ((xcd & 1) << 5) | (hi & 31);  // [0,64)
  const int tq = hi >> 5;                       // [0,4) t-quarter
  const int q0 = qb << 4;
  const int tid = threadIdx.x;
  const int w = tid >> 6, lane = tid & 63;
  const int lr = lane & 15, quad = lane >> 4;

  __shared__ __align__(16) u16 Qs[16][522];       // 16704 B
  __shared__ __align__(16) u16 Plds[8][16][136];  // 34816 B
  float* Sbuf = (float*)&Plds[0][0][0];  // epilogue alias (Plds dead by then)

  {  // stage Q tile (16 x 512)
    const u16* Qb = Qt + ((size_t)b * T_ + q0) * C_;
    for (int i = tid; i < 1024; i += 512) {
      const int r = i >> 6, c8 = i & 63;
      *(u16x8*)&Qs[r][c8 << 3] = *(const u16x8*)(Qb + (size_t)r * C_ + (c8 << 3));
    }
  }

  const u16* __restrict__ Qrow = &Qs[lr][quad << 3];
  const int g = w;  // PV head owned by this wave
  const int win = w >> 1, half = w & 1;  // QK: window pair, K-half
  const u16* __restrict__ Vc =
      VS + (((size_t)((b << 3) | g)) << 16) + (lane << 3);

  float lacc[8] = {}, l2acc[8] = {};
  f32x4 acc[4] = {};

  __syncthreads();

  for (int c = 0; c < 2; ++c) {
    // ---- QK + mix + exp: K loads lane-contiguous from KS ----
    const int t32k = (tq << 3) + (c << 2) + win;
    const u16* __restrict__ Kc =
        KS + (((size_t)((((b << 5) | t32k) << 1) | half)) << 13) + (lane << 3);
    f32x4 m[8] = {};
#pragma unroll 2
    for (int h = 0; h < 8; ++h) {
      f32x4 a0 = {0.f, 0.f, 0.f, 0.f};
      const s16x8 qf0 = *(const s16x8*)(Qrow + (h << 6));
      const s16x8 k0 = *(const s16x8*)(Kc + (h << 10));
      a0 = mfma16(k0, qf0, a0);
      const s16x8 qf1 = *(const s16x8*)(Qrow + (h << 6) + 32);
      const s16x8 k1 = *(const s16x8*)(Kc + (h << 10) + 512);
      a0 = mfma16(k1, qf1, a0);
#pragma unroll
      for (int gg = 0; gg < 8; ++gg) {
        const float wgh = wh[(gg << 3) + h];  // uniform -> SGPR
        m[gg] += a0 * wgh;
      }
    }
    // lane's t slots: win*32 + quad*8 + half*4 + {0..3}; q = lr
#pragma unroll
    for (int gg = 0; gg < 8; ++gg) {
      f32x4 e0;
#pragma unroll
      for (int k = 0; k < 4; ++k) e0[k] = __expf(m[gg][k]);
      u16x4 o;
#pragma unroll
      for (int k = 0; k < 4; ++k) o[k] = f2bf(e0[k]);
      *(u16x4*)&Plds[gg][lr][(win << 5) + (quad << 3) + (half << 2)] = o;
      lacc[gg] += e0[0] + e0[1] + e0[2] + e0[3];
      l2acc[gg] += e0[0] * e0[0] + e0[1] * e0[1] + e0[2] * e0[2] + e0[3] * e0[3];
    }
    __syncthreads();  // P ready
    // ---- PV: V loads lane-contiguous from VS ----
#pragma unroll
    for (int tw = 0; tw < 4; ++tw) {
      const int t32v = (tq << 3) + (c << 2) + tw;
      const s16x8 pa = *(const s16x8*)&Plds[g][lr][(tw << 5) + (quad << 3)];
#pragma unroll
      for (int dj = 0; dj < 4; ++dj) {
        const s16x8 vb =
            *(const s16x8*)(Vc + ((size_t)t32v << 11) + (dj << 9));
        acc[dj] = mfma16(pa, vb, acc[dj]);
      }
    }
    __syncthreads();  // P consumed, safe to overwrite next chunk
  }

  // ---- write raw f32 partial O (normalization happens in combine_o) ----
  const int bg = (b << 3) + g;
  const size_t obase = ((((size_t)(tq << 5) + bg) << 10) + q0) * 64;
#pragma unroll
  for (int dj = 0; dj < 4; ++dj) {
    const int d = (dj << 4) + lr;
#pragma unroll
    for (int r = 0; r < 4; ++r) {
      const int q = (quad << 2) + r;
      Opart[obase + (size_t)q * 64 + d] = acc[dj][r];
    }
  }

  // ---- epilogue: l/l2 reduce (buffers alias Plds), write partials ----
  float* lbuf = Sbuf;          // [8w][8g][16q]  4 KB
  float* l2buf = Sbuf + 1024;  // [8w][8g][16q]  4 KB
#pragma unroll
  for (int gg = 0; gg < 8; ++gg) {
    float l = lacc[gg];
    l += __shfl_xor(l, 16, 64);
    l += __shfl_xor(l, 32, 64);
    float l2 = l2acc[gg];
    l2 += __shfl_xor(l2, 16, 64);
    l2 += __shfl_xor(l2, 32, 64);
    if (quad == 0) {
      lbuf[(w << 7) + (gg << 4) + lr] = l;
      l2buf[(w << 7) + (gg << 4) + lr] = l2;
    }
  }
  __syncthreads();
  if (lane < 16) {  // wave w reduces its own g
    float l = 0.f, l2 = 0.f;
#pragma unroll
    for (int w2 = 0; w2 < 8; ++w2) {
      l += lbuf[(w2 << 7) + (g << 4) + lr];
      l2 += l2buf[(w2 << 7) + (g << 4) + lr];
    }
    const size_t li = (((size_t)(tq << 5) + bg) << 10) + q0 + lr;
    lpart[li] = l;
    l2part[li] = l2;
  }
}

// ---- combine: O = (sum_tq Opart) / l, l/l2 full sums -> lsum/l2sum ----
__global__ __launch_bounds__(256) void combine_o(
    const float* __restrict__ Opart, const float* __restrict__ lpart,
    const float* __restrict__ l2part, u16* __restrict__ O,
    float* __restrict__ lsum, float* __restrict__ l2sum) {
  const int bg = blockIdx.x;       // [0,32)
  const int qo = blockIdx.y;       // [0,8) q-octant
  const int tid = threadIdx.x;
  const int q = (qo << 7) + (tid >> 1);
  const int d0 = (tid & 1) << 5;
  float l = 0.f, l2 = 0.f;
#pragma unroll
  for (int tq = 0; tq < 4; ++tq) {
    const size_t li = (((size_t)(tq << 5) + bg) << 10) + q;
    l += lpart[li];
    l2 += l2part[li];
  }
  const float linv = 1.f / l;
  if ((tid & 1) == 0) {
    lsum[((size_t)bg << 10) + q] = l;
    l2sum[((size_t)bg << 10) + q] = l2;
  }
  f32x4 a[8] = {};
#pragma unroll
  for (int tq = 0; tq < 4; ++tq) {
    const float* src =
        Opart + ((((size_t)(tq << 5) + bg) << 10) + q) * 64 + d0;
#pragma unroll
    for (int j = 0; j < 8; ++j) a[j] += *(const f32x4*)(src + (j << 2));
  }
  u16* dst = O + (((size_t)bg << 10) + q) * 64 + d0;
#pragma unroll
  for (int j = 0; j < 4; ++j) {
    u16x8 o;
#pragma unroll
    for (int k = 0; k < 4; ++k) {
      o[k] = f2bf(a[2 * j][k] * linv);
      o[k + 4] = f2bf(a[2 * j + 1][k] * linv);
    }
    *(u16x8*)(dst + (j << 3)) = o;
  }
}

// ---- merged: reduce per-q l/l2 -> ab, then bias2 via precomputed ws ----
__global__ __launch_bounds__(256) void stats_k(const float* __restrict__ lsum,
                                               const float* __restrict__ l2sum,
                                               const float* __restrict__ gamma,
                                               const float* __restrict__ beta,
                                               const float* __restrict__ ws,
                                               const float* __restrict__ bp,
                                               const float* __restrict__ vsum,
                                               float* __restrict__ ab,
                                               float* __restrict__ bias2) {
  const int bg = blockIdx.x;
  const int g = bg & 7;
  const int tid = threadIdx.x;
  const f32x4 l = *(const f32x4*)(lsum + ((size_t)bg << 10) + (tid << 2));
  const f32x4 l2 = *(const f32x4*)(l2sum + ((size_t)bg << 10) + (tid << 2));
  float ssq = 0.f;
#pragma unroll
  for (int k = 0; k < 4; ++k) ssq += l2[k] / (l[k] * l[k]);
#pragma unroll
  for (int off = 32; off; off >>= 1) ssq += __shfl_xor(ssq, off, 64);
  __shared__ float red[4];
  __shared__ float bt2s;
  if ((tid & 63) == 0) red[tid >> 6] = ssq;
  __syncthreads();
  if (tid == 0) {
    const float s = red[0] + red[1] + red[2] + red[3];
    const float mean = 0.0009765625f;
    const float var = s * (1.f / 1048576.f) - mean * mean;
    const float al = gamma[g] * rsqrtf(var + EPS_);
    const float bt2 = beta[g] - al * mean;
    ab[bg * 2] = al;
    ab[bg * 2 + 1] = bt2;
    bt2s = bt2;
  }
  __syncthreads();
  const float bt2 = bt2s;
  const float* vs = vsum + (bg << 6);
#pragma unroll
  for (int oo = 0; oo < 2; ++oo) {
    const int o = tid + (oo << 8);
    const float* wr = ws + (o << 6);
    float acc = 0.f;
#pragma unroll
    for (int d = 0; d < 64; d += 4) {
      const float4 vv4 = *(const float4*)(vs + d);
      const float4 ws4 = *(const float4*)(wr + d);
      acc += ws4.x * vv4.x + ws4.y * vv4.y + ws4.z * vv4.z + ws4.w * vv4.w;
    }
    bias2[(bg << 9) + o] = bp[o] + bt2 * acc;
  }
}

// ------- y = al[b,g(t)]*(Onorm @ Wp^T) + bias2[b][g(t)][o], 128x128 ----
__global__ __launch_bounds__(256) void gemm_proj(const u16* __restrict__ O,
                                                 const u16* __restrict__ wpb,
                                                 const float* __restrict__ ab,
                                                 const float* __restrict__ bias2,
                                                 float* __restrict__ y) {
  const int b = blockIdx.z;
  const int m0 = blockIdx.y << 7;  // o: 4 tiles
  const int n0 = blockIdx.x << 7;  // t: 8 tiles (tile == head g)
  const int g = blockIdx.x;
  const u16* __restrict__ Ob = O + (size_t)b * (8 * T_ * 64);
  __shared__ u16 As[128][72];
  __shared__ u16 Bs[128][72];
  const int tid = threadIdx.x;
  const int w = tid >> 6, lane = tid & 63, lr = lane & 15, lq = lane >> 4;
  const int wm = (w >> 1) << 6, wn = (w & 1) << 6;
  f32x4 acc[4][4] = {};
  for (int k0 = 0; k0 < C_; k0 += 64) {
#pragma unroll
    for (int it = 0; it < 4; ++it) {
      const int e = tid + (it << 8);
      const int r = e >> 3, c8 = (e & 7) << 3;
      *(u16x8*)&As[r][c8] =
          *(const u16x8*)(wpb + (size_t)(m0 + r) * C_ + k0 + c8);
      const int t = n0 + r;
      const int c = k0 + c8;
      *(u16x8*)&Bs[r][c8] =
          *(const u16x8*)(Ob + (size_t)(t >> 7) * (T_ * 64) +
                          (size_t)(((t & 127) << 3) + (c >> 6)) * 64 + (c & 63));
    }
    __syncthreads();
#pragma unroll
    for (int kf = 0; kf < 2; ++kf) {
      const int ko = (kf << 5) + (lq << 3);
      s16x8 a[4], bb[4];
#pragma unroll
      for (int i = 0; i < 4; ++i) a[i] = *(const s16x8*)&As[wm + (i << 4) + lr][ko];
#pragma unroll
      for (int j = 0; j < 4; ++j) bb[j] = *(const s16x8*)&Bs[wn + (j << 4) + lr][ko];
#pragma unroll
      for (int i = 0; i < 4; ++i)
#pragma unroll
        for (int j = 0; j < 4; ++j) acc[i][j] = mfma16(a[i], bb[j], acc[i][j]);
    }
    __syncthreads();
  }
  const float al = ab[(((b << 3) + g) << 1)];
  const float* __restrict__ b2 = bias2 + (((b << 3) + g) << 9);
#pragma unroll
  for (int i = 0; i < 4; ++i) {
    const int row = wm + (i << 4) + (lq << 2);
#pragma unroll
    for (int j = 0; j < 4; ++j) {
      const int col = wn + (j << 4) + lr;
#pragma unroll
      for (int r = 0; r < 4; ++r)
        y[(size_t)b * (C_ * (size_t)T_) + (size_t)(m0 + row + r) * T_ + n0 + col] =
            acc[i][j][r] * al + b2[m0 + row + r];
    }
  }
}

extern "C" void kernel_launch(void* const* d_in, const int* in_sizes, int n_in,
                              void* d_out, int out_size, void* d_ws,
                              size_t ws_size, hipStream_t stream) {
  const float* x = (const float*)d_in[0];
  const float* wq = (const float*)d_in[1];
  const float* wk = (const float*)d_in[2];
  const float* wv = (const float*)d_in[3];
  const float* wh = (const float*)d_in[4];
  const float* gm = (const float*)d_in[5];
  const float* bt = (const float*)d_in[6];
  const float* wp = (const float*)d_in[7];
  const float* bp = (const float*)d_in[8];
  float* y = (float*)d_out;
  char* wsb = (char*)d_ws;

  u16* Qt = (u16*)(wsb + QT_OFF);
  u16* KS = (u16*)(wsb + KS_OFF);
  u16* VS = (u16*)(wsb + VS_OFF);
  u16* Xt = (u16*)(wsb + XT_OFF);
  u16* Og = (u16*)(wsb + O_OFF);
  float* ab = (float*)(wsb + AB_OFF);
  float* vsum = (float*)(wsb + VSUM_OFF);
  float* bias2 = (float*)(wsb + BIAS2_OFF);
  float* lsum = (float*)(wsb + LSUM_OFF);
  float* l2sum = (float*)(wsb + L2SUM_OFF);
  u16* Wb = (u16*)(wsb + WB_OFF);
  u16* WQb = Wb;
  u16* WKb = Wb + 262144;
  u16* WVb = Wb + 524288;
  u16* WPb = Wb + 786432;
  float* lpart = (float*)(wsb + LP_OFF);
  float* l2part = (float*)(wsb + L2P_OFF);
  float* ws = (float*)(wsb + WS_OFF);
  float* Opart = (float*)(wsb + OP_OFF);

  prep_k<<<dim3(1152), 256, 0, stream>>>(x, wq, wk, wv, wp, Wb, ws, vsum, Xt);
  gemm_qkv<<<dim3(8, 4, 12), 256, 0, stream>>>(Xt, WQb, WKb, WVb, Qt, KS, VS);
  vsum_k<<<dim3(32, 8), 256, 0, stream>>>(VS, vsum);
  attn_fused<<<dim3(1024), 512, 0, stream>>>(Qt, KS, VS, wh, Opart, lpart,
                                             l2part);
  combine_o<<<dim3(32, 8), 256, 0, stream>>>(Opart, lpart, l2part, Og, lsum,
                                             l2sum);
  stats_k<<<dim3(32), 256, 0, stream>>>(lsum, l2sum, gm, bt, ws, bp, vsum, ab,
                                        bias2);
  gemm_proj<<<dim3(8, 4, 4), 256, 0, stream>>>(Og, WPb, ab, bias2, y);
}

// Round 10
// 169.288 us; speedup vs baseline: 1.3203x; 1.0039x over previous
//
#include <hip/hip_runtime.h>
#include <hip/hip_bf16.h>

#define B_ 4
#define C_ 512
#define T_ 1024
#define SCALE_ 0.125f
#define EPS_ 1e-5f

typedef unsigned short u16;
typedef __attribute__((ext_vector_type(8))) unsigned short u16x8;
typedef __attribute__((ext_vector_type(4))) unsigned short u16x4;
typedef __attribute__((ext_vector_type(8))) short s16x8;
typedef __attribute__((ext_vector_type(4))) float f32x4;

// ws byte offsets (ws is 256 MiB)
#define QT_OFF    (0x0ull)         // bf16 Qt[B][T][C]   4 MB (Q pre-scaled by 1/8)
#define KS_OFF    (0x400000ull)    // bf16 KS swizzled [B][t32][half][f][lane][8] 4 MB
#define VS_OFF    (0x800000ull)    // bf16 VS swizzled [B][g][t32][dj][lane][8]   4 MB
#define XT_OFF    (0xC00000ull)    // bf16 Xt[B][T][C]   4 MB
#define O_OFF     (0x1000000ull)   // bf16 O[B][8][T][64] 4 MB (normalized, pre-affine)
#define AB_OFF    (0x1410000ull)   // fp32 ab[B][8][2]
#define VSUM_OFF  (0x1420000ull)   // fp32 vsum[B][8][64]
#define BIAS2_OFF (0x1430000ull)   // fp32 bias2[B][8][512]
#define LSUM_OFF  (0x1440000ull)   // fp32 lsum [B*8][1024]  128 KB
#define L2SUM_OFF (0x1460000ull)   // fp32 l2sum[B*8][1024]  128 KB
#define WB_OFF    (0x1480000ull)   // bf16 W[4][512][512]: wq,wk,wv,wp  2 MB
#define LP_OFF    (0x1680000ull)   // fp32 lpart [4][32][1024] 512 KB
#define L2P_OFF   (0x1700000ull)   // fp32 l2part[4][32][1024] 512 KB
#define WS_OFF    (0x1780000ull)   // fp32 ws[512][64] 128 KB
#define OP_OFF    (0x2000000ull)   // fp32 Opart[4][32][1024][64] 32 MB

static __device__ __forceinline__ u16 f2bf(float f) {
  unsigned u = __float_as_uint(f);
  unsigned r = (u + 0x7fff + ((u >> 16) & 1)) >> 16;  // RNE
  return (u16)r;
}
static __device__ __forceinline__ float b2f(u16 x) {
  return __uint_as_float(((unsigned)x) << 16);
}
static __device__ __forceinline__ f32x4 mfma16(s16x8 a, s16x8 b, f32x4 c) {
  return __builtin_amdgcn_mfma_f32_16x16x32_bf16(a, b, c, 0, 0, 0);
}

// ---- prep: blocks [0,512) wcvt; [512,640) wsum+vsum-zero; [640,1152)
// transpose x -> Xt[b][t][c] bf16. Branch is block-uniform. ----
__global__ __launch_bounds__(256) void prep_k(
    const float* __restrict__ x, const float* __restrict__ wq,
    const float* __restrict__ wk, const float* __restrict__ wv,
    const float* __restrict__ wp, u16* __restrict__ wb,
    float* __restrict__ ws, float* __restrict__ vsum, u16* __restrict__ xt) {
  const int id = blockIdx.x;
  const int tid = threadIdx.x;
  __shared__ float Ts[64][65];
  if (id < 512) {  // ---- wcvt: fp32 -> bf16, 4 weight matrices ----
    const int i = (id << 8) + tid;
    const int idx = i << 3;
    const int which = idx >> 18;  // uniform per block
    const int off = idx & 262143;
    const float* s = which == 0 ? wq : which == 1 ? wk : which == 2 ? wv : wp;
    const float4 f0 = *(const float4*)(s + off);
    const float4 f1 = *(const float4*)(s + off + 4);
    u16x8 o;
    o[0] = f2bf(f0.x); o[1] = f2bf(f0.y); o[2] = f2bf(f0.z); o[3] = f2bf(f0.w);
    o[4] = f2bf(f1.x); o[5] = f2bf(f1.y); o[6] = f2bf(f1.z); o[7] = f2bf(f1.w);
    *(u16x8*)(wb + idx) = o;
  } else if (id < 640) {  // ---- ws[o][d] = sum_j wp[o][j*64+d]; zero vsum ----
    const int idx = ((id - 512) << 8) + tid;
    if (id - 512 < 8) vsum[idx] = 0.f;
    const int o = idx >> 6, d = idx & 63;
    float s = 0.f;
#pragma unroll
    for (int j = 0; j < 8; ++j) s += wp[(o << 9) + (j << 6) + d];
    ws[idx] = s;
  } else {  // ---- transpose x[b][c][t] -> Xt[b][t][c] bf16 ----
    const int id3 = id - 640;
    const int b = id3 >> 7, rem = id3 & 127;
    const int t0 = (rem & 15) << 6;
    const int c0 = (rem >> 4) << 6;
    const float* __restrict__ X = x + (size_t)b * (C_ * (size_t)T_);
    u16* __restrict__ Xt = xt + (size_t)b * (T_ * (size_t)C_);
#pragma unroll
    for (int i = 0; i < 4; ++i) {
      const int e = tid + (i << 8);
      const int r = e >> 4, c4 = e & 15;
      const float4 v =
          *(const float4*)(X + (size_t)(c0 + r) * T_ + t0 + (c4 << 2));
      Ts[r][(c4 << 2) + 0] = v.x; Ts[r][(c4 << 2) + 1] = v.y;
      Ts[r][(c4 << 2) + 2] = v.z; Ts[r][(c4 << 2) + 3] = v.w;
    }
    __syncthreads();
#pragma unroll
    for (int i = 0; i < 2; ++i) {
      const int e = tid + (i << 8);
      const int tt = e >> 3, c8 = e & 7;
      u16x8 o;
#pragma unroll
      for (int j = 0; j < 8; ++j) o[j] = f2bf(Ts[(c8 << 3) + j][tt]);
      *(u16x8*)(Xt + (size_t)(t0 + tt) * C_ + c0 + (c8 << 3)) = o;
    }
  }
}

// ---- unified QKV GEMM, 128x128 tiles. z<4: Q -> Qt[t][o] (scaled).
// z in [4,8): K -> KS swizzled [b][t32][half][f][lane][8] (tp perm baked).
// z>=8: V -> VS swizzled [b][g][t32][dj][lane][8]; vsum folded in (atomics).
// R9's K/V epilogues did 64 SCALAR scattered 2B global stores/thread (the
// same divergence disease R9 cured in attn, on the write side). Now: stage
// the 128x128 output tile in LDS (aliased over As/Bs), then emit KS/VS with
// consecutive-tid -> consecutive-16B coalesced u16x8 stores. ----
__global__ __launch_bounds__(256) void gemm_qkv(
    const u16* __restrict__ xt, const u16* __restrict__ wqb,
    const u16* __restrict__ wkb, const u16* __restrict__ wvb,
    u16* __restrict__ qto, u16* __restrict__ ks, u16* __restrict__ vs,
    float* __restrict__ vsum) {
  const int z = blockIdx.z;
  const int tid = threadIdx.x;
  const int w = tid >> 6, lane = tid & 63, lr = lane & 15, lq = lane >> 4;
  const int wm = (w >> 1) << 6, wn = (w & 1) << 6;
  __shared__ __align__(16) u16 S[2][128][72];  // As=S[0], Bs=S[1]
  u16* Ts = &S[0][0][0];  // epilogue staging tile [128][136] (34816B<=36864B)
  const u16 *Ag, *Bg;
  int m0, n0, mode, b;
  if (z < 8) {
    const int which = z >> 2;
    b = z & 3;
    Ag = xt + (size_t)b * (T_ * (size_t)C_);
    m0 = blockIdx.x << 7;  // t
    Bg = which ? wkb : wqb;
    n0 = blockIdx.y << 7;  // o
    mode = which;          // 0 = Q, 1 = K
  } else {
    b = z - 8;
    Ag = wvb;
    m0 = blockIdx.y << 7;  // o
    Bg = xt + (size_t)b * (T_ * (size_t)C_);
    n0 = blockIdx.x << 7;  // t
    mode = 2;
  }
  f32x4 acc[4][4] = {};
  for (int k0 = 0; k0 < C_; k0 += 64) {
#pragma unroll
    for (int it = 0; it < 4; ++it) {
      const int e = tid + (it << 8);
      const int r = e >> 3, c8 = (e & 7) << 3;
      *(u16x8*)&S[0][r][c8] =
          *(const u16x8*)(Ag + (size_t)(m0 + r) * C_ + k0 + c8);
      *(u16x8*)&S[1][r][c8] =
          *(const u16x8*)(Bg + (size_t)(n0 + r) * C_ + k0 + c8);
    }
    __syncthreads();
#pragma unroll
    for (int kf = 0; kf < 2; ++kf) {
      const int ko = (kf << 5) + (lq << 3);
      s16x8 a[4], bb[4];
#pragma unroll
      for (int i = 0; i < 4; ++i) a[i] = *(const s16x8*)&S[0][wm + (i << 4) + lr][ko];
#pragma unroll
      for (int j = 0; j < 4; ++j) bb[j] = *(const s16x8*)&S[1][wn + (j << 4) + lr][ko];
#pragma unroll
      for (int i = 0; i < 4; ++i)
#pragma unroll
        for (int j = 0; j < 4; ++j) acc[i][j] = mfma16(a[i], bb[j], acc[i][j]);
    }
    __syncthreads();
  }
  if (mode == 0) {
    u16* Y = qto + (size_t)b * (T_ * (size_t)C_);
#pragma unroll
    for (int i = 0; i < 4; ++i) {
      const int row = wm + (i << 4) + (lq << 2);
#pragma unroll
      for (int j = 0; j < 4; ++j) {
        const int col = wn + (j << 4) + lr;
#pragma unroll
        for (int r = 0; r < 4; ++r)
          Y[(size_t)(m0 + row + r) * C_ + n0 + col] =
              f2bf(acc[i][j][r] * SCALE_);
      }
    }
    return;
  }
  if (mode == 2) {
    // ---- vsum contribution: sum over this tile's t-cols, atomic ----
#pragma unroll
    for (int i = 0; i < 4; ++i)
#pragma unroll
      for (int r = 0; r < 4; ++r) {
        float s = acc[i][0][r] + acc[i][1][r] + acc[i][2][r] + acc[i][3][r];
        s += __shfl_xor(s, 1, 64);
        s += __shfl_xor(s, 2, 64);
        s += __shfl_xor(s, 4, 64);
        s += __shfl_xor(s, 8, 64);
        if (lr == 0) {
          const int o = m0 + wm + (i << 4) + (lq << 2) + r;
          atomicAdd(&vsum[(((b << 3) | (o >> 6)) << 6) | (o & 63)], s);
        }
      }
  }
  // ---- stage output tile [m_local][n_local] (stride 136) in LDS ----
#pragma unroll
  for (int i = 0; i < 4; ++i)
#pragma unroll
    for (int j = 0; j < 4; ++j)
#pragma unroll
      for (int r = 0; r < 4; ++r)
        Ts[(wm + (i << 4) + (lq << 2) + r) * 136 + wn + (j << 4) + lr] =
            f2bf(acc[i][j][r]);
  __syncthreads();
  if (mode == 1) {
    // chunk = (t32l, half, fl); 8 threads/chunk; lanek = u*8+part -> coalesced
    const int t32l = tid >> 6, half = (tid >> 5) & 1, fl = (tid >> 3) & 3,
              part = tid & 7;
    const int t32g = (m0 >> 5) + t32l, fg = (n0 >> 5) + fl;
    u16* dst =
        ks + (((((size_t)((b << 5) | t32g) << 1) | half) << 4 | fg) << 9);
#pragma unroll
    for (int u = 0; u < 8; ++u) {
      const int lanek = (u << 3) + part;
      const int quadk = lanek >> 4, lrk = lanek & 15;
      const int rr = ((lrk >> 2) << 3) | (half << 2) | (lrk & 3);
      const u16x8 v = *(const u16x8*)&Ts[((t32l << 5) + rr) * 136 + (fl << 5) +
                                         (quadk << 3)];
      *(u16x8*)(dst + (lanek << 3)) = v;
    }
  } else {
    // chunk = (gl, t32l, dj); lanev = u*8+part -> coalesced
    const int gl = tid >> 7, t32l = (tid >> 5) & 3, dj = (tid >> 3) & 3,
              part = tid & 7;
    const int gg = (m0 >> 6) + gl, t32g = (n0 >> 5) + t32l;
    u16* dst =
        vs + (((((size_t)((b << 3) | gg) << 5) | t32g) << 2 | dj) << 9);
#pragma unroll
    for (int u = 0; u < 8; ++u) {
      const int lanev = (u << 3) + part;
      const int quadv = lanev >> 4, lrv = lanev & 15;
      const u16x8 v = *(const u16x8*)&Ts[((gl << 6) + (dj << 4) + lrv) * 136 +
                                         (t32l << 5) + (quadv << 3)];
      *(u16x8*)(dst + (lanev << 3)) = v;
    }
  }
}

// ---- FUSED attention (R9 structure; unroll 2->4 on the h-loop so 8 K
// loads batch ahead of the dependent MFMA chain). T-SPLIT grid 1024 =
// (b, qb, tq); 512 thr; 2 chunks of 128 t; wave-pair QK; m[8]=32 VGPRs;
// ~51.5KB LDS -> 3 blocks/CU. K/V read from swizzled global layouts. ----
__global__ __launch_bounds__(512, 4) void attn_fused(
    const u16* __restrict__ Qt, const u16* __restrict__ KS,
    const u16* __restrict__ VS, const float* __restrict__ wh,
    float* __restrict__ Opart, float* __restrict__ lpart,
    float* __restrict__ l2part) {
  const int id = blockIdx.x;
  const int xcd = id & 7;
  const int b = xcd >> 1;
  const int hi = id >> 3;                       // [0,128)
  const int qb = ((xcd & 1) << 5) | (hi & 31);  // [0,64)
  const int tq = hi >> 5;                       // [0,4) t-quarter
  const int q0 = qb << 4;
  const int tid = threadIdx.x;
  const int w = tid >> 6, lane = tid & 63;
  const int lr = lane & 15, quad = lane >> 4;

  __shared__ __align__(16) u16 Qs[16][522];       // 16704 B
  __shared__ __align__(16) u16 Plds[8][16][136];  // 34816 B
  float* Sbuf = (float*)&Plds[0][0][0];  // epilogue alias (Plds dead by then)

  {  // stage Q tile (16 x 512)
    const u16* Qb = Qt + ((size_t)b * T_ + q0) * C_;
    for (int i = tid; i < 1024; i += 512) {
      const int r = i >> 6, c8 = i & 63;
      *(u16x8*)&Qs[r][c8 << 3] = *(const u16x8*)(Qb + (size_t)r * C_ + (c8 << 3));
    }
  }

  const u16* __restrict__ Qrow = &Qs[lr][quad << 3];
  const int g = w;  // PV head owned by this wave
  const int win = w >> 1, half = w & 1;  // QK: window pair, K-half
  const u16* __restrict__ Vc =
      VS + (((size_t)((b << 3) | g)) << 16) + (lane << 3);

  float lacc[8] = {}, l2acc[8] = {};
  f32x4 acc[4] = {};

  __syncthreads();

  for (int c = 0; c < 2; ++c) {
    // ---- QK + mix + exp: K loads lane-contiguous from KS ----
    const int t32k = (tq << 3) + (c << 2) + win;
    const u16* __restrict__ Kc =
        KS + (((size_t)((((b << 5) | t32k) << 1) | half)) << 13) + (lane << 3);
    f32x4 m[8] = {};
#pragma unroll 4
    for (int h = 0; h < 8; ++h) {
      f32x4 a0 = {0.f, 0.f, 0.f, 0.f};
      const s16x8 qf0 = *(const s16x8*)(Qrow + (h << 6));
      const s16x8 k0 = *(const s16x8*)(Kc + (h << 10));
      a0 = mfma16(k0, qf0, a0);
      const s16x8 qf1 = *(const s16x8*)(Qrow + (h << 6) + 32);
      const s16x8 k1 = *(const s16x8*)(Kc + (h << 10) + 512);
      a0 = mfma16(k1, qf1, a0);
#pragma unroll
      for (int gg = 0; gg < 8; ++gg) {
        const float wgh = wh[(gg << 3) + h];  // uniform -> SGPR
        m[gg] += a0 * wgh;
      }
    }
    // lane's t slots: win*32 + quad*8 + half*4 + {0..3}; q = lr
#pragma unroll
    for (int gg = 0; gg < 8; ++gg) {
      f32x4 e0;
#pragma unroll
      for (int k = 0; k < 4; ++k) e0[k] = __expf(m[gg][k]);
      u16x4 o;
#pragma unroll
      for (int k = 0; k < 4; ++k) o[k] = f2bf(e0[k]);
      *(u16x4*)&Plds[gg][lr][(win << 5) + (quad << 3) + (half << 2)] = o;
      lacc[gg] += e0[0] + e0[1] + e0[2] + e0[3];
      l2acc[gg] += e0[0] * e0[0] + e0[1] * e0[1] + e0[2] * e0[2] + e0[3] * e0[3];
    }
    __syncthreads();  // P ready
    // ---- PV: V loads lane-contiguous from VS ----
#pragma unroll
    for (int tw = 0; tw < 4; ++tw) {
      const int t32v = (tq << 3) + (c << 2) + tw;
      const s16x8 pa = *(const s16x8*)&Plds[g][lr][(tw << 5) + (quad << 3)];
#pragma unroll
      for (int dj = 0; dj < 4; ++dj) {
        const s16x8 vb =
            *(const s16x8*)(Vc + ((size_t)t32v << 11) + (dj << 9));
        acc[dj] = mfma16(pa, vb, acc[dj]);
      }
    }
    __syncthreads();  // P consumed, safe to overwrite next chunk
  }

  // ---- write raw f32 partial O (normalization happens in combine_o) ----
  const int bg = (b << 3) + g;
  const size_t obase = ((((size_t)(tq << 5) + bg) << 10) + q0) * 64;
#pragma unroll
  for (int dj = 0; dj < 4; ++dj) {
    const int d = (dj << 4) + lr;
#pragma unroll
    for (int r = 0; r < 4; ++r) {
      const int q = (quad << 2) + r;
      Opart[obase + (size_t)q * 64 + d] = acc[dj][r];
    }
  }

  // ---- epilogue: l/l2 reduce (buffers alias Plds), write partials ----
  float* lbuf = Sbuf;          // [8w][8g][16q]  4 KB
  float* l2buf = Sbuf + 1024;  // [8w][8g][16q]  4 KB
#pragma unroll
  for (int gg = 0; gg < 8; ++gg) {
    float l = lacc[gg];
    l += __shfl_xor(l, 16, 64);
    l += __shfl_xor(l, 32, 64);
    float l2 = l2acc[gg];
    l2 += __shfl_xor(l2, 16, 64);
    l2 += __shfl_xor(l2, 32, 64);
    if (quad == 0) {
      lbuf[(w << 7) + (gg << 4) + lr] = l;
      l2buf[(w << 7) + (gg << 4) + lr] = l2;
    }
  }
  __syncthreads();
  if (lane < 16) {  // wave w reduces its own g
    float l = 0.f, l2 = 0.f;
#pragma unroll
    for (int w2 = 0; w2 < 8; ++w2) {
      l += lbuf[(w2 << 7) + (g << 4) + lr];
      l2 += l2buf[(w2 << 7) + (g << 4) + lr];
    }
    const size_t li = (((size_t)(tq << 5) + bg) << 10) + q0 + lr;
    lpart[li] = l;
    l2part[li] = l2;
  }
}

// ---- combine: O = (sum_tq Opart) / l, l/l2 full sums -> lsum/l2sum ----
__global__ __launch_bounds__(256) void combine_o(
    const float* __restrict__ Opart, const float* __restrict__ lpart,
    const float* __restrict__ l2part, u16* __restrict__ O,
    float* __restrict__ lsum, float* __restrict__ l2sum) {
  const int bg = blockIdx.x;       // [0,32)
  const int qo = blockIdx.y;       // [0,8) q-octant
  const int tid = threadIdx.x;
  const int q = (qo << 7) + (tid >> 1);
  const int d0 = (tid & 1) << 5;
  float l = 0.f, l2 = 0.f;
#pragma unroll
  for (int tq = 0; tq < 4; ++tq) {
    const size_t li = (((size_t)(tq << 5) + bg) << 10) + q;
    l += lpart[li];
    l2 += l2part[li];
  }
  const float linv = 1.f / l;
  if ((tid & 1) == 0) {
    lsum[((size_t)bg << 10) + q] = l;
    l2sum[((size_t)bg << 10) + q] = l2;
  }
  f32x4 a[8] = {};
#pragma unroll
  for (int tq = 0; tq < 4; ++tq) {
    const float* src =
        Opart + ((((size_t)(tq << 5) + bg) << 10) + q) * 64 + d0;
#pragma unroll
    for (int j = 0; j < 8; ++j) a[j] += *(const f32x4*)(src + (j << 2));
  }
  u16* dst = O + (((size_t)bg << 10) + q) * 64 + d0;
#pragma unroll
  for (int j = 0; j < 4; ++j) {
    u16x8 o;
#pragma unroll
    for (int k = 0; k < 4; ++k) {
      o[k] = f2bf(a[2 * j][k] * linv);
      o[k + 4] = f2bf(a[2 * j + 1][k] * linv);
    }
    *(u16x8*)(dst + (j << 3)) = o;
  }
}

// ---- merged: reduce per-q l/l2 -> ab, then bias2 via precomputed ws ----
__global__ __launch_bounds__(256) void stats_k(const float* __restrict__ lsum,
                                               const float* __restrict__ l2sum,
                                               const float* __restrict__ gamma,
                                               const float* __restrict__ beta,
                                               const float* __restrict__ ws,
                                               const float* __restrict__ bp,
                                               const float* __restrict__ vsum,
                                               float* __restrict__ ab,
                                               float* __restrict__ bias2) {
  const int bg = blockIdx.x;
  const int g = bg & 7;
  const int tid = threadIdx.x;
  const f32x4 l = *(const f32x4*)(lsum + ((size_t)bg << 10) + (tid << 2));
  const f32x4 l2 = *(const f32x4*)(l2sum + ((size_t)bg << 10) + (tid << 2));
  float ssq = 0.f;
#pragma unroll
  for (int k = 0; k < 4; ++k) ssq += l2[k] / (l[k] * l[k]);
#pragma unroll
  for (int off = 32; off; off >>= 1) ssq += __shfl_xor(ssq, off, 64);
  __shared__ float red[4];
  __shared__ float bt2s;
  if ((tid & 63) == 0) red[tid >> 6] = ssq;
  __syncthreads();
  if (tid == 0) {
    const float s = red[0] + red[1] + red[2] + red[3];
    const float mean = 0.0009765625f;
    const float var = s * (1.f / 1048576.f) - mean * mean;
    const float al = gamma[g] * rsqrtf(var + EPS_);
    const float bt2 = beta[g] - al * mean;
    ab[bg * 2] = al;
    ab[bg * 2 + 1] = bt2;
    bt2s = bt2;
  }
  __syncthreads();
  const float bt2 = bt2s;
  const float* vs = vsum + (bg << 6);
#pragma unroll
  for (int oo = 0; oo < 2; ++oo) {
    const int o = tid + (oo << 8);
    const float* wr = ws + (o << 6);
    float acc = 0.f;
#pragma unroll
    for (int d = 0; d < 64; d += 4) {
      const float4 vv4 = *(const float4*)(vs + d);
      const float4 ws4 = *(const float4*)(wr + d);
      acc += ws4.x * vv4.x + ws4.y * vv4.y + ws4.z * vv4.z + ws4.w * vv4.w;
    }
    bias2[(bg << 9) + o] = bp[o] + bt2 * acc;
  }
}

// ------- y = al[b,g(t)]*(Onorm @ Wp^T) + bias2[b][g(t)][o], 128x128 ----
__global__ __launch_bounds__(256) void gemm_proj(const u16* __restrict__ O,
                                                 const u16* __restrict__ wpb,
                                                 const float* __restrict__ ab,
                                                 const float* __restrict__ bias2,
                                                 float* __restrict__ y) {
  const int b = blockIdx.z;
  const int m0 = blockIdx.y << 7;  // o: 4 tiles
  const int n0 = blockIdx.x << 7;  // t: 8 tiles (tile == head g)
  const int g = blockIdx.x;
  const u16* __restrict__ Ob = O + (size_t)b * (8 * T_ * 64);
  __shared__ u16 As[128][72];
  __shared__ u16 Bs[128][72];
  const int tid = threadIdx.x;
  const int w = tid >> 6, lane = tid & 63, lr = lane & 15, lq = lane >> 4;
  const int wm = (w >> 1) << 6, wn = (w & 1) << 6;
  f32x4 acc[4][4] = {};
  for (int k0 = 0; k0 < C_; k0 += 64) {
#pragma unroll
    for (int it = 0; it < 4; ++it) {
      const int e = tid + (it << 8);
      const int r = e >> 3, c8 = (e & 7) << 3;
      *(u16x8*)&As[r][c8] =
          *(const u16x8*)(wpb + (size_t)(m0 + r) * C_ + k0 + c8);
      const int t = n0 + r;
      const int c = k0 + c8;
      *(u16x8*)&Bs[r][c8] =
          *(const u16x8*)(Ob + (size_t)(t >> 7) * (T_ * 64) +
                          (size_t)(((t & 127) << 3) + (c >> 6)) * 64 + (c & 63));
    }
    __syncthreads();
#pragma unroll
    for (int kf = 0; kf < 2; ++kf) {
      const int ko = (kf << 5) + (lq << 3);
      s16x8 a[4], bb[4];
#pragma unroll
      for (int i = 0; i < 4; ++i) a[i] = *(const s16x8*)&As[wm + (i << 4) + lr][ko];
#pragma unroll
      for (int j = 0; j < 4; ++j) bb[j] = *(const s16x8*)&Bs[wn + (j << 4) + lr][ko];
#pragma unroll
      for (int i = 0; i < 4; ++i)
#pragma unroll
        for (int j = 0; j < 4; ++j) acc[i][j] = mfma16(a[i], bb[j], acc[i][j]);
    }
    __syncthreads();
  }
  const float al = ab[(((b << 3) + g) << 1)];
  const float* __restrict__ b2 = bias2 + (((b << 3) + g) << 9);
#pragma unroll
  for (int i = 0; i < 4; ++i) {
    const int row = wm + (i << 4) + (lq << 2);
#pragma unroll
    for (int j = 0; j < 4; ++j) {
      const int col = wn + (j << 4) + lr;
#pragma unroll
      for (int r = 0; r < 4; ++r)
        y[(size_t)b * (C_ * (size_t)T_) + (size_t)(m0 + row + r) * T_ + n0 + col] =
            acc[i][j][r] * al + b2[m0 + row + r];
    }
  }
}

extern "C" void kernel_launch(void* const* d_in, const int* in_sizes, int n_in,
                              void* d_out, int out_size, void* d_ws,
                              size_t ws_size, hipStream_t stream) {
  const float* x = (const float*)d_in[0];
  const float* wq = (const float*)d_in[1];
  const float* wk = (const float*)d_in[2];
  const float* wv = (const float*)d_in[3];
  const float* wh = (const float*)d_in[4];
  const float* gm = (const float*)d_in[5];
  const float* bt = (const float*)d_in[6];
  const float* wp = (const float*)d_in[7];
  const float* bp = (const float*)d_in[8];
  float* y = (float*)d_out;
  char* wsb = (char*)d_ws;

  u16* Qt = (u16*)(wsb + QT_OFF);
  u16* KS = (u16*)(wsb + KS_OFF);
  u16* VS = (u16*)(wsb + VS_OFF);
  u16* Xt = (u16*)(wsb + XT_OFF);
  u16* Og = (u16*)(wsb + O_OFF);
  float* ab = (float*)(wsb + AB_OFF);
  float* vsum = (float*)(wsb + VSUM_OFF);
  float* bias2 = (float*)(wsb + BIAS2_OFF);
  float* lsum = (float*)(wsb + LSUM_OFF);
  float* l2sum = (float*)(wsb + L2SUM_OFF);
  u16* Wb = (u16*)(wsb + WB_OFF);
  u16* WQb = Wb;
  u16* WKb = Wb + 262144;
  u16* WVb = Wb + 524288;
  u16* WPb = Wb + 786432;
  float* lpart = (float*)(wsb + LP_OFF);
  float* l2part = (float*)(wsb + L2P_OFF);
  float* ws = (float*)(wsb + WS_OFF);
  float* Opart = (float*)(wsb + OP_OFF);

  prep_k<<<dim3(1152), 256, 0, stream>>>(x, wq, wk, wv, wp, Wb, ws, vsum, Xt);
  gemm_qkv<<<dim3(8, 4, 12), 256, 0, stream>>>(Xt, WQb, WKb, WVb, Qt, KS, VS,
                                               vsum);
  attn_fused<<<dim3(1024), 512, 0, stream>>>(Qt, KS, VS, wh, Opart, lpart,
                                             l2part);
  combine_o<<<dim3(32, 8), 256, 0, stream>>>(Opart, lpart, l2part, Og, lsum,
                                             l2sum);
  stats_k<<<dim3(32), 256, 0, stream>>>(lsum, l2sum, gm, bt, ws, bp, vsum, ab,
                                        bias2);
  gemm_proj<<<dim3(8, 4, 4), 256, 0, stream>>>(Og, WPb, ab, bias2, y);
}

// Round 11
// 163.716 us; speedup vs baseline: 1.3653x; 1.0340x over previous
//
#include <hip/hip_runtime.h>
#include <hip/hip_bf16.h>

#define B_ 4
#define C_ 512
#define T_ 1024
#define SCALE_ 0.125f
#define EPS_ 1e-5f

typedef unsigned short u16;
typedef __attribute__((ext_vector_type(8))) unsigned short u16x8;
typedef __attribute__((ext_vector_type(4))) unsigned short u16x4;
typedef __attribute__((ext_vector_type(8))) short s16x8;
typedef __attribute__((ext_vector_type(4))) float f32x4;

// ws byte offsets (ws is 256 MiB)
#define QT_OFF    (0x0ull)         // bf16 Qt[B][T][C]   4 MB (Q pre-scaled by 1/8)
#define KS_OFF    (0x400000ull)    // bf16 KS swizzled [B][t32][half][f][lane][8] 4 MB
#define VS_OFF    (0x800000ull)    // bf16 VS swizzled [B][g][t32][dj][lane][8]   4 MB
#define XT_OFF    (0xC00000ull)    // bf16 Xt[B][T][C]   4 MB
#define O_OFF     (0x1000000ull)   // bf16 O[B][8][T][64] 4 MB (normalized, pre-affine)
#define AB_OFF    (0x1410000ull)   // fp32 ab[B][8][2]
#define VSUM_OFF  (0x1420000ull)   // fp32 vsum[B][8][64]
#define BIAS2_OFF (0x1430000ull)   // fp32 bias2[B][8][512]
#define LSUM_OFF  (0x1440000ull)   // fp32 lsum [B*8][1024]  128 KB
#define L2SUM_OFF (0x1460000ull)   // fp32 l2sum[B*8][1024]  128 KB
#define WB_OFF    (0x1480000ull)   // bf16 W[4][512][512]: wq,wk,wv,wp  2 MB
#define LP_OFF    (0x1680000ull)   // fp32 lpart [4][32][1024] 512 KB
#define L2P_OFF   (0x1700000ull)   // fp32 l2part[4][32][1024] 512 KB
#define WS_OFF    (0x1780000ull)   // fp32 ws[512][64] 128 KB
#define OP_OFF    (0x2000000ull)   // fp32 Opart[4][32][1024][64] 32 MB

static __device__ __forceinline__ u16 f2bf(float f) {
  unsigned u = __float_as_uint(f);
  unsigned r = (u + 0x7fff + ((u >> 16) & 1)) >> 16;  // RNE
  return (u16)r;
}
static __device__ __forceinline__ float b2f(u16 x) {
  return __uint_as_float(((unsigned)x) << 16);
}
static __device__ __forceinline__ f32x4 mfma16(s16x8 a, s16x8 b, f32x4 c) {
  return __builtin_amdgcn_mfma_f32_16x16x32_bf16(a, b, c, 0, 0, 0);
}

// ---- prep: blocks [0,512) wcvt; [512,640) wsum+vsum-zero; [640,1152)
// transpose x -> Xt[b][t][c] bf16. Branch is block-uniform. ----
__global__ __launch_bounds__(256) void prep_k(
    const float* __restrict__ x, const float* __restrict__ wq,
    const float* __restrict__ wk, const float* __restrict__ wv,
    const float* __restrict__ wp, u16* __restrict__ wb,
    float* __restrict__ ws, float* __restrict__ vsum, u16* __restrict__ xt) {
  const int id = blockIdx.x;
  const int tid = threadIdx.x;
  __shared__ float Ts[64][65];
  if (id < 512) {  // ---- wcvt: fp32 -> bf16, 4 weight matrices ----
    const int i = (id << 8) + tid;
    const int idx = i << 3;
    const int which = idx >> 18;  // uniform per block
    const int off = idx & 262143;
    const float* s = which == 0 ? wq : which == 1 ? wk : which == 2 ? wv : wp;
    const float4 f0 = *(const float4*)(s + off);
    const float4 f1 = *(const float4*)(s + off + 4);
    u16x8 o;
    o[0] = f2bf(f0.x); o[1] = f2bf(f0.y); o[2] = f2bf(f0.z); o[3] = f2bf(f0.w);
    o[4] = f2bf(f1.x); o[5] = f2bf(f1.y); o[6] = f2bf(f1.z); o[7] = f2bf(f1.w);
    *(u16x8*)(wb + idx) = o;
  } else if (id < 640) {  // ---- ws[o][d] = sum_j wp[o][j*64+d]; zero vsum ----
    const int idx = ((id - 512) << 8) + tid;
    if (id - 512 < 8) vsum[idx] = 0.f;
    const int o = idx >> 6, d = idx & 63;
    float s = 0.f;
#pragma unroll
    for (int j = 0; j < 8; ++j) s += wp[(o << 9) + (j << 6) + d];
    ws[idx] = s;
  } else {  // ---- transpose x[b][c][t] -> Xt[b][t][c] bf16 ----
    const int id3 = id - 640;
    const int b = id3 >> 7, rem = id3 & 127;
    const int t0 = (rem & 15) << 6;
    const int c0 = (rem >> 4) << 6;
    const float* __restrict__ X = x + (size_t)b * (C_ * (size_t)T_);
    u16* __restrict__ Xt = xt + (size_t)b * (T_ * (size_t)C_);
#pragma unroll
    for (int i = 0; i < 4; ++i) {
      const int e = tid + (i << 8);
      const int r = e >> 4, c4 = e & 15;
      const float4 v =
          *(const float4*)(X + (size_t)(c0 + r) * T_ + t0 + (c4 << 2));
      Ts[r][(c4 << 2) + 0] = v.x; Ts[r][(c4 << 2) + 1] = v.y;
      Ts[r][(c4 << 2) + 2] = v.z; Ts[r][(c4 << 2) + 3] = v.w;
    }
    __syncthreads();
#pragma unroll
    for (int i = 0; i < 2; ++i) {
      const int e = tid + (i << 8);
      const int tt = e >> 3, c8 = e & 7;
      u16x8 o;
#pragma unroll
      for (int j = 0; j < 8; ++j) o[j] = f2bf(Ts[(c8 << 3) + j][tt]);
      *(u16x8*)(Xt + (size_t)(t0 + tt) * C_ + c0 + (c8 << 3)) = o;
    }
  }
}

// ---- unified QKV GEMM, 128x64 tiles -> grid 8x8x12 = 768 blocks (3/CU;
// the 128x128 version was 384 blocks = 1.5/CU, latency-bound with nothing
// to overlap). z<4: Q -> Qt[t][o] (scaled). z in [4,8): K -> KS swizzled
// [b][t32][half][f][lane][8]. z>=8: V -> VS swizzled [b][g][t32][dj][lane]
// [8] + vsum fold (atomics). KS/VS emitted via LDS stage + coalesced
// u16x8 stores (16 chunks x 16 thr x 4 vecs). ----
__global__ __launch_bounds__(256) void gemm_qkv(
    const u16* __restrict__ xt, const u16* __restrict__ wqb,
    const u16* __restrict__ wkb, const u16* __restrict__ wvb,
    u16* __restrict__ qto, u16* __restrict__ ks, u16* __restrict__ vs,
    float* __restrict__ vsum) {
  const int z = blockIdx.z;
  const int tid = threadIdx.x;
  const int w = tid >> 6, lane = tid & 63, lr = lane & 15, lq = lane >> 4;
  const int wm = (w >> 1) << 6, wn = (w & 1) << 5;  // 2x2 waves: 64m x 32n
  __shared__ __align__(16) u16 As[128][72];
  __shared__ __align__(16) u16 Bs[64][72];
  u16* Ts = &As[0][0];  // epilogue staging tile [128][72] (aliases As)
  const u16 *Ag, *Bg;
  int m0, n0, mode, b;
  if (z < 8) {
    const int which = z >> 2;
    b = z & 3;
    Ag = xt + (size_t)b * (T_ * (size_t)C_);
    m0 = blockIdx.x << 7;  // t: 8 tiles
    Bg = which ? wkb : wqb;
    n0 = blockIdx.y << 6;  // o: 8 tiles
    mode = which;          // 0 = Q, 1 = K
  } else {
    b = z - 8;
    const int ti = (blockIdx.y << 3) | blockIdx.x;  // [0,64)
    Ag = wvb;
    m0 = (ti >> 4) << 7;  // o: 4 tiles
    Bg = xt + (size_t)b * (T_ * (size_t)C_);
    n0 = (ti & 15) << 6;  // t: 16 tiles
    mode = 2;
  }
  f32x4 acc[4][2] = {};
  for (int k0 = 0; k0 < C_; k0 += 64) {
#pragma unroll
    for (int it = 0; it < 4; ++it) {
      const int e = tid + (it << 8);
      const int r = e >> 3, c8 = (e & 7) << 3;
      *(u16x8*)&As[r][c8] =
          *(const u16x8*)(Ag + (size_t)(m0 + r) * C_ + k0 + c8);
    }
#pragma unroll
    for (int it = 0; it < 2; ++it) {
      const int e = tid + (it << 8);
      const int r = e >> 3, c8 = (e & 7) << 3;
      *(u16x8*)&Bs[r][c8] =
          *(const u16x8*)(Bg + (size_t)(n0 + r) * C_ + k0 + c8);
    }
    __syncthreads();
#pragma unroll
    for (int kf = 0; kf < 2; ++kf) {
      const int ko = (kf << 5) + (lq << 3);
      s16x8 a[4], bb[2];
#pragma unroll
      for (int i = 0; i < 4; ++i) a[i] = *(const s16x8*)&As[wm + (i << 4) + lr][ko];
#pragma unroll
      for (int j = 0; j < 2; ++j) bb[j] = *(const s16x8*)&Bs[wn + (j << 4) + lr][ko];
#pragma unroll
      for (int i = 0; i < 4; ++i)
#pragma unroll
        for (int j = 0; j < 2; ++j) acc[i][j] = mfma16(a[i], bb[j], acc[i][j]);
    }
    __syncthreads();
  }
  if (mode == 0) {
    u16* Y = qto + (size_t)b * (T_ * (size_t)C_);
#pragma unroll
    for (int i = 0; i < 4; ++i) {
      const int row = wm + (i << 4) + (lq << 2);
#pragma unroll
      for (int j = 0; j < 2; ++j) {
        const int col = wn + (j << 4) + lr;
#pragma unroll
        for (int r = 0; r < 4; ++r)
          Y[(size_t)(m0 + row + r) * C_ + n0 + col] =
              f2bf(acc[i][j][r] * SCALE_);
      }
    }
    return;
  }
  if (mode == 2) {
    // ---- vsum contribution: sum over this tile's 64 t-cols, atomic ----
#pragma unroll
    for (int i = 0; i < 4; ++i)
#pragma unroll
      for (int r = 0; r < 4; ++r) {
        float s = acc[i][0][r] + acc[i][1][r];
        s += __shfl_xor(s, 1, 64);
        s += __shfl_xor(s, 2, 64);
        s += __shfl_xor(s, 4, 64);
        s += __shfl_xor(s, 8, 64);
        if (lr == 0) {
          const int o = m0 + wm + (i << 4) + (lq << 2) + r;
          atomicAdd(&vsum[(((b << 3) | (o >> 6)) << 6) | (o & 63)], s);
        }
      }
  }
  // ---- stage output tile [m_local 128][n_local 64] (stride 72) in LDS ----
#pragma unroll
  for (int i = 0; i < 4; ++i)
#pragma unroll
    for (int j = 0; j < 2; ++j)
#pragma unroll
      for (int r = 0; r < 4; ++r)
        Ts[(wm + (i << 4) + (lq << 2) + r) * 72 + wn + (j << 4) + lr] =
            f2bf(acc[i][j][r]);
  __syncthreads();
  const int ch = tid >> 4, part = tid & 15;  // 16 chunks x 16 threads
  if (mode == 1) {
    // chunk = (t32l[4], half[2], fl[2]); lanek = u*16+part -> coalesced
    const int t32l = ch >> 2, half = (ch >> 1) & 1, fl = ch & 1;
    const int t32g = (m0 >> 5) + t32l, fg = (n0 >> 5) + fl;
    u16* dst =
        ks + (((((size_t)((b << 5) | t32g) << 1) | half) << 4 | fg) << 9);
#pragma unroll
    for (int u = 0; u < 4; ++u) {
      const int lanek = (u << 4) + part;
      const int quadk = lanek >> 4, lrk = lanek & 15;
      const int rr = ((lrk >> 2) << 3) | (half << 2) | (lrk & 3);
      const u16x8 v =
          *(const u16x8*)&Ts[((t32l << 5) + rr) * 72 + (fl << 5) + (quadk << 3)];
      *(u16x8*)(dst + (lanek << 3)) = v;
    }
  } else {
    // chunk = (gl[2], t32l[2], dj[4]); lanev = u*16+part -> coalesced
    const int gl = ch >> 3, t32l = (ch >> 2) & 1, dj = ch & 3;
    const int gg = (m0 >> 6) + gl, t32g = (n0 >> 5) + t32l;
    u16* dst =
        vs + (((((size_t)((b << 3) | gg) << 5) | t32g) << 2 | dj) << 9);
#pragma unroll
    for (int u = 0; u < 4; ++u) {
      const int lanev = (u << 4) + part;
      const int quadv = lanev >> 4, lrv = lanev & 15;
      const u16x8 v = *(const u16x8*)&Ts[((gl << 6) + (dj << 4) + lrv) * 72 +
                                         (t32l << 5) + (quadv << 3)];
      *(u16x8*)(dst + (lanev << 3)) = v;
    }
  }
}

// ---- FUSED attention (unchanged from R10, 52us). T-SPLIT grid 1024 =
// (b, qb, tq); 512 thr; 2 chunks of 128 t; wave-pair QK; m[8]=32 VGPRs;
// ~51.5KB LDS -> 3 blocks/CU. K/V read from swizzled global layouts. ----
__global__ __launch_bounds__(512, 4) void attn_fused(
    const u16* __restrict__ Qt, const u16* __restrict__ KS,
    const u16* __restrict__ VS, const float* __restrict__ wh,
    float* __restrict__ Opart, float* __restrict__ lpart,
    float* __restrict__ l2part) {
  const int id = blockIdx.x;
  const int xcd = id & 7;
  const int b = xcd >> 1;
  const int hi = id >> 3;                       // [0,128)
  const int qb = ((xcd & 1) << 5) | (hi & 31);  // [0,64)
  const int tq = hi >> 5;                       // [0,4) t-quarter
  const int q0 = qb << 4;
  const int tid = threadIdx.x;
  const int w = tid >> 6, lane = tid & 63;
  const int lr = lane & 15, quad = lane >> 4;

  __shared__ __align__(16) u16 Qs[16][522];       // 16704 B
  __shared__ __align__(16) u16 Plds[8][16][136];  // 34816 B
  float* Sbuf = (float*)&Plds[0][0][0];  // epilogue alias (Plds dead by then)

  {  // stage Q tile (16 x 512)
    const u16* Qb = Qt + ((size_t)b * T_ + q0) * C_;
    for (int i = tid; i < 1024; i += 512) {
      const int r = i >> 6, c8 = i & 63;
      *(u16x8*)&Qs[r][c8 << 3] = *(const u16x8*)(Qb + (size_t)r * C_ + (c8 << 3));
    }
  }

  const u16* __restrict__ Qrow = &Qs[lr][quad << 3];
  const int g = w;  // PV head owned by this wave
  const int win = w >> 1, half = w & 1;  // QK: window pair, K-half
  const u16* __restrict__ Vc =
      VS + (((size_t)((b << 3) | g)) << 16) + (lane << 3);

  float lacc[8] = {}, l2acc[8] = {};
  f32x4 acc[4] = {};

  __syncthreads();

  for (int c = 0; c < 2; ++c) {
    // ---- QK + mix + exp: K loads lane-contiguous from KS ----
    const int t32k = (tq << 3) + (c << 2) + win;
    const u16* __restrict__ Kc =
        KS + (((size_t)((((b << 5) | t32k) << 1) | half)) << 13) + (lane << 3);
    f32x4 m[8] = {};
#pragma unroll 4
    for (int h = 0; h < 8; ++h) {
      f32x4 a0 = {0.f, 0.f, 0.f, 0.f};
      const s16x8 qf0 = *(const s16x8*)(Qrow + (h << 6));
      const s16x8 k0 = *(const s16x8*)(Kc + (h << 10));
      a0 = mfma16(k0, qf0, a0);
      const s16x8 qf1 = *(const s16x8*)(Qrow + (h << 6) + 32);
      const s16x8 k1 = *(const s16x8*)(Kc + (h << 10) + 512);
      a0 = mfma16(k1, qf1, a0);
#pragma unroll
      for (int gg = 0; gg < 8; ++gg) {
        const float wgh = wh[(gg << 3) + h];  // uniform -> SGPR
        m[gg] += a0 * wgh;
      }
    }
    // lane's t slots: win*32 + quad*8 + half*4 + {0..3}; q = lr
#pragma unroll
    for (int gg = 0; gg < 8; ++gg) {
      f32x4 e0;
#pragma unroll
      for (int k = 0; k < 4; ++k) e0[k] = __expf(m[gg][k]);
      u16x4 o;
#pragma unroll
      for (int k = 0; k < 4; ++k) o[k] = f2bf(e0[k]);
      *(u16x4*)&Plds[gg][lr][(win << 5) + (quad << 3) + (half << 2)] = o;
      lacc[gg] += e0[0] + e0[1] + e0[2] + e0[3];
      l2acc[gg] += e0[0] * e0[0] + e0[1] * e0[1] + e0[2] * e0[2] + e0[3] * e0[3];
    }
    __syncthreads();  // P ready
    // ---- PV: V loads lane-contiguous from VS ----
#pragma unroll
    for (int tw = 0; tw < 4; ++tw) {
      const int t32v = (tq << 3) + (c << 2) + tw;
      const s16x8 pa = *(const s16x8*)&Plds[g][lr][(tw << 5) + (quad << 3)];
#pragma unroll
      for (int dj = 0; dj < 4; ++dj) {
        const s16x8 vb =
            *(const s16x8*)(Vc + ((size_t)t32v << 11) + (dj << 9));
        acc[dj] = mfma16(pa, vb, acc[dj]);
      }
    }
    __syncthreads();  // P consumed, safe to overwrite next chunk
  }

  // ---- write raw f32 partial O (normalization happens in combine_o) ----
  const int bg = (b << 3) + g;
  const size_t obase = ((((size_t)(tq << 5) + bg) << 10) + q0) * 64;
#pragma unroll
  for (int dj = 0; dj < 4; ++dj) {
    const int d = (dj << 4) + lr;
#pragma unroll
    for (int r = 0; r < 4; ++r) {
      const int q = (quad << 2) + r;
      Opart[obase + (size_t)q * 64 + d] = acc[dj][r];
    }
  }

  // ---- epilogue: l/l2 reduce (buffers alias Plds), write partials ----
  float* lbuf = Sbuf;          // [8w][8g][16q]  4 KB
  float* l2buf = Sbuf + 1024;  // [8w][8g][16q]  4 KB
#pragma unroll
  for (int gg = 0; gg < 8; ++gg) {
    float l = lacc[gg];
    l += __shfl_xor(l, 16, 64);
    l += __shfl_xor(l, 32, 64);
    float l2 = l2acc[gg];
    l2 += __shfl_xor(l2, 16, 64);
    l2 += __shfl_xor(l2, 32, 64);
    if (quad == 0) {
      lbuf[(w << 7) + (gg << 4) + lr] = l;
      l2buf[(w << 7) + (gg << 4) + lr] = l2;
    }
  }
  __syncthreads();
  if (lane < 16) {  // wave w reduces its own g
    float l = 0.f, l2 = 0.f;
#pragma unroll
    for (int w2 = 0; w2 < 8; ++w2) {
      l += lbuf[(w2 << 7) + (g << 4) + lr];
      l2 += l2buf[(w2 << 7) + (g << 4) + lr];
    }
    const size_t li = (((size_t)(tq << 5) + bg) << 10) + q0 + lr;
    lpart[li] = l;
    l2part[li] = l2;
  }
}

// ---- combine: O = (sum_tq Opart) / l, l/l2 full sums -> lsum/l2sum ----
__global__ __launch_bounds__(256) void combine_o(
    const float* __restrict__ Opart, const float* __restrict__ lpart,
    const float* __restrict__ l2part, u16* __restrict__ O,
    float* __restrict__ lsum, float* __restrict__ l2sum) {
  const int bg = blockIdx.x;       // [0,32)
  const int qo = blockIdx.y;       // [0,8) q-octant
  const int tid = threadIdx.x;
  const int q = (qo << 7) + (tid >> 1);
  const int d0 = (tid & 1) << 5;
  float l = 0.f, l2 = 0.f;
#pragma unroll
  for (int tq = 0; tq < 4; ++tq) {
    const size_t li = (((size_t)(tq << 5) + bg) << 10) + q;
    l += lpart[li];
    l2 += l2part[li];
  }
  const float linv = 1.f / l;
  if ((tid & 1) == 0) {
    lsum[((size_t)bg << 10) + q] = l;
    l2sum[((size_t)bg << 10) + q] = l2;
  }
  f32x4 a[8] = {};
#pragma unroll
  for (int tq = 0; tq < 4; ++tq) {
    const float* src =
        Opart + ((((size_t)(tq << 5) + bg) << 10) + q) * 64 + d0;
#pragma unroll
    for (int j = 0; j < 8; ++j) a[j] += *(const f32x4*)(src + (j << 2));
  }
  u16* dst = O + (((size_t)bg << 10) + q) * 64 + d0;
#pragma unroll
  for (int j = 0; j < 4; ++j) {
    u16x8 o;
#pragma unroll
    for (int k = 0; k < 4; ++k) {
      o[k] = f2bf(a[2 * j][k] * linv);
      o[k + 4] = f2bf(a[2 * j + 1][k] * linv);
    }
    *(u16x8*)(dst + (j << 3)) = o;
  }
}

// ---- merged: reduce per-q l/l2 -> ab, then bias2 via precomputed ws ----
__global__ __launch_bounds__(256) void stats_k(const float* __restrict__ lsum,
                                               const float* __restrict__ l2sum,
                                               const float* __restrict__ gamma,
                                               const float* __restrict__ beta,
                                               const float* __restrict__ ws,
                                               const float* __restrict__ bp,
                                               const float* __restrict__ vsum,
                                               float* __restrict__ ab,
                                               float* __restrict__ bias2) {
  const int bg = blockIdx.x;
  const int g = bg & 7;
  const int tid = threadIdx.x;
  const f32x4 l = *(const f32x4*)(lsum + ((size_t)bg << 10) + (tid << 2));
  const f32x4 l2 = *(const f32x4*)(l2sum + ((size_t)bg << 10) + (tid << 2));
  float ssq = 0.f;
#pragma unroll
  for (int k = 0; k < 4; ++k) ssq += l2[k] / (l[k] * l[k]);
#pragma unroll
  for (int off = 32; off; off >>= 1) ssq += __shfl_xor(ssq, off, 64);
  __shared__ float red[4];
  __shared__ float bt2s;
  if ((tid & 63) == 0) red[tid >> 6] = ssq;
  __syncthreads();
  if (tid == 0) {
    const float s = red[0] + red[1] + red[2] + red[3];
    const float mean = 0.0009765625f;
    const float var = s * (1.f / 1048576.f) - mean * mean;
    const float al = gamma[g] * rsqrtf(var + EPS_);
    const float bt2 = beta[g] - al * mean;
    ab[bg * 2] = al;
    ab[bg * 2 + 1] = bt2;
    bt2s = bt2;
  }
  __syncthreads();
  const float bt2 = bt2s;
  const float* vs = vsum + (bg << 6);
#pragma unroll
  for (int oo = 0; oo < 2; ++oo) {
    const int o = tid + (oo << 8);
    const float* wr = ws + (o << 6);
    float acc = 0.f;
#pragma unroll
    for (int d = 0; d < 64; d += 4) {
      const float4 vv4 = *(const float4*)(vs + d);
      const float4 ws4 = *(const float4*)(wr + d);
      acc += ws4.x * vv4.x + ws4.y * vv4.y + ws4.z * vv4.z + ws4.w * vv4.w;
    }
    bias2[(bg << 9) + o] = bp[o] + bt2 * acc;
  }
}

// ------- y = al[b,g(t)]*(Onorm @ Wp^T) + bias2, 64x64 tiles, 512 blocks ----
__global__ __launch_bounds__(256) void gemm_proj(const u16* __restrict__ O,
                                                 const u16* __restrict__ wpb,
                                                 const float* __restrict__ ab,
                                                 const float* __restrict__ bias2,
                                                 float* __restrict__ y) {
  const int b = blockIdx.z;
  const int m0 = blockIdx.y << 6;  // o: 8 tiles
  const int n0 = blockIdx.x << 6;  // t: 16 tiles
  const int gidx = blockIdx.x >> 1;
  const u16* __restrict__ Ob = O + (size_t)b * (8 * T_ * 64);
  __shared__ u16 As[64][72];
  __shared__ u16 Bs[64][72];
  const int tid = threadIdx.x;
  const int w = tid >> 6, lane = tid & 63, lr = lane & 15, lq = lane >> 4;
  const int mw = (w >> 1) << 5, nw = (w & 1) << 5;
  f32x4 acc[2][2] = {};
  for (int k0 = 0; k0 < C_; k0 += 64) {
#pragma unroll
    for (int it = 0; it < 2; ++it) {
      const int e = tid + (it << 8);
      const int r = e >> 3, c8 = e & 7;
      *(u16x8*)&As[r][c8 << 3] =
          *(const u16x8*)(wpb + (size_t)(m0 + r) * C_ + k0 + (c8 << 3));
      const int t = n0 + r;
      const int c = k0 + (c8 << 3);
      *(u16x8*)&Bs[r][c8 << 3] =
          *(const u16x8*)(Ob + (size_t)(t >> 7) * (T_ * 64) +
                          (size_t)(((t & 127) << 3) + (c >> 6)) * 64 + (c & 63));
    }
    __syncthreads();
#pragma unroll
    for (int kf = 0; kf < 2; ++kf) {
      const int ko = (kf << 5) + (lq << 3);
      s16x8 a[2], bb[2];
#pragma unroll
      for (int i = 0; i < 2; ++i) a[i] = *(const s16x8*)&As[mw + (i << 4) + lr][ko];
#pragma unroll
      for (int j = 0; j < 2; ++j) bb[j] = *(const s16x8*)&Bs[nw + (j << 4) + lr][ko];
#pragma unroll
      for (int i = 0; i < 2; ++i)
#pragma unroll
        for (int j = 0; j < 2; ++j) acc[i][j] = mfma16(a[i], bb[j], acc[i][j]);
    }
    __syncthreads();
  }
  const float al = ab[(((b << 3) + gidx) << 1)];
  const float* __restrict__ b2 = bias2 + (((b << 3) + gidx) << 9);
#pragma unroll
  for (int i = 0; i < 2; ++i) {
    const int row = mw + (i << 4) + (lq << 2);
#pragma unroll
    for (int j = 0; j < 2; ++j) {
      const int col = nw + (j << 4) + lr;
#pragma unroll
      for (int r = 0; r < 4; ++r)
        y[(size_t)b * (C_ * (size_t)T_) + (size_t)(m0 + row + r) * T_ + n0 + col] =
            acc[i][j][r] * al + b2[m0 + row + r];
    }
  }
}

extern "C" void kernel_launch(void* const* d_in, const int* in_sizes, int n_in,
                              void* d_out, int out_size, void* d_ws,
                              size_t ws_size, hipStream_t stream) {
  const float* x = (const float*)d_in[0];
  const float* wq = (const float*)d_in[1];
  const float* wk = (const float*)d_in[2];
  const float* wv = (const float*)d_in[3];
  const float* wh = (const float*)d_in[4];
  const float* gm = (const float*)d_in[5];
  const float* bt = (const float*)d_in[6];
  const float* wp = (const float*)d_in[7];
  const float* bp = (const float*)d_in[8];
  float* y = (float*)d_out;
  char* wsb = (char*)d_ws;

  u16* Qt = (u16*)(wsb + QT_OFF);
  u16* KS = (u16*)(wsb + KS_OFF);
  u16* VS = (u16*)(wsb + VS_OFF);
  u16* Xt = (u16*)(wsb + XT_OFF);
  u16* Og = (u16*)(wsb + O_OFF);
  float* ab = (float*)(wsb + AB_OFF);
  float* vsum = (float*)(wsb + VSUM_OFF);
  float* bias2 = (float*)(wsb + BIAS2_OFF);
  float* lsum = (float*)(wsb + LSUM_OFF);
  float* l2sum = (float*)(wsb + L2SUM_OFF);
  u16* Wb = (u16*)(wsb + WB_OFF);
  u16* WQb = Wb;
  u16* WKb = Wb + 262144;
  u16* WVb = Wb + 524288;
  u16* WPb = Wb + 786432;
  float* lpart = (float*)(wsb + LP_OFF);
  float* l2part = (float*)(wsb + L2P_OFF);
  float* ws = (float*)(wsb + WS_OFF);
  float* Opart = (float*)(wsb + OP_OFF);

  prep_k<<<dim3(1152), 256, 0, stream>>>(x, wq, wk, wv, wp, Wb, ws, vsum, Xt);
  gemm_qkv<<<dim3(8, 8, 12), 256, 0, stream>>>(Xt, WQb, WKb, WVb, Qt, KS, VS,
                                               vsum);
  attn_fused<<<dim3(1024), 512, 0, stream>>>(Qt, KS, VS, wh, Opart, lpart,
                                             l2part);
  combine_o<<<dim3(32, 8), 256, 0, stream>>>(Opart, lpart, l2part, Og, lsum,
                                             l2sum);
  stats_k<<<dim3(32), 256, 0, stream>>>(lsum, l2sum, gm, bt, ws, bp, vsum, ab,
                                        bias2);
  gemm_proj<<<dim3(16, 8, 4), 256, 0, stream>>>(Og, WPb, ab, bias2, y);
}

// Round 12
// 158.596 us; speedup vs baseline: 1.4093x; 1.0323x over previous
//
#include <hip/hip_runtime.h>
#include <hip/hip_bf16.h>

#define B_ 4
#define C_ 512
#define T_ 1024
#define SCALE_ 0.125f
#define EPS_ 1e-5f

typedef unsigned short u16;
typedef __attribute__((ext_vector_type(8))) unsigned short u16x8;
typedef __attribute__((ext_vector_type(4))) unsigned short u16x4;
typedef __attribute__((ext_vector_type(8))) short s16x8;
typedef __attribute__((ext_vector_type(4))) float f32x4;

// ws byte offsets (ws is 256 MiB)
#define QT_OFF    (0x0ull)         // bf16 Qt[B][T][C]   4 MB (Q pre-scaled by 1/8)
#define KS_OFF    (0x400000ull)    // bf16 KS swizzled [B][t32][half][f][lane][8] 4 MB
#define VS_OFF    (0x800000ull)    // bf16 VS swizzled [B][g][t32][dj][lane][8]   4 MB
#define XT_OFF    (0xC00000ull)    // bf16 Xt[B][T][C]   4 MB
#define O_OFF     (0x1000000ull)   // bf16 O[B][8][T][64] 4 MB (normalized, pre-affine)
#define LSUM_OFF  (0x1440000ull)   // fp32 lsum [B*8][1024]  128 KB
#define L2SUM_OFF (0x1460000ull)   // fp32 l2sum[B*8][1024]  128 KB
#define WB_OFF    (0x1480000ull)   // bf16 W[4][512][512]: wq,wk,wv,wp  2 MB
#define LP_OFF    (0x1680000ull)   // fp32 lpart [2][32][1024] 256 KB
#define L2P_OFF   (0x1700000ull)   // fp32 l2part[2][32][1024] 256 KB
#define WS_OFF    (0x1780000ull)   // fp32 ws[512][64] 128 KB
#define VSUM_OFF  (0x17A0000ull)   // fp32 vsum[B][8][64] 8 KB
#define OP_OFF    (0x2000000ull)   // fp32 Opart[2][32][1024][64] 16 MB

static __device__ __forceinline__ u16 f2bf(float f) {
  unsigned u = __float_as_uint(f);
  unsigned r = (u + 0x7fff + ((u >> 16) & 1)) >> 16;  // RNE
  return (u16)r;
}
static __device__ __forceinline__ float b2f(u16 x) {
  return __uint_as_float(((unsigned)x) << 16);
}
static __device__ __forceinline__ f32x4 mfma16(s16x8 a, s16x8 b, f32x4 c) {
  return __builtin_amdgcn_mfma_f32_16x16x32_bf16(a, b, c, 0, 0, 0);
}

// ---- prep: blocks [0,512) wcvt; [512,640) wsum+vsum-zero; [640,1152)
// transpose x -> Xt[b][t][c] bf16. Branch is block-uniform. ----
__global__ __launch_bounds__(256) void prep_k(
    const float* __restrict__ x, const float* __restrict__ wq,
    const float* __restrict__ wk, const float* __restrict__ wv,
    const float* __restrict__ wp, u16* __restrict__ wb,
    float* __restrict__ ws, float* __restrict__ vsum, u16* __restrict__ xt) {
  const int id = blockIdx.x;
  const int tid = threadIdx.x;
  __shared__ float Ts[64][65];
  if (id < 512) {  // ---- wcvt: fp32 -> bf16, 4 weight matrices ----
    const int i = (id << 8) + tid;
    const int idx = i << 3;
    const int which = idx >> 18;  // uniform per block
    const int off = idx & 262143;
    const float* s = which == 0 ? wq : which == 1 ? wk : which == 2 ? wv : wp;
    const float4 f0 = *(const float4*)(s + off);
    const float4 f1 = *(const float4*)(s + off + 4);
    u16x8 o;
    o[0] = f2bf(f0.x); o[1] = f2bf(f0.y); o[2] = f2bf(f0.z); o[3] = f2bf(f0.w);
    o[4] = f2bf(f1.x); o[5] = f2bf(f1.y); o[6] = f2bf(f1.z); o[7] = f2bf(f1.w);
    *(u16x8*)(wb + idx) = o;
  } else if (id < 640) {  // ---- ws[o][d] = sum_j wp[o][j*64+d]; zero vsum ----
    const int idx = ((id - 512) << 8) + tid;
    if (id - 512 < 8) vsum[idx] = 0.f;
    const int o = idx >> 6, d = idx & 63;
    float s = 0.f;
#pragma unroll
    for (int j = 0; j < 8; ++j) s += wp[(o << 9) + (j << 6) + d];
    ws[idx] = s;
  } else {  // ---- transpose x[b][c][t] -> Xt[b][t][c] bf16 ----
    const int id3 = id - 640;
    const int b = id3 >> 7, rem = id3 & 127;
    const int t0 = (rem & 15) << 6;
    const int c0 = (rem >> 4) << 6;
    const float* __restrict__ X = x + (size_t)b * (C_ * (size_t)T_);
    u16* __restrict__ Xt = xt + (size_t)b * (T_ * (size_t)C_);
#pragma unroll
    for (int i = 0; i < 4; ++i) {
      const int e = tid + (i << 8);
      const int r = e >> 4, c4 = e & 15;
      const float4 v =
          *(const float4*)(X + (size_t)(c0 + r) * T_ + t0 + (c4 << 2));
      Ts[r][(c4 << 2) + 0] = v.x; Ts[r][(c4 << 2) + 1] = v.y;
      Ts[r][(c4 << 2) + 2] = v.z; Ts[r][(c4 << 2) + 3] = v.w;
    }
    __syncthreads();
#pragma unroll
    for (int i = 0; i < 2; ++i) {
      const int e = tid + (i << 8);
      const int tt = e >> 3, c8 = e & 7;
      u16x8 o;
#pragma unroll
      for (int j = 0; j < 8; ++j) o[j] = f2bf(Ts[(c8 << 3) + j][tt]);
      *(u16x8*)(Xt + (size_t)(t0 + tt) * C_ + c0 + (c8 << 3)) = o;
    }
  }
}

// ---- unified QKV GEMM, 128x64 tiles -> grid 8x8x12 = 768 blocks (3/CU).
// z<4: Q -> Qt[t][o] (scaled). z in [4,8): K -> KS swizzled
// [b][t32][half][f][lane][8]. z>=8: V -> VS swizzled [b][g][t32][dj][lane]
// [8] + vsum fold (atomics). KS/VS emitted via LDS stage + coalesced
// u16x8 stores (16 chunks x 16 thr x 4 vecs). ----
__global__ __launch_bounds__(256) void gemm_qkv(
    const u16* __restrict__ xt, const u16* __restrict__ wqb,
    const u16* __restrict__ wkb, const u16* __restrict__ wvb,
    u16* __restrict__ qto, u16* __restrict__ ks, u16* __restrict__ vs,
    float* __restrict__ vsum) {
  const int z = blockIdx.z;
  const int tid = threadIdx.x;
  const int w = tid >> 6, lane = tid & 63, lr = lane & 15, lq = lane >> 4;
  const int wm = (w >> 1) << 6, wn = (w & 1) << 5;  // 2x2 waves: 64m x 32n
  __shared__ __align__(16) u16 As[128][72];
  __shared__ __align__(16) u16 Bs[64][72];
  u16* Ts = &As[0][0];  // epilogue staging tile [128][72] (aliases As)
  const u16 *Ag, *Bg;
  int m0, n0, mode, b;
  if (z < 8) {
    const int which = z >> 2;
    b = z & 3;
    Ag = xt + (size_t)b * (T_ * (size_t)C_);
    m0 = blockIdx.x << 7;  // t: 8 tiles
    Bg = which ? wkb : wqb;
    n0 = blockIdx.y << 6;  // o: 8 tiles
    mode = which;          // 0 = Q, 1 = K
  } else {
    b = z - 8;
    const int ti = (blockIdx.y << 3) | blockIdx.x;  // [0,64)
    Ag = wvb;
    m0 = (ti >> 4) << 7;  // o: 4 tiles
    Bg = xt + (size_t)b * (T_ * (size_t)C_);
    n0 = (ti & 15) << 6;  // t: 16 tiles
    mode = 2;
  }
  f32x4 acc[4][2] = {};
  for (int k0 = 0; k0 < C_; k0 += 64) {
#pragma unroll
    for (int it = 0; it < 4; ++it) {
      const int e = tid + (it << 8);
      const int r = e >> 3, c8 = (e & 7) << 3;
      *(u16x8*)&As[r][c8] =
          *(const u16x8*)(Ag + (size_t)(m0 + r) * C_ + k0 + c8);
    }
#pragma unroll
    for (int it = 0; it < 2; ++it) {
      const int e = tid + (it << 8);
      const int r = e >> 3, c8 = (e & 7) << 3;
      *(u16x8*)&Bs[r][c8] =
          *(const u16x8*)(Bg + (size_t)(n0 + r) * C_ + k0 + c8);
    }
    __syncthreads();
#pragma unroll
    for (int kf = 0; kf < 2; ++kf) {
      const int ko = (kf << 5) + (lq << 3);
      s16x8 a[4], bb[2];
#pragma unroll
      for (int i = 0; i < 4; ++i) a[i] = *(const s16x8*)&As[wm + (i << 4) + lr][ko];
#pragma unroll
      for (int j = 0; j < 2; ++j) bb[j] = *(const s16x8*)&Bs[wn + (j << 4) + lr][ko];
#pragma unroll
      for (int i = 0; i < 4; ++i)
#pragma unroll
        for (int j = 0; j < 2; ++j) acc[i][j] = mfma16(a[i], bb[j], acc[i][j]);
    }
    __syncthreads();
  }
  if (mode == 0) {
    u16* Y = qto + (size_t)b * (T_ * (size_t)C_);
#pragma unroll
    for (int i = 0; i < 4; ++i) {
      const int row = wm + (i << 4) + (lq << 2);
#pragma unroll
      for (int j = 0; j < 2; ++j) {
        const int col = wn + (j << 4) + lr;
#pragma unroll
        for (int r = 0; r < 4; ++r)
          Y[(size_t)(m0 + row + r) * C_ + n0 + col] =
              f2bf(acc[i][j][r] * SCALE_);
      }
    }
    return;
  }
  if (mode == 2) {
    // ---- vsum contribution: sum over this tile's 64 t-cols, atomic ----
#pragma unroll
    for (int i = 0; i < 4; ++i)
#pragma unroll
      for (int r = 0; r < 4; ++r) {
        float s = acc[i][0][r] + acc[i][1][r];
        s += __shfl_xor(s, 1, 64);
        s += __shfl_xor(s, 2, 64);
        s += __shfl_xor(s, 4, 64);
        s += __shfl_xor(s, 8, 64);
        if (lr == 0) {
          const int o = m0 + wm + (i << 4) + (lq << 2) + r;
          atomicAdd(&vsum[(((b << 3) | (o >> 6)) << 6) | (o & 63)], s);
        }
      }
  }
  // ---- stage output tile [m_local 128][n_local 64] (stride 72) in LDS ----
#pragma unroll
  for (int i = 0; i < 4; ++i)
#pragma unroll
    for (int j = 0; j < 2; ++j)
#pragma unroll
      for (int r = 0; r < 4; ++r)
        Ts[(wm + (i << 4) + (lq << 2) + r) * 72 + wn + (j << 4) + lr] =
            f2bf(acc[i][j][r]);
  __syncthreads();
  const int ch = tid >> 4, part = tid & 15;  // 16 chunks x 16 threads
  if (mode == 1) {
    // chunk = (t32l[4], half[2], fl[2]); lanek = u*16+part -> coalesced
    const int t32l = ch >> 2, half = (ch >> 1) & 1, fl = ch & 1;
    const int t32g = (m0 >> 5) + t32l, fg = (n0 >> 5) + fl;
    u16* dst =
        ks + (((((size_t)((b << 5) | t32g) << 1) | half) << 4 | fg) << 9);
#pragma unroll
    for (int u = 0; u < 4; ++u) {
      const int lanek = (u << 4) + part;
      const int quadk = lanek >> 4, lrk = lanek & 15;
      const int rr = ((lrk >> 2) << 3) | (half << 2) | (lrk & 3);
      const u16x8 v =
          *(const u16x8*)&Ts[((t32l << 5) + rr) * 72 + (fl << 5) + (quadk << 3)];
      *(u16x8*)(dst + (lanek << 3)) = v;
    }
  } else {
    // chunk = (gl[2], t32l[2], dj[4]); lanev = u*16+part -> coalesced
    const int gl = ch >> 3, t32l = (ch >> 2) & 1, dj = ch & 3;
    const int gg = (m0 >> 6) + gl, t32g = (n0 >> 5) + t32l;
    u16* dst =
        vs + (((((size_t)((b << 3) | gg) << 5) | t32g) << 2 | dj) << 9);
#pragma unroll
    for (int u = 0; u < 4; ++u) {
      const int lanev = (u << 4) + part;
      const int quadv = lanev >> 4, lrv = lanev & 15;
      const u16x8 v = *(const u16x8*)&Ts[((gl << 6) + (dj << 4) + lrv) * 72 +
                                         (t32l << 5) + (quadv << 3)];
      *(u16x8*)(dst + (lanev << 3)) = v;
    }
  }
}

// ---- FUSED attention: tq=2 t-halves (grid 512 = 2 blocks/CU, 4 chunks of
// 128 t -> Opart traffic halved to 16 MB) + P-LDS XOR SWIZZLE: the old
// [8][16][136] layout had bank = 4*(lr+quad) mod 32 on BOTH P-write and
// PV P-read (8-way conflict, 1.18M conflict cycles/dispatch). Fix: XOR the
// 8-u16 column group with (lr&7) on both sides (rows indexed by lr on both
// sides -> involution matches). ----
__global__ __launch_bounds__(512, 4) void attn_fused(
    const u16* __restrict__ Qt, const u16* __restrict__ KS,
    const u16* __restrict__ VS, const float* __restrict__ wh,
    float* __restrict__ Opart, float* __restrict__ lpart,
    float* __restrict__ l2part) {
  const int id = blockIdx.x;
  const int xcd = id & 7;
  const int b = xcd >> 1;
  const int hi = id >> 3;                       // [0,64)
  const int qb = ((xcd & 1) << 5) | (hi & 31);  // [0,64)
  const int tq = hi >> 5;                       // [0,2) t-half
  const int q0 = qb << 4;
  const int tid = threadIdx.x;
  const int w = tid >> 6, lane = tid & 63;
  const int lr = lane & 15, quad = lane >> 4;

  __shared__ __align__(16) u16 Qs[16][522];       // 16704 B
  __shared__ __align__(16) u16 Plds[8][16][136];  // 34816 B
  float* Sbuf = (float*)&Plds[0][0][0];  // epilogue alias (Plds dead by then)

  {  // stage Q tile (16 x 512)
    const u16* Qb = Qt + ((size_t)b * T_ + q0) * C_;
    for (int i = tid; i < 1024; i += 512) {
      const int r = i >> 6, c8 = i & 63;
      *(u16x8*)&Qs[r][c8 << 3] = *(const u16x8*)(Qb + (size_t)r * C_ + (c8 << 3));
    }
  }

  const u16* __restrict__ Qrow = &Qs[lr][quad << 3];
  const int g = w;  // PV head owned by this wave
  const int win = w >> 1, half = w & 1;  // QK: window pair, K-half
  const int swz = lr & 7;                // P-LDS bank swizzle key (row = lr)
  const u16* __restrict__ Vc =
      VS + (((size_t)((b << 3) | g)) << 16) + (lane << 3);

  float lacc[8] = {}, l2acc[8] = {};
  f32x4 acc[4] = {};

  __syncthreads();

  for (int c = 0; c < 4; ++c) {
    // ---- QK + mix + exp: K loads lane-contiguous from KS ----
    const int t32k = (tq << 4) + (c << 2) + win;
    const u16* __restrict__ Kc =
        KS + (((size_t)((((b << 5) | t32k) << 1) | half)) << 13) + (lane << 3);
    f32x4 m[8] = {};
#pragma unroll 4
    for (int h = 0; h < 8; ++h) {
      f32x4 a0 = {0.f, 0.f, 0.f, 0.f};
      const s16x8 qf0 = *(const s16x8*)(Qrow + (h << 6));
      const s16x8 k0 = *(const s16x8*)(Kc + (h << 10));
      a0 = mfma16(k0, qf0, a0);
      const s16x8 qf1 = *(const s16x8*)(Qrow + (h << 6) + 32);
      const s16x8 k1 = *(const s16x8*)(Kc + (h << 10) + 512);
      a0 = mfma16(k1, qf1, a0);
#pragma unroll
      for (int gg = 0; gg < 8; ++gg) {
        const float wgh = wh[(gg << 3) + h];  // uniform -> SGPR
        m[gg] += a0 * wgh;
      }
    }
    // lane's t slots: win*32 + quad*8 + half*4 + {0..3}; q = lr
    const int wgrp = ((win << 2) | quad) ^ swz;  // swizzled 8-u16 group
#pragma unroll
    for (int gg = 0; gg < 8; ++gg) {
      f32x4 e0;
#pragma unroll
      for (int k = 0; k < 4; ++k) e0[k] = __expf(m[gg][k]);
      u16x4 o;
#pragma unroll
      for (int k = 0; k < 4; ++k) o[k] = f2bf(e0[k]);
      *(u16x4*)&Plds[gg][lr][(wgrp << 3) + (half << 2)] = o;
      lacc[gg] += e0[0] + e0[1] + e0[2] + e0[3];
      l2acc[gg] += e0[0] * e0[0] + e0[1] * e0[1] + e0[2] * e0[2] + e0[3] * e0[3];
    }
    __syncthreads();  // P ready
    // ---- PV: V loads lane-contiguous from VS ----
#pragma unroll
    for (int tw = 0; tw < 4; ++tw) {
      const int t32v = (tq << 4) + (c << 2) + tw;
      const int rgrp = ((tw << 2) | quad) ^ swz;
      const s16x8 pa = *(const s16x8*)&Plds[g][lr][rgrp << 3];
#pragma unroll
      for (int dj = 0; dj < 4; ++dj) {
        const s16x8 vb =
            *(const s16x8*)(Vc + ((size_t)t32v << 11) + (dj << 9));
        acc[dj] = mfma16(pa, vb, acc[dj]);
      }
    }
    __syncthreads();  // P consumed, safe to overwrite next chunk
  }

  // ---- write raw f32 partial O (normalization happens in combine_o) ----
  const int bg = (b << 3) + g;
  const size_t obase = ((((size_t)(tq << 5) + bg) << 10) + q0) * 64;
#pragma unroll
  for (int dj = 0; dj < 4; ++dj) {
    const int d = (dj << 4) + lr;
#pragma unroll
    for (int r = 0; r < 4; ++r) {
      const int q = (quad << 2) + r;
      Opart[obase + (size_t)q * 64 + d] = acc[dj][r];
    }
  }

  // ---- epilogue: l/l2 reduce (buffers alias Plds), write partials ----
  float* lbuf = Sbuf;          // [8w][8g][16q]  4 KB
  float* l2buf = Sbuf + 1024;  // [8w][8g][16q]  4 KB
#pragma unroll
  for (int gg = 0; gg < 8; ++gg) {
    float l = lacc[gg];
    l += __shfl_xor(l, 16, 64);
    l += __shfl_xor(l, 32, 64);
    float l2 = l2acc[gg];
    l2 += __shfl_xor(l2, 16, 64);
    l2 += __shfl_xor(l2, 32, 64);
    if (quad == 0) {
      lbuf[(w << 7) + (gg << 4) + lr] = l;
      l2buf[(w << 7) + (gg << 4) + lr] = l2;
    }
  }
  __syncthreads();
  if (lane < 16) {  // wave w reduces its own g
    float l = 0.f, l2 = 0.f;
#pragma unroll
    for (int w2 = 0; w2 < 8; ++w2) {
      l += lbuf[(w2 << 7) + (g << 4) + lr];
      l2 += l2buf[(w2 << 7) + (g << 4) + lr];
    }
    const size_t li = (((size_t)(tq << 5) + bg) << 10) + q0 + lr;
    lpart[li] = l;
    l2part[li] = l2;
  }
}

// ---- combine: O = (sum_tq Opart) / l, l/l2 full sums -> lsum/l2sum ----
__global__ __launch_bounds__(256) void combine_o(
    const float* __restrict__ Opart, const float* __restrict__ lpart,
    const float* __restrict__ l2part, u16* __restrict__ O,
    float* __restrict__ lsum, float* __restrict__ l2sum) {
  const int bg = blockIdx.x;       // [0,32)
  const int qo = blockIdx.y;       // [0,8) q-octant
  const int tid = threadIdx.x;
  const int q = (qo << 7) + (tid >> 1);
  const int d0 = (tid & 1) << 5;
  float l = 0.f, l2 = 0.f;
#pragma unroll
  for (int tq = 0; tq < 2; ++tq) {
    const size_t li = (((size_t)(tq << 5) + bg) << 10) + q;
    l += lpart[li];
    l2 += l2part[li];
  }
  const float linv = 1.f / l;
  if ((tid & 1) == 0) {
    lsum[((size_t)bg << 10) + q] = l;
    l2sum[((size_t)bg << 10) + q] = l2;
  }
  f32x4 a[8] = {};
#pragma unroll
  for (int tq = 0; tq < 2; ++tq) {
    const float* src =
        Opart + ((((size_t)(tq << 5) + bg) << 10) + q) * 64 + d0;
#pragma unroll
    for (int j = 0; j < 8; ++j) a[j] += *(const f32x4*)(src + (j << 2));
  }
  u16* dst = O + (((size_t)bg << 10) + q) * 64 + d0;
#pragma unroll
  for (int j = 0; j < 4; ++j) {
    u16x8 o;
#pragma unroll
    for (int k = 0; k < 4; ++k) {
      o[k] = f2bf(a[2 * j][k] * linv);
      o[k + 4] = f2bf(a[2 * j + 1][k] * linv);
    }
    *(u16x8*)(dst + (j << 3)) = o;
  }
}

// ------- y = al*(Onorm @ Wp^T) + bias2, 64x64 tiles; stats (InstanceNorm
// alpha/beta + bias2) folded into the prologue (redundant per block: 8 KB
// lsum/l2sum read + 64 ws.vsum dots -- cheaper than a dedicated launch). --
__global__ __launch_bounds__(256) void gemm_proj(
    const u16* __restrict__ O, const u16* __restrict__ wpb,
    const float* __restrict__ lsum, const float* __restrict__ l2sum,
    const float* __restrict__ gamma, const float* __restrict__ beta,
    const float* __restrict__ ws, const float* __restrict__ bp,
    const float* __restrict__ vsum, float* __restrict__ y) {
  const int b = blockIdx.z;
  const int m0 = blockIdx.y << 6;  // o: 8 tiles
  const int n0 = blockIdx.x << 6;  // t: 16 tiles
  const int gidx = blockIdx.x >> 1;
  const int bg = (b << 3) + gidx;
  const u16* __restrict__ Ob = O + (size_t)b * (8 * T_ * 64);
  __shared__ u16 As[64][72];
  __shared__ u16 Bs[64][72];
  __shared__ float red[4];
  __shared__ float albc[2];
  __shared__ float b2s[64];
  const int tid = threadIdx.x;
  const int w = tid >> 6, lane = tid & 63, lr = lane & 15, lq = lane >> 4;
  const int mw = (w >> 1) << 5, nw = (w & 1) << 5;
  // ---- prologue: ssq reduce -> al, bt2; then bias2 slice ----
  {
    const f32x4 l = *(const f32x4*)(lsum + ((size_t)bg << 10) + (tid << 2));
    const f32x4 l2 = *(const f32x4*)(l2sum + ((size_t)bg << 10) + (tid << 2));
    float ssq = 0.f;
#pragma unroll
    for (int k = 0; k < 4; ++k) ssq += l2[k] / (l[k] * l[k]);
#pragma unroll
    for (int off = 32; off; off >>= 1) ssq += __shfl_xor(ssq, off, 64);
    if (lane == 0) red[w] = ssq;
  }
  __syncthreads();
  if (tid == 0) {
    const float s = red[0] + red[1] + red[2] + red[3];
    const float mean = 0.0009765625f;
    const float var = s * (1.f / 1048576.f) - mean * mean;
    const float al = gamma[gidx] * rsqrtf(var + EPS_);
    albc[0] = al;
    albc[1] = beta[gidx] - al * mean;
  }
  __syncthreads();
  if (tid < 64) {
    const int o = m0 + tid;
    const float* wr = ws + (o << 6);
    const float* vsr = vsum + (bg << 6);
    float acc = 0.f;
#pragma unroll
    for (int d = 0; d < 64; d += 4) {
      const float4 vv4 = *(const float4*)(vsr + d);
      const float4 ws4 = *(const float4*)(wr + d);
      acc += ws4.x * vv4.x + ws4.y * vv4.y + ws4.z * vv4.z + ws4.w * vv4.w;
    }
    b2s[tid] = bp[o] + albc[1] * acc;
  }
  f32x4 acc[2][2] = {};
  for (int k0 = 0; k0 < C_; k0 += 64) {
    if (k0 == 0) __syncthreads();  // b2s/albc visible; staging below re-syncs
#pragma unroll
    for (int it = 0; it < 2; ++it) {
      const int e = tid + (it << 8);
      const int r = e >> 3, c8 = e & 7;
      *(u16x8*)&As[r][c8 << 3] =
          *(const u16x8*)(wpb + (size_t)(m0 + r) * C_ + k0 + (c8 << 3));
      const int t = n0 + r;
      const int c = k0 + (c8 << 3);
      *(u16x8*)&Bs[r][c8 << 3] =
          *(const u16x8*)(Ob + (size_t)(t >> 7) * (T_ * 64) +
                          (size_t)(((t & 127) << 3) + (c >> 6)) * 64 + (c & 63));
    }
    __syncthreads();
#pragma unroll
    for (int kf = 0; kf < 2; ++kf) {
      const int ko = (kf << 5) + (lq << 3);
      s16x8 a[2], bb[2];
#pragma unroll
      for (int i = 0; i < 2; ++i) a[i] = *(const s16x8*)&As[mw + (i << 4) + lr][ko];
#pragma unroll
      for (int j = 0; j < 2; ++j) bb[j] = *(const s16x8*)&Bs[nw + (j << 4) + lr][ko];
#pragma unroll
      for (int i = 0; i < 2; ++i)
#pragma unroll
        for (int j = 0; j < 2; ++j) acc[i][j] = mfma16(a[i], bb[j], acc[i][j]);
    }
    __syncthreads();
  }
  const float al = albc[0];
#pragma unroll
  for (int i = 0; i < 2; ++i) {
    const int row = mw + (i << 4) + (lq << 2);
#pragma unroll
    for (int j = 0; j < 2; ++j) {
      const int col = nw + (j << 4) + lr;
#pragma unroll
      for (int r = 0; r < 4; ++r)
        y[(size_t)b * (C_ * (size_t)T_) + (size_t)(m0 + row + r) * T_ + n0 + col] =
            acc[i][j][r] * al + b2s[row + r];
    }
  }
}

extern "C" void kernel_launch(void* const* d_in, const int* in_sizes, int n_in,
                              void* d_out, int out_size, void* d_ws,
                              size_t ws_size, hipStream_t stream) {
  const float* x = (const float*)d_in[0];
  const float* wq = (const float*)d_in[1];
  const float* wk = (const float*)d_in[2];
  const float* wv = (const float*)d_in[3];
  const float* wh = (const float*)d_in[4];
  const float* gm = (const float*)d_in[5];
  const float* bt = (const float*)d_in[6];
  const float* wp = (const float*)d_in[7];
  const float* bp = (const float*)d_in[8];
  float* y = (float*)d_out;
  char* wsb = (char*)d_ws;

  u16* Qt = (u16*)(wsb + QT_OFF);
  u16* KS = (u16*)(wsb + KS_OFF);
  u16* VS = (u16*)(wsb + VS_OFF);
  u16* Xt = (u16*)(wsb + XT_OFF);
  u16* Og = (u16*)(wsb + O_OFF);
  float* vsum = (float*)(wsb + VSUM_OFF);
  float* lsum = (float*)(wsb + LSUM_OFF);
  float* l2sum = (float*)(wsb + L2SUM_OFF);
  u16* Wb = (u16*)(wsb + WB_OFF);
  u16* WQb = Wb;
  u16* WKb = Wb + 262144;
  u16* WVb = Wb + 524288;
  u16* WPb = Wb + 786432;
  float* lpart = (float*)(wsb + LP_OFF);
  float* l2part = (float*)(wsb + L2P_OFF);
  float* ws = (float*)(wsb + WS_OFF);
  float* Opart = (float*)(wsb + OP_OFF);

  prep_k<<<dim3(1152), 256, 0, stream>>>(x, wq, wk, wv, wp, Wb, ws, vsum, Xt);
  gemm_qkv<<<dim3(8, 8, 12), 256, 0, stream>>>(Xt, WQb, WKb, WVb, Qt, KS, VS,
                                               vsum);
  attn_fused<<<dim3(512), 512, 0, stream>>>(Qt, KS, VS, wh, Opart, lpart,
                                            l2part);
  combine_o<<<dim3(32, 8), 256, 0, stream>>>(Opart, lpart, l2part, Og, lsum,
                                             l2sum);
  gemm_proj<<<dim3(16, 8, 4), 256, 0, stream>>>(Og, WPb, lsum, l2sum, gm, bt,
                                                ws, bp, vsum, y);
}

// Round 13
// 150.142 us; speedup vs baseline: 1.4887x; 1.0563x over previous
//
#include <hip/hip_runtime.h>
#include <hip/hip_bf16.h>

#define B_ 4
#define C_ 512
#define T_ 1024
#define SCALE_ 0.125f
#define EPS_ 1e-5f

typedef unsigned short u16;
typedef __attribute__((ext_vector_type(8))) unsigned short u16x8;
typedef __attribute__((ext_vector_type(4))) unsigned short u16x4;
typedef __attribute__((ext_vector_type(8))) short s16x8;
typedef __attribute__((ext_vector_type(4))) float f32x4;

// ws byte offsets (ws is 256 MiB)
#define QT_OFF    (0x0ull)         // bf16 Qt[B][T][C]   4 MB (Q pre-scaled by 1/8)
#define KS_OFF    (0x400000ull)    // bf16 KS swizzled [B][t32][half][f][lane][8] 4 MB
#define VS_OFF    (0x800000ull)    // bf16 VS swizzled [B][g][t32][dj][lane][8]   4 MB
#define XT_OFF    (0xC00000ull)    // bf16 Xt[B][T][C]   4 MB
#define WB_OFF    (0x1480000ull)   // bf16 W[4][512][512]: wq,wk,wv,wp  2 MB
#define LP_OFF    (0x1680000ull)   // fp32 lpart [2][32][1024] 256 KB
#define L2P_OFF   (0x1700000ull)   // fp32 l2part[2][32][1024] 256 KB
#define WS_OFF    (0x1780000ull)   // fp32 ws[512][64] 128 KB
#define VSUM_OFF  (0x17A0000ull)   // fp32 vsum[B][8][64] 8 KB
#define OP_OFF    (0x2000000ull)   // fp32 Opart[2][32][1024][64] 16 MB

static __device__ __forceinline__ u16 f2bf(float f) {
  unsigned u = __float_as_uint(f);
  unsigned r = (u + 0x7fff + ((u >> 16) & 1)) >> 16;  // RNE
  return (u16)r;
}
static __device__ __forceinline__ float b2f(u16 x) {
  return __uint_as_float(((unsigned)x) << 16);
}
static __device__ __forceinline__ f32x4 mfma16(s16x8 a, s16x8 b, f32x4 c) {
  return __builtin_amdgcn_mfma_f32_16x16x32_bf16(a, b, c, 0, 0, 0);
}
// lgkmcnt(0) + raw barrier: LDS ops ordered, but in-flight GLOBAL loads (to
// regs) legitimately cross the barrier -- the T3 2-phase pipeline primitive.
#define BARSYNC()                                       \
  {                                                     \
    asm volatile("s_waitcnt lgkmcnt(0)" ::: "memory");  \
    __builtin_amdgcn_s_barrier();                       \
  }

// ---- prep: blocks [0,512) wcvt; [512,640) wsum+vsum-zero; [640,1152)
// transpose x -> Xt[b][t][c] bf16. Branch is block-uniform. ----
__global__ __launch_bounds__(256) void prep_k(
    const float* __restrict__ x, const float* __restrict__ wq,
    const float* __restrict__ wk, const float* __restrict__ wv,
    const float* __restrict__ wp, u16* __restrict__ wb,
    float* __restrict__ ws, float* __restrict__ vsum, u16* __restrict__ xt) {
  const int id = blockIdx.x;
  const int tid = threadIdx.x;
  __shared__ float Ts[64][65];
  if (id < 512) {  // ---- wcvt: fp32 -> bf16, 4 weight matrices ----
    const int i = (id << 8) + tid;
    const int idx = i << 3;
    const int which = idx >> 18;  // uniform per block
    const int off = idx & 262143;
    const float* s = which == 0 ? wq : which == 1 ? wk : which == 2 ? wv : wp;
    const float4 f0 = *(const float4*)(s + off);
    const float4 f1 = *(const float4*)(s + off + 4);
    u16x8 o;
    o[0] = f2bf(f0.x); o[1] = f2bf(f0.y); o[2] = f2bf(f0.z); o[3] = f2bf(f0.w);
    o[4] = f2bf(f1.x); o[5] = f2bf(f1.y); o[6] = f2bf(f1.z); o[7] = f2bf(f1.w);
    *(u16x8*)(wb + idx) = o;
  } else if (id < 640) {  // ---- ws[o][d] = sum_j wp[o][j*64+d]; zero vsum ----
    const int idx = ((id - 512) << 8) + tid;
    if (id - 512 < 8) vsum[idx] = 0.f;
    const int o = idx >> 6, d = idx & 63;
    float s = 0.f;
#pragma unroll
    for (int j = 0; j < 8; ++j) s += wp[(o << 9) + (j << 6) + d];
    ws[idx] = s;
  } else {  // ---- transpose x[b][c][t] -> Xt[b][t][c] bf16 ----
    const int id3 = id - 640;
    const int b = id3 >> 7, rem = id3 & 127;
    const int t0 = (rem & 15) << 6;
    const int c0 = (rem >> 4) << 6;
    const float* __restrict__ X = x + (size_t)b * (C_ * (size_t)T_);
    u16* __restrict__ Xt = xt + (size_t)b * (T_ * (size_t)C_);
#pragma unroll
    for (int i = 0; i < 4; ++i) {
      const int e = tid + (i << 8);
      const int r = e >> 4, c4 = e & 15;
      const float4 v =
          *(const float4*)(X + (size_t)(c0 + r) * T_ + t0 + (c4 << 2));
      Ts[r][(c4 << 2) + 0] = v.x; Ts[r][(c4 << 2) + 1] = v.y;
      Ts[r][(c4 << 2) + 2] = v.z; Ts[r][(c4 << 2) + 3] = v.w;
    }
    __syncthreads();
#pragma unroll
    for (int i = 0; i < 2; ++i) {
      const int e = tid + (i << 8);
      const int tt = e >> 3, c8 = e & 7;
      u16x8 o;
#pragma unroll
      for (int j = 0; j < 8; ++j) o[j] = f2bf(Ts[(c8 << 3) + j][tt]);
      *(u16x8*)(Xt + (size_t)(t0 + tt) * C_ + c0 + (c8 << 3)) = o;
    }
  }
}

// ---- unified QKV GEMM, 128x64 tiles, 768 blocks (3/CU), 2-PHASE REGISTER
// PREFETCH: per K-step {bar; write regs->LDS; issue loads k+1; lgkm+bar;
// MFMA} with raw s_barrier so the k+1 global loads stay in flight across
// the MFMA phase (the __syncthreads vmcnt-drain was exposing full load
// latency every step). z<4: Q -> Qt. z in [4,8): K -> KS swizzled.
// z>=8: V -> VS swizzled + vsum fold. ----
__global__ __launch_bounds__(256) void gemm_qkv(
    const u16* __restrict__ xt, const u16* __restrict__ wqb,
    const u16* __restrict__ wkb, const u16* __restrict__ wvb,
    u16* __restrict__ qto, u16* __restrict__ ks, u16* __restrict__ vs,
    float* __restrict__ vsum) {
  const int z = blockIdx.z;
  const int tid = threadIdx.x;
  const int w = tid >> 6, lane = tid & 63, lr = lane & 15, lq = lane >> 4;
  const int wm = (w >> 1) << 6, wn = (w & 1) << 5;  // 2x2 waves: 64m x 32n
  __shared__ __align__(16) u16 As[128][72];
  __shared__ __align__(16) u16 Bs[64][72];
  u16* Ts = &As[0][0];  // epilogue staging tile [128][72] (aliases As)
  const u16 *Ag, *Bg;
  int m0, n0, mode, b;
  if (z < 8) {
    const int which = z >> 2;
    b = z & 3;
    Ag = xt + (size_t)b * (T_ * (size_t)C_);
    m0 = blockIdx.x << 7;  // t: 8 tiles
    Bg = which ? wkb : wqb;
    n0 = blockIdx.y << 6;  // o: 8 tiles
    mode = which;          // 0 = Q, 1 = K
  } else {
    b = z - 8;
    const int ti = (blockIdx.y << 3) | blockIdx.x;  // [0,64)
    Ag = wvb;
    m0 = (ti >> 4) << 7;  // o: 4 tiles
    Bg = xt + (size_t)b * (T_ * (size_t)C_);
    n0 = (ti & 15) << 6;  // t: 16 tiles
    mode = 2;
  }
  u16x8 rA[4], rB[2];
#define LOADQ(K)                                                          \
  {                                                                       \
    _Pragma("unroll") for (int it = 0; it < 4; ++it) {                    \
      const int e = tid + (it << 8);                                      \
      const int r = e >> 3, c8 = (e & 7) << 3;                            \
      rA[it] = *(const u16x8*)(Ag + (size_t)(m0 + r) * C_ + (K) + c8);    \
    }                                                                     \
    _Pragma("unroll") for (int it = 0; it < 2; ++it) {                    \
      const int e = tid + (it << 8);                                      \
      const int r = e >> 3, c8 = (e & 7) << 3;                            \
      rB[it] = *(const u16x8*)(Bg + (size_t)(n0 + r) * C_ + (K) + c8);    \
    }                                                                     \
  }
  f32x4 acc[4][2] = {};
  LOADQ(0);
  for (int k0 = 0; k0 < C_; k0 += 64) {
    if (k0) BARSYNC();  // all waves' prev ds_reads consumed
#pragma unroll
    for (int it = 0; it < 4; ++it) {
      const int e = tid + (it << 8);
      *(u16x8*)&As[e >> 3][(e & 7) << 3] = rA[it];
    }
#pragma unroll
    for (int it = 0; it < 2; ++it) {
      const int e = tid + (it << 8);
      *(u16x8*)&Bs[e >> 3][(e & 7) << 3] = rB[it];
    }
    if (k0 < C_ - 64) LOADQ(k0 + 64);  // in flight across MFMA phase
    BARSYNC();  // ds_writes committed in all waves
#pragma unroll
    for (int kf = 0; kf < 2; ++kf) {
      const int ko = (kf << 5) + (lq << 3);
      s16x8 a[4], bb[2];
#pragma unroll
      for (int i = 0; i < 4; ++i) a[i] = *(const s16x8*)&As[wm + (i << 4) + lr][ko];
#pragma unroll
      for (int j = 0; j < 2; ++j) bb[j] = *(const s16x8*)&Bs[wn + (j << 4) + lr][ko];
#pragma unroll
      for (int i = 0; i < 4; ++i)
#pragma unroll
        for (int j = 0; j < 2; ++j) acc[i][j] = mfma16(a[i], bb[j], acc[i][j]);
    }
  }
#undef LOADQ
  if (mode == 0) {
    u16* Y = qto + (size_t)b * (T_ * (size_t)C_);
#pragma unroll
    for (int i = 0; i < 4; ++i) {
      const int row = wm + (i << 4) + (lq << 2);
#pragma unroll
      for (int j = 0; j < 2; ++j) {
        const int col = wn + (j << 4) + lr;
#pragma unroll
        for (int r = 0; r < 4; ++r)
          Y[(size_t)(m0 + row + r) * C_ + n0 + col] =
              f2bf(acc[i][j][r] * SCALE_);
      }
    }
    return;
  }
  if (mode == 2) {
    // ---- vsum contribution: sum over this tile's 64 t-cols, atomic ----
#pragma unroll
    for (int i = 0; i < 4; ++i)
#pragma unroll
      for (int r = 0; r < 4; ++r) {
        float s = acc[i][0][r] + acc[i][1][r];
        s += __shfl_xor(s, 1, 64);
        s += __shfl_xor(s, 2, 64);
        s += __shfl_xor(s, 4, 64);
        s += __shfl_xor(s, 8, 64);
        if (lr == 0) {
          const int o = m0 + wm + (i << 4) + (lq << 2) + r;
          atomicAdd(&vsum[(((b << 3) | (o >> 6)) << 6) | (o & 63)], s);
        }
      }
  }
  BARSYNC();  // all waves done reading As before Ts overwrite
  // ---- stage output tile [m_local 128][n_local 64] (stride 72) in LDS ----
#pragma unroll
  for (int i = 0; i < 4; ++i)
#pragma unroll
    for (int j = 0; j < 2; ++j)
#pragma unroll
      for (int r = 0; r < 4; ++r)
        Ts[(wm + (i << 4) + (lq << 2) + r) * 72 + wn + (j << 4) + lr] =
            f2bf(acc[i][j][r]);
  __syncthreads();
  const int ch = tid >> 4, part = tid & 15;  // 16 chunks x 16 threads
  if (mode == 1) {
    // chunk = (t32l[4], half[2], fl[2]); lanek = u*16+part -> coalesced
    const int t32l = ch >> 2, half = (ch >> 1) & 1, fl = ch & 1;
    const int t32g = (m0 >> 5) + t32l, fg = (n0 >> 5) + fl;
    u16* dst =
        ks + (((((size_t)((b << 5) | t32g) << 1) | half) << 4 | fg) << 9);
#pragma unroll
    for (int u = 0; u < 4; ++u) {
      const int lanek = (u << 4) + part;
      const int quadk = lanek >> 4, lrk = lanek & 15;
      const int rr = ((lrk >> 2) << 3) | (half << 2) | (lrk & 3);
      const u16x8 v =
          *(const u16x8*)&Ts[((t32l << 5) + rr) * 72 + (fl << 5) + (quadk << 3)];
      *(u16x8*)(dst + (lanek << 3)) = v;
    }
  } else {
    // chunk = (gl[2], t32l[2], dj[4]); lanev = u*16+part -> coalesced
    const int gl = ch >> 3, t32l = (ch >> 2) & 1, dj = ch & 3;
    const int gg = (m0 >> 6) + gl, t32g = (n0 >> 5) + t32l;
    u16* dst =
        vs + (((((size_t)((b << 3) | gg) << 5) | t32g) << 2 | dj) << 9);
#pragma unroll
    for (int u = 0; u < 4; ++u) {
      const int lanev = (u << 4) + part;
      const int quadv = lanev >> 4, lrv = lanev & 15;
      const u16x8 v = *(const u16x8*)&Ts[((gl << 6) + (dj << 4) + lrv) * 72 +
                                         (t32l << 5) + (quadv << 3)];
      *(u16x8*)(dst + (lanev << 3)) = v;
    }
  }
}

// ---- FUSED attention (unchanged from R12, 51.4us known-good). ----
__global__ __launch_bounds__(512, 4) void attn_fused(
    const u16* __restrict__ Qt, const u16* __restrict__ KS,
    const u16* __restrict__ VS, const float* __restrict__ wh,
    float* __restrict__ Opart, float* __restrict__ lpart,
    float* __restrict__ l2part) {
  const int id = blockIdx.x;
  const int xcd = id & 7;
  const int b = xcd >> 1;
  const int hi = id >> 3;                       // [0,64)
  const int qb = ((xcd & 1) << 5) | (hi & 31);  // [0,64)
  const int tq = hi >> 5;                       // [0,2) t-half
  const int q0 = qb << 4;
  const int tid = threadIdx.x;
  const int w = tid >> 6, lane = tid & 63;
  const int lr = lane & 15, quad = lane >> 4;

  __shared__ __align__(16) u16 Qs[16][522];       // 16704 B
  __shared__ __align__(16) u16 Plds[8][16][136];  // 34816 B
  float* Sbuf = (float*)&Plds[0][0][0];  // epilogue alias (Plds dead by then)

  {  // stage Q tile (16 x 512)
    const u16* Qb = Qt + ((size_t)b * T_ + q0) * C_;
    for (int i = tid; i < 1024; i += 512) {
      const int r = i >> 6, c8 = i & 63;
      *(u16x8*)&Qs[r][c8 << 3] = *(const u16x8*)(Qb + (size_t)r * C_ + (c8 << 3));
    }
  }

  const u16* __restrict__ Qrow = &Qs[lr][quad << 3];
  const int g = w;  // PV head owned by this wave
  const int win = w >> 1, half = w & 1;  // QK: window pair, K-half
  const int swz = lr & 7;                // P-LDS bank swizzle key (row = lr)
  const u16* __restrict__ Vc =
      VS + (((size_t)((b << 3) | g)) << 16) + (lane << 3);

  float lacc[8] = {}, l2acc[8] = {};
  f32x4 acc[4] = {};

  __syncthreads();

  for (int c = 0; c < 4; ++c) {
    // ---- QK + mix + exp: K loads lane-contiguous from KS ----
    const int t32k = (tq << 4) + (c << 2) + win;
    const u16* __restrict__ Kc =
        KS + (((size_t)((((b << 5) | t32k) << 1) | half)) << 13) + (lane << 3);
    f32x4 m[8] = {};
#pragma unroll 4
    for (int h = 0; h < 8; ++h) {
      f32x4 a0 = {0.f, 0.f, 0.f, 0.f};
      const s16x8 qf0 = *(const s16x8*)(Qrow + (h << 6));
      const s16x8 k0 = *(const s16x8*)(Kc + (h << 10));
      a0 = mfma16(k0, qf0, a0);
      const s16x8 qf1 = *(const s16x8*)(Qrow + (h << 6) + 32);
      const s16x8 k1 = *(const s16x8*)(Kc + (h << 10) + 512);
      a0 = mfma16(k1, qf1, a0);
#pragma unroll
      for (int gg = 0; gg < 8; ++gg) {
        const float wgh = wh[(gg << 3) + h];  // uniform -> SGPR
        m[gg] += a0 * wgh;
      }
    }
    // lane's t slots: win*32 + quad*8 + half*4 + {0..3}; q = lr
    const int wgrp = ((win << 2) | quad) ^ swz;  // swizzled 8-u16 group
#pragma unroll
    for (int gg = 0; gg < 8; ++gg) {
      f32x4 e0;
#pragma unroll
      for (int k = 0; k < 4; ++k) e0[k] = __expf(m[gg][k]);
      u16x4 o;
#pragma unroll
      for (int k = 0; k < 4; ++k) o[k] = f2bf(e0[k]);
      *(u16x4*)&Plds[gg][lr][(wgrp << 3) + (half << 2)] = o;
      lacc[gg] += e0[0] + e0[1] + e0[2] + e0[3];
      l2acc[gg] += e0[0] * e0[0] + e0[1] * e0[1] + e0[2] * e0[2] + e0[3] * e0[3];
    }
    __syncthreads();  // P ready
    // ---- PV: V loads lane-contiguous from VS ----
#pragma unroll
    for (int tw = 0; tw < 4; ++tw) {
      const int t32v = (tq << 4) + (c << 2) + tw;
      const int rgrp = ((tw << 2) | quad) ^ swz;
      const s16x8 pa = *(const s16x8*)&Plds[g][lr][rgrp << 3];
#pragma unroll
      for (int dj = 0; dj < 4; ++dj) {
        const s16x8 vb =
            *(const s16x8*)(Vc + ((size_t)t32v << 11) + (dj << 9));
        acc[dj] = mfma16(pa, vb, acc[dj]);
      }
    }
    __syncthreads();  // P consumed, safe to overwrite next chunk
  }

  // ---- write raw f32 partial O (normalization happens in gemm_proj) ----
  const int bg = (b << 3) + g;
  const size_t obase = ((((size_t)(tq << 5) + bg) << 10) + q0) * 64;
#pragma unroll
  for (int dj = 0; dj < 4; ++dj) {
    const int d = (dj << 4) + lr;
#pragma unroll
    for (int r = 0; r < 4; ++r) {
      const int q = (quad << 2) + r;
      Opart[obase + (size_t)q * 64 + d] = acc[dj][r];
    }
  }

  // ---- epilogue: l/l2 reduce (buffers alias Plds), write partials ----
  float* lbuf = Sbuf;          // [8w][8g][16q]  4 KB
  float* l2buf = Sbuf + 1024;  // [8w][8g][16q]  4 KB
#pragma unroll
  for (int gg = 0; gg < 8; ++gg) {
    float l = lacc[gg];
    l += __shfl_xor(l, 16, 64);
    l += __shfl_xor(l, 32, 64);
    float l2 = l2acc[gg];
    l2 += __shfl_xor(l2, 16, 64);
    l2 += __shfl_xor(l2, 32, 64);
    if (quad == 0) {
      lbuf[(w << 7) + (gg << 4) + lr] = l;
      l2buf[(w << 7) + (gg << 4) + lr] = l2;
    }
  }
  __syncthreads();
  if (lane < 16) {  // wave w reduces its own g
    float l = 0.f, l2 = 0.f;
#pragma unroll
    for (int w2 = 0; w2 < 8; ++w2) {
      l += lbuf[(w2 << 7) + (g << 4) + lr];
      l2 += l2buf[(w2 << 7) + (g << 4) + lr];
    }
    const size_t li = (((size_t)(tq << 5) + bg) << 10) + q0 + lr;
    lpart[li] = l;
    l2part[li] = l2;
  }
}

// ------- y = al*(Onorm @ Wp^T) + bias2, 64x64 tiles, 512 blocks.
// combine_o FOLDED IN: B-stage reads the two Opart f32 partials directly
// (per-u16x8 vector q is constant -> one linvS[q] scalar) and normalizes
// on the fly. InstanceNorm stats reduced from lpart/l2part in prologue.
// 2-phase register-prefetch pipeline as in gemm_qkv. ----
__global__ __launch_bounds__(256) void gemm_proj(
    const float* __restrict__ Opart, const u16* __restrict__ wpb,
    const float* __restrict__ lpart, const float* __restrict__ l2part,
    const float* __restrict__ gamma, const float* __restrict__ beta,
    const float* __restrict__ ws, const float* __restrict__ bp,
    const float* __restrict__ vsum, float* __restrict__ y) {
  const int b = blockIdx.z;
  const int m0 = blockIdx.y << 6;  // o: 8 tiles
  const int n0 = blockIdx.x << 6;  // t: 16 tiles
  const int gidx = blockIdx.x >> 1;
  const int bg = (b << 3) + gidx;
  __shared__ __align__(16) u16 As[64][72];
  __shared__ __align__(16) u16 Bs[64][72];
  __shared__ float red[4];
  __shared__ float albc[2];
  __shared__ float b2s[64];
  __shared__ float linvS[512];
  const int tid = threadIdx.x;
  const int w = tid >> 6, lane = tid & 63, lr = lane & 15, lq = lane >> 4;
  const int mw = (w >> 1) << 5, nw = (w & 1) << 5;
  u16x8 rA[2];
  f32x4 rB[2][2][2];  // [it][tq][lo/hi f32x4]
#define LOADP(K)                                                            \
  {                                                                         \
    _Pragma("unroll") for (int it = 0; it < 2; ++it) {                      \
      const int e = tid + (it << 8);                                        \
      const int r = e >> 3, c8 = (e & 7) << 3;                              \
      rA[it] = *(const u16x8*)(wpb + (size_t)(m0 + r) * C_ + (K) + c8);     \
      const int q = (((n0 + r) & 127) << 3) + ((K) >> 6);                   \
      _Pragma("unroll") for (int tq = 0; tq < 2; ++tq) {                    \
        const float* src =                                                  \
            Opart + ((((size_t)((tq << 5) + bg)) << 10) + q) * 64 + c8;     \
        rB[it][tq][0] = *(const f32x4*)(src);                               \
        rB[it][tq][1] = *(const f32x4*)(src + 4);                           \
      }                                                                     \
    }                                                                       \
  }
  LOADP(0);  // in flight under the prologue stats
  // ---- prologue: ssq reduce over full 1024 q (from partials) ----
  {
    const size_t p0 = ((size_t)bg) << 10, p1 = ((size_t)(32 + bg)) << 10;
    const f32x4 la = *(const f32x4*)(lpart + p0 + (tid << 2));
    const f32x4 lb = *(const f32x4*)(lpart + p1 + (tid << 2));
    const f32x4 l2a = *(const f32x4*)(l2part + p0 + (tid << 2));
    const f32x4 l2b = *(const f32x4*)(l2part + p1 + (tid << 2));
    float ssq = 0.f;
#pragma unroll
    for (int k = 0; k < 4; ++k) {
      const float l = la[k] + lb[k];
      ssq += (l2a[k] + l2b[k]) / (l * l);
    }
#pragma unroll
    for (int off = 32; off; off >>= 1) ssq += __shfl_xor(ssq, off, 64);
    if (lane == 0) red[w] = ssq;
    // linv for this block's 512-q window (qb0 = (n0&127)*8 = 0 or 512)
    const int qb0 = (n0 & 127) << 3;
#pragma unroll
    for (int j = 0; j < 2; ++j) {
      const int qq = (tid << 1) + j;
      const float l = lpart[p0 + qb0 + qq] + lpart[p1 + qb0 + qq];
      linvS[qq] = 1.f / l;
    }
  }
  __syncthreads();
  if (tid == 0) {
    const float s = red[0] + red[1] + red[2] + red[3];
    const float mean = 0.0009765625f;
    const float var = s * (1.f / 1048576.f) - mean * mean;
    const float al = gamma[gidx] * rsqrtf(var + EPS_);
    albc[0] = al;
    albc[1] = beta[gidx] - al * mean;
  }
  __syncthreads();
  if (tid < 64) {
    const int o = m0 + tid;
    const float* wr = ws + (o << 6);
    const float* vsr = vsum + (bg << 6);
    float acc = 0.f;
#pragma unroll
    for (int d = 0; d < 64; d += 4) {
      const float4 vv4 = *(const float4*)(vsr + d);
      const float4 ws4 = *(const float4*)(wr + d);
      acc += ws4.x * vv4.x + ws4.y * vv4.y + ws4.z * vv4.z + ws4.w * vv4.w;
    }
    b2s[tid] = bp[o] + albc[1] * acc;
  }
  f32x4 acc[2][2] = {};
  for (int k0 = 0; k0 < C_; k0 += 64) {
    if (k0) BARSYNC();
    __syncthreads();  // k0==0: b2s/linvS visible; k0>0: harmless extra sync
#pragma unroll
    for (int it = 0; it < 2; ++it) {
      const int e = tid + (it << 8);
      const int r = e >> 3, c8 = (e & 7) << 3;
      *(u16x8*)&As[r][c8] = rA[it];
      const float li = linvS[(r << 3) + (k0 >> 6)];
      u16x8 o;
#pragma unroll
      for (int k = 0; k < 4; ++k) {
        o[k] = f2bf((rB[it][0][0][k] + rB[it][1][0][k]) * li);
        o[k + 4] = f2bf((rB[it][0][1][k] + rB[it][1][1][k]) * li);
      }
      *(u16x8*)&Bs[r][c8] = o;
    }
    if (k0 < C_ - 64) LOADP(k0 + 64);  // in flight across MFMA phase
    BARSYNC();
#pragma unroll
    for (int kf = 0; kf < 2; ++kf) {
      const int ko = (kf << 5) + (lq << 3);
      s16x8 a[2], bb[2];
#pragma unroll
      for (int i = 0; i < 2; ++i) a[i] = *(const s16x8*)&As[mw + (i << 4) + lr][ko];
#pragma unroll
      for (int j = 0; j < 2; ++j) bb[j] = *(const s16x8*)&Bs[nw + (j << 4) + lr][ko];
#pragma unroll
      for (int i = 0; i < 2; ++i)
#pragma unroll
        for (int j = 0; j < 2; ++j) acc[i][j] = mfma16(a[i], bb[j], acc[i][j]);
    }
  }
#undef LOADP
  const float al = albc[0];
#pragma unroll
  for (int i = 0; i < 2; ++i) {
    const int row = mw + (i << 4) + (lq << 2);
#pragma unroll
    for (int j = 0; j < 2; ++j) {
      const int col = nw + (j << 4) + lr;
#pragma unroll
      for (int r = 0; r < 4; ++r)
        y[(size_t)b * (C_ * (size_t)T_) + (size_t)(m0 + row + r) * T_ + n0 + col] =
            acc[i][j][r] * al + b2s[row + r];
    }
  }
}

extern "C" void kernel_launch(void* const* d_in, const int* in_sizes, int n_in,
                              void* d_out, int out_size, void* d_ws,
                              size_t ws_size, hipStream_t stream) {
  const float* x = (const float*)d_in[0];
  const float* wq = (const float*)d_in[1];
  const float* wk = (const float*)d_in[2];
  const float* wv = (const float*)d_in[3];
  const float* wh = (const float*)d_in[4];
  const float* gm = (const float*)d_in[5];
  const float* bt = (const float*)d_in[6];
  const float* wp = (const float*)d_in[7];
  const float* bp = (const float*)d_in[8];
  float* y = (float*)d_out;
  char* wsb = (char*)d_ws;

  u16* Qt = (u16*)(wsb + QT_OFF);
  u16* KS = (u16*)(wsb + KS_OFF);
  u16* VS = (u16*)(wsb + VS_OFF);
  u16* Xt = (u16*)(wsb + XT_OFF);
  float* vsum = (float*)(wsb + VSUM_OFF);
  u16* Wb = (u16*)(wsb + WB_OFF);
  u16* WQb = Wb;
  u16* WKb = Wb + 262144;
  u16* WVb = Wb + 524288;
  u16* WPb = Wb + 786432;
  float* lpart = (float*)(wsb + LP_OFF);
  float* l2part = (float*)(wsb + L2P_OFF);
  float* ws = (float*)(wsb + WS_OFF);
  float* Opart = (float*)(wsb + OP_OFF);

  prep_k<<<dim3(1152), 256, 0, stream>>>(x, wq, wk, wv, wp, Wb, ws, vsum, Xt);
  gemm_qkv<<<dim3(8, 8, 12), 256, 0, stream>>>(Xt, WQb, WKb, WVb, Qt, KS, VS,
                                               vsum);
  attn_fused<<<dim3(512), 512, 0, stream>>>(Qt, KS, VS, wh, Opart, lpart,
                                            l2part);
  gemm_proj<<<dim3(16, 8, 4), 256, 0, stream>>>(Opart, WPb, lpart, l2part, gm,
                                                bt, ws, bp, vsum, y);
}

// Round 14
// 146.261 us; speedup vs baseline: 1.5282x; 1.0265x over previous
//
#include <hip/hip_runtime.h>
#include <hip/hip_bf16.h>

#define B_ 4
#define C_ 512
#define T_ 1024
#define SCALE_ 0.125f
#define EPS_ 1e-5f

typedef unsigned short u16;
typedef __attribute__((ext_vector_type(8))) unsigned short u16x8;
typedef __attribute__((ext_vector_type(4))) unsigned short u16x4;
typedef __attribute__((ext_vector_type(8))) short s16x8;
typedef __attribute__((ext_vector_type(4))) float f32x4;

// ws byte offsets (ws is 256 MiB)
#define QT_OFF    (0x0ull)         // bf16 Qt[B][T][C]   4 MB (Q pre-scaled by 1/8)
#define KS_OFF    (0x400000ull)    // bf16 KS swizzled [B][t32][half][f][lane][8] 4 MB
#define VS_OFF    (0x800000ull)    // bf16 VS swizzled [B][g][t32][dj][lane][8]   4 MB
#define XT_OFF    (0xC00000ull)    // bf16 Xt[B][T][C]   4 MB
#define WB_OFF    (0x1480000ull)   // bf16 W[4][512][512]: wq,wk,wv,wp  2 MB
#define LP_OFF    (0x1680000ull)   // fp32 lpart [2][32][1024] 256 KB
#define L2P_OFF   (0x1700000ull)   // fp32 l2part[2][32][1024] 256 KB
#define WS_OFF    (0x1780000ull)   // fp32 ws[512][64] 128 KB
#define VSUM_OFF  (0x17A0000ull)   // fp32 vsum[B][8][64] 8 KB
#define OP_OFF    (0x2000000ull)   // fp32 Opart[2][32][1024][64] 16 MB

static __device__ __forceinline__ u16 f2bf(float f) {
  unsigned u = __float_as_uint(f);
  unsigned r = (u + 0x7fff + ((u >> 16) & 1)) >> 16;  // RNE
  return (u16)r;
}
static __device__ __forceinline__ float b2f(u16 x) {
  return __uint_as_float(((unsigned)x) << 16);
}
static __device__ __forceinline__ f32x4 mfma16(s16x8 a, s16x8 b, f32x4 c) {
  return __builtin_amdgcn_mfma_f32_16x16x32_bf16(a, b, c, 0, 0, 0);
}
// lgkmcnt(0) + raw barrier: LDS ops ordered, but in-flight GLOBAL loads (to
// regs) legitimately cross the barrier -- the T3 2-phase pipeline primitive.
#define BARSYNC()                                       \
  {                                                     \
    asm volatile("s_waitcnt lgkmcnt(0)" ::: "memory");  \
    __builtin_amdgcn_s_barrier();                       \
  }

// ---- prep: blocks [0,512) wcvt; [512,640) wsum+vsum-zero; [640,1152)
// transpose x -> Xt[b][t][c] bf16. Branch is block-uniform. ----
__global__ __launch_bounds__(256) void prep_k(
    const float* __restrict__ x, const float* __restrict__ wq,
    const float* __restrict__ wk, const float* __restrict__ wv,
    const float* __restrict__ wp, u16* __restrict__ wb,
    float* __restrict__ ws, float* __restrict__ vsum, u16* __restrict__ xt) {
  const int id = blockIdx.x;
  const int tid = threadIdx.x;
  __shared__ float Ts[64][65];
  if (id < 512) {  // ---- wcvt: fp32 -> bf16, 4 weight matrices ----
    const int i = (id << 8) + tid;
    const int idx = i << 3;
    const int which = idx >> 18;  // uniform per block
    const int off = idx & 262143;
    const float* s = which == 0 ? wq : which == 1 ? wk : which == 2 ? wv : wp;
    const float4 f0 = *(const float4*)(s + off);
    const float4 f1 = *(const float4*)(s + off + 4);
    u16x8 o;
    o[0] = f2bf(f0.x); o[1] = f2bf(f0.y); o[2] = f2bf(f0.z); o[3] = f2bf(f0.w);
    o[4] = f2bf(f1.x); o[5] = f2bf(f1.y); o[6] = f2bf(f1.z); o[7] = f2bf(f1.w);
    *(u16x8*)(wb + idx) = o;
  } else if (id < 640) {  // ---- ws[o][d] = sum_j wp[o][j*64+d]; zero vsum ----
    const int idx = ((id - 512) << 8) + tid;
    if (id - 512 < 8) vsum[idx] = 0.f;
    const int o = idx >> 6, d = idx & 63;
    float s = 0.f;
#pragma unroll
    for (int j = 0; j < 8; ++j) s += wp[(o << 9) + (j << 6) + d];
    ws[idx] = s;
  } else {  // ---- transpose x[b][c][t] -> Xt[b][t][c] bf16 ----
    const int id3 = id - 640;
    const int b = id3 >> 7, rem = id3 & 127;
    const int t0 = (rem & 15) << 6;
    const int c0 = (rem >> 4) << 6;
    const float* __restrict__ X = x + (size_t)b * (C_ * (size_t)T_);
    u16* __restrict__ Xt = xt + (size_t)b * (T_ * (size_t)C_);
#pragma unroll
    for (int i = 0; i < 4; ++i) {
      const int e = tid + (i << 8);
      const int r = e >> 4, c4 = e & 15;
      const float4 v =
          *(const float4*)(X + (size_t)(c0 + r) * T_ + t0 + (c4 << 2));
      Ts[r][(c4 << 2) + 0] = v.x; Ts[r][(c4 << 2) + 1] = v.y;
      Ts[r][(c4 << 2) + 2] = v.z; Ts[r][(c4 << 2) + 3] = v.w;
    }
    __syncthreads();
#pragma unroll
    for (int i = 0; i < 2; ++i) {
      const int e = tid + (i << 8);
      const int tt = e >> 3, c8 = e & 7;
      u16x8 o;
#pragma unroll
      for (int j = 0; j < 8; ++j) o[j] = f2bf(Ts[(c8 << 3) + j][tt]);
      *(u16x8*)(Xt + (size_t)(t0 + tt) * C_ + c0 + (c8 << 3)) = o;
    }
  }
}

// ---- unified QKV GEMM, 128x64 tiles, 768 blocks (3/CU), DEPTH-2 REGISTER
// PREFETCH (ping-pong reg sets, loop body doubled for static indexing):
// load k+2 issued at step k -> two MFMA phases + barriers of latency cover
// (depth-1 only covered ~80cy vs 200-900cy L2/HBM). Q epilogue now also
// goes through LDS -> coalesced u16x8 stores (was 2B scatter). ----
__global__ __launch_bounds__(256) void gemm_qkv(
    const u16* __restrict__ xt, const u16* __restrict__ wqb,
    const u16* __restrict__ wkb, const u16* __restrict__ wvb,
    u16* __restrict__ qto, u16* __restrict__ ks, u16* __restrict__ vs,
    float* __restrict__ vsum) {
  const int z = blockIdx.z;
  const int tid = threadIdx.x;
  const int w = tid >> 6, lane = tid & 63, lr = lane & 15, lq = lane >> 4;
  const int wm = (w >> 1) << 6, wn = (w & 1) << 5;  // 2x2 waves: 64m x 32n
  __shared__ __align__(16) u16 As[128][72];
  __shared__ __align__(16) u16 Bs[64][72];
  u16* Ts = &As[0][0];  // epilogue staging tile [128][72] (aliases As)
  const u16 *Ag, *Bg;
  int m0, n0, mode, b;
  if (z < 8) {
    const int which = z >> 2;
    b = z & 3;
    Ag = xt + (size_t)b * (T_ * (size_t)C_);
    m0 = blockIdx.x << 7;  // t: 8 tiles
    Bg = which ? wkb : wqb;
    n0 = blockIdx.y << 6;  // o: 8 tiles
    mode = which;          // 0 = Q, 1 = K
  } else {
    b = z - 8;
    const int ti = (blockIdx.y << 3) | blockIdx.x;  // [0,64)
    Ag = wvb;
    m0 = (ti >> 4) << 7;  // o: 4 tiles
    Bg = xt + (size_t)b * (T_ * (size_t)C_);
    n0 = (ti & 15) << 6;  // t: 16 tiles
    mode = 2;
  }
  u16x8 rA0[4], rB0[2], rA1[4], rB1[2];
#define LOADQ(RA, RB, K)                                                  \
  {                                                                       \
    _Pragma("unroll") for (int it = 0; it < 4; ++it) {                    \
      const int e = tid + (it << 8);                                      \
      const int r = e >> 3, c8 = (e & 7) << 3;                            \
      RA[it] = *(const u16x8*)(Ag + (size_t)(m0 + r) * C_ + (K) + c8);    \
    }                                                                     \
    _Pragma("unroll") for (int it = 0; it < 2; ++it) {                    \
      const int e = tid + (it << 8);                                      \
      const int r = e >> 3, c8 = (e & 7) << 3;                            \
      RB[it] = *(const u16x8*)(Bg + (size_t)(n0 + r) * C_ + (K) + c8);    \
    }                                                                     \
  }
#define WRITEQ(RA, RB)                                       \
  {                                                          \
    _Pragma("unroll") for (int it = 0; it < 4; ++it) {       \
      const int e = tid + (it << 8);                         \
      *(u16x8*)&As[e >> 3][(e & 7) << 3] = RA[it];           \
    }                                                        \
    _Pragma("unroll") for (int it = 0; it < 2; ++it) {       \
      const int e = tid + (it << 8);                         \
      *(u16x8*)&Bs[e >> 3][(e & 7) << 3] = RB[it];           \
    }                                                        \
  }
#define MFMAQ()                                                                \
  {                                                                            \
    _Pragma("unroll") for (int kf = 0; kf < 2; ++kf) {                         \
      const int ko = (kf << 5) + (lq << 3);                                    \
      s16x8 a[4], bb[2];                                                       \
      _Pragma("unroll") for (int i = 0; i < 4; ++i) a[i] =                     \
          *(const s16x8*)&As[wm + (i << 4) + lr][ko];                          \
      _Pragma("unroll") for (int j = 0; j < 2; ++j) bb[j] =                    \
          *(const s16x8*)&Bs[wn + (j << 4) + lr][ko];                          \
      _Pragma("unroll") for (int i = 0; i < 4; ++i)                            \
          _Pragma("unroll") for (int j = 0; j < 2; ++j) acc[i][j] =            \
              mfma16(a[i], bb[j], acc[i][j]);                                  \
    }                                                                          \
  }
  f32x4 acc[4][2] = {};
  LOADQ(rA0, rB0, 0);
  LOADQ(rA1, rB1, 64);
  for (int k0 = 0; k0 < C_; k0 += 128) {
    // even K-step (k0)
    if (k0) BARSYNC();  // prev reads consumed (all waves)
    WRITEQ(rA0, rB0);
    if (k0 + 128 < C_) LOADQ(rA0, rB0, k0 + 128);  // 2 phases of cover
    BARSYNC();  // writes committed
    MFMAQ();
    // odd K-step (k0+64)
    BARSYNC();
    WRITEQ(rA1, rB1);
    if (k0 + 192 < C_) LOADQ(rA1, rB1, k0 + 192);
    BARSYNC();
    MFMAQ();
  }
#undef LOADQ
#undef WRITEQ
#undef MFMAQ
  if (mode == 2) {
    // ---- vsum contribution: sum over this tile's 64 t-cols, atomic ----
#pragma unroll
    for (int i = 0; i < 4; ++i)
#pragma unroll
      for (int r = 0; r < 4; ++r) {
        float s = acc[i][0][r] + acc[i][1][r];
        s += __shfl_xor(s, 1, 64);
        s += __shfl_xor(s, 2, 64);
        s += __shfl_xor(s, 4, 64);
        s += __shfl_xor(s, 8, 64);
        if (lr == 0) {
          const int o = m0 + wm + (i << 4) + (lq << 2) + r;
          atomicAdd(&vsum[(((b << 3) | (o >> 6)) << 6) | (o & 63)], s);
        }
      }
  }
  BARSYNC();  // all waves done reading As before Ts overwrite
  // ---- stage output tile [m_local 128][n_local 64] (stride 72) in LDS ----
  const float osc = (mode == 0) ? SCALE_ : 1.0f;
#pragma unroll
  for (int i = 0; i < 4; ++i)
#pragma unroll
    for (int j = 0; j < 2; ++j)
#pragma unroll
      for (int r = 0; r < 4; ++r)
        Ts[(wm + (i << 4) + (lq << 2) + r) * 72 + wn + (j << 4) + lr] =
            f2bf(acc[i][j][r] * osc);
  __syncthreads();
  if (mode == 0) {
    // coalesced Qt store: row = tid>>1, col-half = (tid&1)*32; 4 u16x8 each
    u16* Y = qto + (size_t)b * (T_ * (size_t)C_);
    const int row = tid >> 1, ch32 = (tid & 1) << 5;
    u16* dst = Y + (size_t)(m0 + row) * C_ + n0 + ch32;
    const u16* src = &Ts[row * 72 + ch32];
#pragma unroll
    for (int u = 0; u < 4; ++u)
      *(u16x8*)(dst + (u << 3)) = *(const u16x8*)(src + (u << 3));
    return;
  }
  const int ch = tid >> 4, part = tid & 15;  // 16 chunks x 16 threads
  if (mode == 1) {
    // chunk = (t32l[4], half[2], fl[2]); lanek = u*16+part -> coalesced
    const int t32l = ch >> 2, half = (ch >> 1) & 1, fl = ch & 1;
    const int t32g = (m0 >> 5) + t32l, fg = (n0 >> 5) + fl;
    u16* dst =
        ks + (((((size_t)((b << 5) | t32g) << 1) | half) << 4 | fg) << 9);
#pragma unroll
    for (int u = 0; u < 4; ++u) {
      const int lanek = (u << 4) + part;
      const int quadk = lanek >> 4, lrk = lanek & 15;
      const int rr = ((lrk >> 2) << 3) | (half << 2) | (lrk & 3);
      const u16x8 v =
          *(const u16x8*)&Ts[((t32l << 5) + rr) * 72 + (fl << 5) + (quadk << 3)];
      *(u16x8*)(dst + (lanek << 3)) = v;
    }
  } else {
    // chunk = (gl[2], t32l[2], dj[4]); lanev = u*16+part -> coalesced
    const int gl = ch >> 3, t32l = (ch >> 2) & 1, dj = ch & 3;
    const int gg = (m0 >> 6) + gl, t32g = (n0 >> 5) + t32l;
    u16* dst =
        vs + (((((size_t)((b << 3) | gg) << 5) | t32g) << 2 | dj) << 9);
#pragma unroll
    for (int u = 0; u < 4; ++u) {
      const int lanev = (u << 4) + part;
      const int quadv = lanev >> 4, lrv = lanev & 15;
      const u16x8 v = *(const u16x8*)&Ts[((gl << 6) + (dj << 4) + lrv) * 72 +
                                         (t32l << 5) + (quadv << 3)];
      *(u16x8*)(dst + (lanev << 3)) = v;
    }
  }
}

// ---- FUSED attention: R13 structure with the R12 P-swizzle REVERTED
// (it made bank conflicts 4.5x WORSE: 1.18M -> 5.3M; time-neutral but
// wrong -- this is the first measurement of tq=2 WITHOUT it). ----
__global__ __launch_bounds__(512, 4) void attn_fused(
    const u16* __restrict__ Qt, const u16* __restrict__ KS,
    const u16* __restrict__ VS, const float* __restrict__ wh,
    float* __restrict__ Opart, float* __restrict__ lpart,
    float* __restrict__ l2part) {
  const int id = blockIdx.x;
  const int xcd = id & 7;
  const int b = xcd >> 1;
  const int hi = id >> 3;                       // [0,64)
  const int qb = ((xcd & 1) << 5) | (hi & 31);  // [0,64)
  const int tq = hi >> 5;                       // [0,2) t-half
  const int q0 = qb << 4;
  const int tid = threadIdx.x;
  const int w = tid >> 6, lane = tid & 63;
  const int lr = lane & 15, quad = lane >> 4;

  __shared__ __align__(16) u16 Qs[16][522];       // 16704 B
  __shared__ __align__(16) u16 Plds[8][16][136];  // 34816 B
  float* Sbuf = (float*)&Plds[0][0][0];  // epilogue alias (Plds dead by then)

  {  // stage Q tile (16 x 512)
    const u16* Qb = Qt + ((size_t)b * T_ + q0) * C_;
    for (int i = tid; i < 1024; i += 512) {
      const int r = i >> 6, c8 = i & 63;
      *(u16x8*)&Qs[r][c8 << 3] = *(const u16x8*)(Qb + (size_t)r * C_ + (c8 << 3));
    }
  }

  const u16* __restrict__ Qrow = &Qs[lr][quad << 3];
  const int g = w;  // PV head owned by this wave
  const int win = w >> 1, half = w & 1;  // QK: window pair, K-half
  const u16* __restrict__ Vc =
      VS + (((size_t)((b << 3) | g)) << 16) + (lane << 3);

  float lacc[8] = {}, l2acc[8] = {};
  f32x4 acc[4] = {};

  __syncthreads();

  for (int c = 0; c < 4; ++c) {
    // ---- QK + mix + exp: K loads lane-contiguous from KS ----
    const int t32k = (tq << 4) + (c << 2) + win;
    const u16* __restrict__ Kc =
        KS + (((size_t)((((b << 5) | t32k) << 1) | half)) << 13) + (lane << 3);
    f32x4 m[8] = {};
#pragma unroll 4
    for (int h = 0; h < 8; ++h) {
      f32x4 a0 = {0.f, 0.f, 0.f, 0.f};
      const s16x8 qf0 = *(const s16x8*)(Qrow + (h << 6));
      const s16x8 k0 = *(const s16x8*)(Kc + (h << 10));
      a0 = mfma16(k0, qf0, a0);
      const s16x8 qf1 = *(const s16x8*)(Qrow + (h << 6) + 32);
      const s16x8 k1 = *(const s16x8*)(Kc + (h << 10) + 512);
      a0 = mfma16(k1, qf1, a0);
#pragma unroll
      for (int gg = 0; gg < 8; ++gg) {
        const float wgh = wh[(gg << 3) + h];  // uniform -> SGPR
        m[gg] += a0 * wgh;
      }
    }
    // lane's t slots: win*32 + quad*8 + half*4 + {0..3}; q = lr
#pragma unroll
    for (int gg = 0; gg < 8; ++gg) {
      f32x4 e0;
#pragma unroll
      for (int k = 0; k < 4; ++k) e0[k] = __expf(m[gg][k]);
      u16x4 o;
#pragma unroll
      for (int k = 0; k < 4; ++k) o[k] = f2bf(e0[k]);
      *(u16x4*)&Plds[gg][lr][(win << 5) + (quad << 3) + (half << 2)] = o;
      lacc[gg] += e0[0] + e0[1] + e0[2] + e0[3];
      l2acc[gg] += e0[0] * e0[0] + e0[1] * e0[1] + e0[2] * e0[2] + e0[3] * e0[3];
    }
    __syncthreads();  // P ready
    // ---- PV: V loads lane-contiguous from VS ----
#pragma unroll
    for (int tw = 0; tw < 4; ++tw) {
      const int t32v = (tq << 4) + (c << 2) + tw;
      const s16x8 pa = *(const s16x8*)&Plds[g][lr][(tw << 5) + (quad << 3)];
#pragma unroll
      for (int dj = 0; dj < 4; ++dj) {
        const s16x8 vb =
            *(const s16x8*)(Vc + ((size_t)t32v << 11) + (dj << 9));
        acc[dj] = mfma16(pa, vb, acc[dj]);
      }
    }
    __syncthreads();  // P consumed, safe to overwrite next chunk
  }

  // ---- write raw f32 partial O (normalization happens in gemm_proj) ----
  const int bg = (b << 3) + g;
  const size_t obase = ((((size_t)(tq << 5) + bg) << 10) + q0) * 64;
#pragma unroll
  for (int dj = 0; dj < 4; ++dj) {
    const int d = (dj << 4) + lr;
#pragma unroll
    for (int r = 0; r < 4; ++r) {
      const int q = (quad << 2) + r;
      Opart[obase + (size_t)q * 64 + d] = acc[dj][r];
    }
  }

  // ---- epilogue: l/l2 reduce (buffers alias Plds), write partials ----
  float* lbuf = Sbuf;          // [8w][8g][16q]  4 KB
  float* l2buf = Sbuf + 1024;  // [8w][8g][16q]  4 KB
#pragma unroll
  for (int gg = 0; gg < 8; ++gg) {
    float l = lacc[gg];
    l += __shfl_xor(l, 16, 64);
    l += __shfl_xor(l, 32, 64);
    float l2 = l2acc[gg];
    l2 += __shfl_xor(l2, 16, 64);
    l2 += __shfl_xor(l2, 32, 64);
    if (quad == 0) {
      lbuf[(w << 7) + (gg << 4) + lr] = l;
      l2buf[(w << 7) + (gg << 4) + lr] = l2;
    }
  }
  __syncthreads();
  if (lane < 16) {  // wave w reduces its own g
    float l = 0.f, l2 = 0.f;
#pragma unroll
    for (int w2 = 0; w2 < 8; ++w2) {
      l += lbuf[(w2 << 7) + (g << 4) + lr];
      l2 += l2buf[(w2 << 7) + (g << 4) + lr];
    }
    const size_t li = (((size_t)(tq << 5) + bg) << 10) + q0 + lr;
    lpart[li] = l;
    l2part[li] = l2;
  }
}

// ------- y = al*(Onorm @ Wp^T) + bias2, 64x64 tiles, 512 blocks.
// combine_o folded in; InstanceNorm stats from lpart/l2part in prologue;
// depth-1 register prefetch (prologue stats give extra cover). ----
__global__ __launch_bounds__(256) void gemm_proj(
    const float* __restrict__ Opart, const u16* __restrict__ wpb,
    const float* __restrict__ lpart, const float* __restrict__ l2part,
    const float* __restrict__ gamma, const float* __restrict__ beta,
    const float* __restrict__ ws, const float* __restrict__ bp,
    const float* __restrict__ vsum, float* __restrict__ y) {
  const int b = blockIdx.z;
  const int m0 = blockIdx.y << 6;  // o: 8 tiles
  const int n0 = blockIdx.x << 6;  // t: 16 tiles
  const int gidx = blockIdx.x >> 1;
  const int bg = (b << 3) + gidx;
  __shared__ __align__(16) u16 As[64][72];
  __shared__ __align__(16) u16 Bs[64][72];
  __shared__ float red[4];
  __shared__ float albc[2];
  __shared__ float b2s[64];
  __shared__ float linvS[512];
  const int tid = threadIdx.x;
  const int w = tid >> 6, lane = tid & 63, lr = lane & 15, lq = lane >> 4;
  const int mw = (w >> 1) << 5, nw = (w & 1) << 5;
  u16x8 rA[2];
  f32x4 rB[2][2][2];  // [it][tq][lo/hi f32x4]
#define LOADP(K)                                                            \
  {                                                                         \
    _Pragma("unroll") for (int it = 0; it < 2; ++it) {                      \
      const int e = tid + (it << 8);                                        \
      const int r = e >> 3, c8 = (e & 7) << 3;                              \
      rA[it] = *(const u16x8*)(wpb + (size_t)(m0 + r) * C_ + (K) + c8);     \
      const int q = (((n0 + r) & 127) << 3) + ((K) >> 6);                   \
      _Pragma("unroll") for (int tq = 0; tq < 2; ++tq) {                    \
        const float* src =                                                  \
            Opart + ((((size_t)((tq << 5) + bg)) << 10) + q) * 64 + c8;     \
        rB[it][tq][0] = *(const f32x4*)(src);                               \
        rB[it][tq][1] = *(const f32x4*)(src + 4);                           \
      }                                                                     \
    }                                                                       \
  }
  LOADP(0);  // in flight under the prologue stats
  // ---- prologue: ssq reduce over full 1024 q (from partials) ----
  {
    const size_t p0 = ((size_t)bg) << 10, p1 = ((size_t)(32 + bg)) << 10;
    const f32x4 la = *(const f32x4*)(lpart + p0 + (tid << 2));
    const f32x4 lb = *(const f32x4*)(lpart + p1 + (tid << 2));
    const f32x4 l2a = *(const f32x4*)(l2part + p0 + (tid << 2));
    const f32x4 l2b = *(const f32x4*)(l2part + p1 + (tid << 2));
    float ssq = 0.f;
#pragma unroll
    for (int k = 0; k < 4; ++k) {
      const float l = la[k] + lb[k];
      ssq += (l2a[k] + l2b[k]) / (l * l);
    }
#pragma unroll
    for (int off = 32; off; off >>= 1) ssq += __shfl_xor(ssq, off, 64);
    if (lane == 0) red[w] = ssq;
    // linv for this block's 512-q window (qb0 = (n0&127)*8 = 0 or 512)
    const int qb0 = (n0 & 127) << 3;
#pragma unroll
    for (int j = 0; j < 2; ++j) {
      const int qq = (tid << 1) + j;
      const float l = lpart[p0 + qb0 + qq] + lpart[p1 + qb0 + qq];
      linvS[qq] = 1.f / l;
    }
  }
  __syncthreads();
  if (tid == 0) {
    const float s = red[0] + red[1] + red[2] + red[3];
    const float mean = 0.0009765625f;
    const float var = s * (1.f / 1048576.f) - mean * mean;
    const float al = gamma[gidx] * rsqrtf(var + EPS_);
    albc[0] = al;
    albc[1] = beta[gidx] - al * mean;
  }
  __syncthreads();
  if (tid < 64) {
    const int o = m0 + tid;
    const float* wr = ws + (o << 6);
    const float* vsr = vsum + (bg << 6);
    float acc = 0.f;
#pragma unroll
    for (int d = 0; d < 64; d += 4) {
      const float4 vv4 = *(const float4*)(vsr + d);
      const float4 ws4 = *(const float4*)(wr + d);
      acc += ws4.x * vv4.x + ws4.y * vv4.y + ws4.z * vv4.z + ws4.w * vv4.w;
    }
    b2s[tid] = bp[o] + albc[1] * acc;
  }
  f32x4 acc[2][2] = {};
  for (int k0 = 0; k0 < C_; k0 += 64) {
    if (k0) BARSYNC();
    __syncthreads();  // k0==0: b2s/linvS visible; k0>0: harmless extra sync
#pragma unroll
    for (int it = 0; it < 2; ++it) {
      const int e = tid + (it << 8);
      const int r = e >> 3, c8 = (e & 7) << 3;
      *(u16x8*)&As[r][c8] = rA[it];
      const float li = linvS[(r << 3) + (k0 >> 6)];
      u16x8 o;
#pragma unroll
      for (int k = 0; k < 4; ++k) {
        o[k] = f2bf((rB[it][0][0][k] + rB[it][1][0][k]) * li);
        o[k + 4] = f2bf((rB[it][0][1][k] + rB[it][1][1][k]) * li);
      }
      *(u16x8*)&Bs[r][c8] = o;
    }
    if (k0 < C_ - 64) LOADP(k0 + 64);  // in flight across MFMA phase
    BARSYNC();
#pragma unroll
    for (int kf = 0; kf < 2; ++kf) {
      const int ko = (kf << 5) + (lq << 3);
      s16x8 a[2], bb[2];
#pragma unroll
      for (int i = 0; i < 2; ++i) a[i] = *(const s16x8*)&As[mw + (i << 4) + lr][ko];
#pragma unroll
      for (int j = 0; j < 2; ++j) bb[j] = *(const s16x8*)&Bs[nw + (j << 4) + lr][ko];
#pragma unroll
      for (int i = 0; i < 2; ++i)
#pragma unroll
        for (int j = 0; j < 2; ++j) acc[i][j] = mfma16(a[i], bb[j], acc[i][j]);
    }
  }
#undef LOADP
  const float al = albc[0];
#pragma unroll
  for (int i = 0; i < 2; ++i) {
    const int row = mw + (i << 4) + (lq << 2);
#pragma unroll
    for (int j = 0; j < 2; ++j) {
      const int col = nw + (j << 4) + lr;
#pragma unroll
      for (int r = 0; r < 4; ++r)
        y[(size_t)b * (C_ * (size_t)T_) + (size_t)(m0 + row + r) * T_ + n0 + col] =
            acc[i][j][r] * al + b2s[row + r];
    }
  }
}

extern "C" void kernel_launch(void* const* d_in, const int* in_sizes, int n_in,
                              void* d_out, int out_size, void* d_ws,
                              size_t ws_size, hipStream_t stream) {
  const float* x = (const float*)d_in[0];
  const float* wq = (const float*)d_in[1];
  const float* wk = (const float*)d_in[2];
  const float* wv = (const float*)d_in[3];
  const float* wh = (const float*)d_in[4];
  const float* gm = (const float*)d_in[5];
  const float* bt = (const float*)d_in[6];
  const float* wp = (const float*)d_in[7];
  const float* bp = (const float*)d_in[8];
  float* y = (float*)d_out;
  char* wsb = (char*)d_ws;

  u16* Qt = (u16*)(wsb + QT_OFF);
  u16* KS = (u16*)(wsb + KS_OFF);
  u16* VS = (u16*)(wsb + VS_OFF);
  u16* Xt = (u16*)(wsb + XT_OFF);
  float* vsum = (float*)(wsb + VSUM_OFF);
  u16* Wb = (u16*)(wsb + WB_OFF);
  u16* WQb = Wb;
  u16* WKb = Wb + 262144;
  u16* WVb = Wb + 524288;
  u16* WPb = Wb + 786432;
  float* lpart = (float*)(wsb + LP_OFF);
  float* l2part = (float*)(wsb + L2P_OFF);
  float* ws = (float*)(wsb + WS_OFF);
  float* Opart = (float*)(wsb + OP_OFF);

  prep_k<<<dim3(1152), 256, 0, stream>>>(x, wq, wk, wv, wp, Wb, ws, vsum, Xt);
  gemm_qkv<<<dim3(8, 8, 12), 256, 0, stream>>>(Xt, WQb, WKb, WVb, Qt, KS, VS,
                                               vsum);
  attn_fused<<<dim3(512), 512, 0, stream>>>(Qt, KS, VS, wh, Opart, lpart,
                                            l2part);
  gemm_proj<<<dim3(16, 8, 4), 256, 0, stream>>>(Opart, WPb, lpart, l2part, gm,
                                                bt, ws, bp, vsum, y);
}